// Round 2
// 1661.379 us; speedup vs baseline: 1.1457x; 1.1457x over previous
//
#include <hip/hip_runtime.h>
#include <hip/hip_bf16.h>
#include <math.h>

typedef __hip_bfloat16 hbf16;

#define B_ 8
#define C_ 768
#define HW_ 1024
#define NH_ 8
#define HD_ 96
#define NPTS 2048      // PH*PW*K
#define AROUND_ 5
#define TOPK_ 5
#define MOD_ 2
#define FF_ 3072
#define TOK_ (B_*HW_)  // 8192

typedef __attribute__((ext_vector_type(8))) short short8v;
typedef __attribute__((ext_vector_type(4))) short short4v;
typedef __attribute__((ext_vector_type(4))) float f32x4;

__device__ __forceinline__ float b2f(hbf16 v){ return __bfloat162float(v); }

// ---- bilinear taps, torch grid_sample semantics (align_corners=False, zeros pad), H=W=32 ----
struct Taps { int x0,x1,y0,y1; float w00,w10,w01,w11; };
__device__ __forceinline__ Taps bilin_taps(float gx, float gy) {
  Taps t;
  float ix = ((gx+1.f)*32.f - 1.f)*0.5f;
  float iy = ((gy+1.f)*32.f - 1.f)*0.5f;
  float x0f = floorf(ix), y0f = floorf(iy);
  float wx1 = ix-x0f, wy1 = iy-y0f, wx0 = 1.f-wx1, wy0 = 1.f-wy1;
  int x0=(int)x0f, y0=(int)y0f, x1=x0+1, y1=y0+1;
  bool vx0=(x0>=0)&&(x0<=31), vx1=(x1>=0)&&(x1<=31);
  bool vy0=(y0>=0)&&(y0<=31), vy1=(y1>=0)&&(y1<=31);
  t.w00 = (vx0&&vy0) ? wx0*wy0 : 0.f;
  t.w10 = (vx1&&vy0) ? wx1*wy0 : 0.f;
  t.w01 = (vx0&&vy1) ? wx0*wy1 : 0.f;
  t.w11 = (vx1&&vy1) ? wx1*wy1 : 0.f;
  t.x0 = min(max(x0,0),31); t.x1 = min(max(x1,0),31);
  t.y0 = min(max(y0,0),31); t.y1 = min(max(y1,0),31);
  return t;
}

__device__ __forceinline__ float block_reduce_sum_256(float v, float* red) {
  int tid = threadIdx.x;
  red[tid] = v; __syncthreads();
  for (int s = 128; s > 0; s >>= 1) { if (tid < s) red[tid] += red[tid+s]; __syncthreads(); }
  float r = red[0]; __syncthreads();
  return r;
}

// ---- fp32 -> bf16 elementwise convert (n multiple of 4) ----
__global__ __launch_bounds__(256) void f2b_kernel(const float* __restrict__ in,
    hbf16* __restrict__ out, int n) {
  int i = (blockIdx.x*256 + threadIdx.x)*4;
  if (i >= n) return;
  float4 v = *(const float4*)&in[i];
  out[i+0] = __float2bfloat16(v.x);
  out[i+1] = __float2bfloat16(v.y);
  out[i+2] = __float2bfloat16(v.z);
  out[i+3] = __float2bfloat16(v.w);
}

// ---- transpose+convert: fp32 in[K][N] -> bf16 out[N][K] (K,N multiples of 32) ----
__global__ __launch_bounds__(256) void wtrans_kernel(const float* __restrict__ in,
    hbf16* __restrict__ out, int K, int N) {
  __shared__ float t[32][33];
  int tx = threadIdx.x & 31, ty = threadIdx.x >> 5;
  int k0 = blockIdx.y*32, n0 = blockIdx.x*32;
  #pragma unroll
  for (int i = 0; i < 32; i += 8) t[ty+i][tx] = in[(size_t)(k0+ty+i)*N + n0+tx];
  __syncthreads();
  #pragma unroll
  for (int i = 0; i < 32; i += 8)
    out[(size_t)(n0+ty+i)*K + k0 + tx] = __float2bfloat16(t[tx][ty+i]);
}

// ---- transpose + split-convert: fp32 in[K][N] -> hi[N][K], lo[N][K] ----
__global__ __launch_bounds__(256) void wtrans_split_kernel(const float* __restrict__ in,
    hbf16* __restrict__ hi, hbf16* __restrict__ lo, int K, int N) {
  __shared__ float t[32][33];
  int tx = threadIdx.x & 31, ty = threadIdx.x >> 5;
  int k0 = blockIdx.y*32, n0 = blockIdx.x*32;
  #pragma unroll
  for (int i = 0; i < 32; i += 8) t[ty+i][tx] = in[(size_t)(k0+ty+i)*N + n0+tx];
  __syncthreads();
  #pragma unroll
  for (int i = 0; i < 32; i += 8) {
    float v = t[tx][ty+i];
    hbf16 h = __float2bfloat16(v);
    hi[(size_t)(n0+ty+i)*K + k0 + tx] = h;
    lo[(size_t)(n0+ty+i)*K + k0 + tx] = __float2bfloat16(v - b2f(h));
  }
}

// ---- batched fp32 transpose: per z, in [R][S] -> out [S][R] (R,S multiples of 32) ----
// grid (S/32, R/32, batch)
__global__ __launch_bounds__(256) void btrans_kernel(const float* __restrict__ in,
    float* __restrict__ out, int R, int S) {
  __shared__ float t[32][33];
  int tx = threadIdx.x & 31, ty = threadIdx.x >> 5;
  int r0 = blockIdx.y*32, s0 = blockIdx.x*32;
  const float* ib = in + (size_t)blockIdx.z*R*S;
  float* ob = out + (size_t)blockIdx.z*R*S;
  #pragma unroll
  for (int i = 0; i < 32; i += 8) t[ty+i][tx] = ib[(size_t)(r0+ty+i)*S + s0+tx];
  __syncthreads();
  #pragma unroll
  for (int i = 0; i < 32; i += 8) ob[(size_t)(s0+ty+i)*R + r0+tx] = t[tx][ty+i];
}

__global__ __launch_bounds__(256) void zero_kernel(float* __restrict__ p, int n) {
  int i = blockIdx.x*256 + threadIdx.x;
  if (i < n) p[i] = 0.f;
}

// ---- stage A: blockwise sample from CHANNEL-LAST image oT [B][HW][C] ----
// grid (G, NPTS/4): blockIdx.x = instance (XCD-pinned), 4 points per block.
__global__ __launch_bounds__(256) void sample_all_kernel(const float* __restrict__ oT,
    const float* __restrict__ brand, hbf16* __restrict__ pf_hi, hbf16* __restrict__ pf_lo,
    float* __restrict__ coords_all, int g0) {
  int ly = blockIdx.x;
  int inst = g0 + ly;
  int b = inst & 7;
  const float* xT = oT + (size_t)b*HW_*C_;
  int tid = threadIdx.x;
  int p = tid >> 6, lane = tid & 63;
  int n = blockIdx.y*4 + p;
  int k = n & 1, pw = (n >> 1) & 31, ph = n >> 6;
  const float* br = brand + (size_t)inst*4096;
  int roff = ((ph*32 + pw)*2 + k)*2;
  float r0 = br[roff], r1 = br[roff+1];
  const float bs = 0.0625f;
  float c0 = r0*bs + ((float)ph*bs - 1.0f);
  float c1 = r1*bs + ((float)pw*bs - 1.0f);
  Taps t = bilin_taps(c0, c1);
  const float* r00 = xT + (size_t)(t.y0*32+t.x0)*C_;
  const float* r10 = xT + (size_t)(t.y0*32+t.x1)*C_;
  const float* r01 = xT + (size_t)(t.y1*32+t.x0)*C_;
  const float* r11 = xT + (size_t)(t.y1*32+t.x1)*C_;
  size_t base = ((size_t)ly*NPTS + n)*C_;
  short* ph_ = (short*)pf_hi;
  short* pl_ = (short*)pf_lo;
  #pragma unroll
  for (int kk = 0; kk < 3; ++kk) {
    int c = kk*256 + lane*4;
    float4 v00 = *(const float4*)(r00 + c);
    float4 v10 = *(const float4*)(r10 + c);
    float4 v01 = *(const float4*)(r01 + c);
    float4 v11 = *(const float4*)(r11 + c);
    float o[4];
    o[0] = t.w00*v00.x + t.w10*v10.x + t.w01*v01.x + t.w11*v11.x;
    o[1] = t.w00*v00.y + t.w10*v10.y + t.w01*v01.y + t.w11*v11.y;
    o[2] = t.w00*v00.z + t.w10*v10.z + t.w01*v01.z + t.w11*v11.z;
    o[3] = t.w00*v00.w + t.w10*v10.w + t.w01*v01.w + t.w11*v11.w;
    short4v hs, ls;
    #pragma unroll
    for (int e = 0; e < 4; ++e) {
      hbf16 h = __float2bfloat16(o[e]);
      hs[e] = *(short*)&h;
      hbf16 l = __float2bfloat16(o[e] - b2f(h));
      ls[e] = *(short*)&l;
    }
    *(short4v*)&ph_[base + c] = hs;
    *(short4v*)&pl_[base + c] = ls;
  }
  if (lane == 0) {
    size_t co = ((size_t)inst*NPTS + n)*2;
    coords_all[co] = c0; coords_all[co+1] = c1;
  }
}

// ---- fused score GEMM (split-bf16, 3-term) + relu + w2-dot -> atomicAdd logits ----
__global__ __launch_bounds__(256) void score_gemm_kernel(const short* __restrict__ Ahi,
    const short* __restrict__ Alo, const short* __restrict__ Bhi, const short* __restrict__ Blo,
    const float* __restrict__ b1, const float* __restrict__ w2, float* __restrict__ logit) {
  __shared__ short AsH[128*40];
  __shared__ short AsL[128*40];
  __shared__ short BsH[128*40];
  __shared__ short BsL[128*40];
  int tid = threadIdx.x;
  int lane = tid & 63, w = tid >> 6;
  int wr = (w >> 1) * 64, wc = (w & 1) * 64;
  int m16 = lane & 15, quad = lane >> 4, q8 = quad * 8;
  int bm = blockIdx.y * 128, bn = blockIdx.x * 128;
  int ar = tid >> 2, ac = (tid & 3) * 8;
  f32x4 acc[4][4] = {};
  for (int k0 = 0; k0 < 768; k0 += 32) {
    *(short8v*)&AsH[ar*40 + ac]      = *(const short8v*)&Ahi[(size_t)(bm+ar)*768 + k0 + ac];
    *(short8v*)&AsH[(ar+64)*40 + ac] = *(const short8v*)&Ahi[(size_t)(bm+ar+64)*768 + k0 + ac];
    *(short8v*)&AsL[ar*40 + ac]      = *(const short8v*)&Alo[(size_t)(bm+ar)*768 + k0 + ac];
    *(short8v*)&AsL[(ar+64)*40 + ac] = *(const short8v*)&Alo[(size_t)(bm+ar+64)*768 + k0 + ac];
    *(short8v*)&BsH[ar*40 + ac]      = *(const short8v*)&Bhi[(size_t)(bn+ar)*768 + k0 + ac];
    *(short8v*)&BsH[(ar+64)*40 + ac] = *(const short8v*)&Bhi[(size_t)(bn+ar+64)*768 + k0 + ac];
    *(short8v*)&BsL[ar*40 + ac]      = *(const short8v*)&Blo[(size_t)(bn+ar)*768 + k0 + ac];
    *(short8v*)&BsL[(ar+64)*40 + ac] = *(const short8v*)&Blo[(size_t)(bn+ar+64)*768 + k0 + ac];
    __syncthreads();
    short8v ah[4], al[4], bh[4], bl[4];
    #pragma unroll
    for (int i=0;i<4;++i) {
      ah[i] = *(const short8v*)&AsH[(wr + i*16 + m16)*40 + q8];
      al[i] = *(const short8v*)&AsL[(wr + i*16 + m16)*40 + q8];
      bh[i] = *(const short8v*)&BsH[(wc + i*16 + m16)*40 + q8];
      bl[i] = *(const short8v*)&BsL[(wc + i*16 + m16)*40 + q8];
    }
    #pragma unroll
    for (int i=0;i<4;++i)
      #pragma unroll
      for (int j=0;j<4;++j) {
        acc[i][j] = __builtin_amdgcn_mfma_f32_16x16x32_bf16(ah[i], bh[j], acc[i][j], 0, 0, 0);
        acc[i][j] = __builtin_amdgcn_mfma_f32_16x16x32_bf16(ah[i], bl[j], acc[i][j], 0, 0, 0);
        acc[i][j] = __builtin_amdgcn_mfma_f32_16x16x32_bf16(al[i], bh[j], acc[i][j], 0, 0, 0);
      }
    __syncthreads();
  }
  float b1v[4], w2v[4];
  #pragma unroll
  for (int j=0;j<4;++j) {
    int col = bn + wc + j*16 + m16;
    b1v[j] = b1[col]; w2v[j] = w2[col];
  }
  #pragma unroll
  for (int i=0;i<4;++i) {
    #pragma unroll
    for (int r=0;r<4;++r) {
      float v = 0.f;
      #pragma unroll
      for (int j=0;j<4;++j) {
        float h = fmaxf(acc[i][j][r] + b1v[j], 0.f);
        v += h * w2v[j];
      }
      v += __shfl_xor(v, 1); v += __shfl_xor(v, 2);
      v += __shfl_xor(v, 4); v += __shfl_xor(v, 8);
      if (m16 == 0) atomicAdd(&logit[bm + wr + i*16 + quad*4 + r], v);
    }
  }
}

// ---- top-5 of 2048 per instance (on logits; sigmoid monotone), jax tie semantics ----
__global__ void topk_all_kernel(const float* __restrict__ logit, int* __restrict__ idx) {
  int lane = threadIdx.x;   // 64 lanes
  const float* score = logit + (size_t)blockIdx.x*NPTS;
  float v[32];
  #pragma unroll
  for (int i = 0; i < 32; ++i) v[i] = score[(i<<6) | lane];
  for (int t = 0; t < TOPK_; ++t) {
    float bv = v[0]; int bi = lane;
    #pragma unroll
    for (int i = 1; i < 32; ++i) { if (v[i] > bv) { bv = v[i]; bi = (i<<6)|lane; } }
    for (int off = 32; off; off >>= 1) {
      float ov = __shfl_xor(bv, off);
      int   oi = __shfl_xor(bi, off);
      if (ov > bv || (ov == bv && oi < bi)) { bv = ov; bi = oi; }
    }
    if (lane == 0) idx[blockIdx.x*8 + t] = bi;
    if ((bi & 63) == lane) v[bi >> 6] = -1e30f;
  }
}

// ---- soft_align + modality query -> memf rows; grid (TOPK, G) ----
// mainxT is channel-last [B][HW][C] (the tgt buffer, pre-tgt0)
__global__ __launch_bounds__(256) void softalign_all_kernel(const float* __restrict__ mainxT,
    const float* __restrict__ pos, const hbf16* __restrict__ pf_hi, const hbf16* __restrict__ pf_lo,
    const float* __restrict__ coords_all, const int* __restrict__ idx_all,
    const float* __restrict__ arand, const float* __restrict__ mq,
    float* __restrict__ memf, int g0) {
  int t = blockIdx.x;
  int ly = blockIdx.y;
  int inst = g0 + ly;
  int mod = inst >> 3, b = inst & 7;
  const float* mT_b = mainxT + (size_t)b*HW_*C_;
  const float* arand_ib = arand + (size_t)inst*AROUND_*TOPK_*2;
  const float* coords = coords_all + (size_t)inst*NPTS*2;
  int tid = threadIdx.x;
  int n = idx_all[ly*8 + t];
  float px0 = coords[n*2], px1 = coords[n*2+1];
  size_t pfb = ((size_t)ly*NPTS + n)*C_;
  float pfv[3];
  #pragma unroll
  for (int i=0;i<3;++i) {
    int c = tid + i*256;
    pfv[i] = b2f(pf_hi[pfb + c]) + b2f(pf_lo[pfb + c]);
  }
  __shared__ float red[256];
  float pp = block_reduce_sum_256(pfv[0]*pfv[0]+pfv[1]*pfv[1]+pfv[2]*pfv[2], red);
  float embr[AROUND_][3];
  float num_a[AROUND_], aa_a[AROUND_];
  for (int a=0; a<AROUND_; ++a) {
    int ar = (a*TOPK_ + t)*2;
    float g0c = px0 + (arand_ib[ar]*2.f - 0.5f)*0.2f;
    float g1c = px1 + (arand_ib[ar+1]*2.f - 0.5f)*0.2f;
    g0c = fminf(fmaxf(g0c,-1.f),1.f);
    g1c = fminf(fmaxf(g1c,-1.f),1.f);
    Taps tp = bilin_taps(g0c, g1c);
    int i00=tp.y0*32+tp.x0, i10=tp.y0*32+tp.x1, i01=tp.y1*32+tp.x0, i11=tp.y1*32+tp.x1;
    float s_num = 0.f, s_aa = 0.f;
    #pragma unroll
    for (int i=0;i<3;++i) {
      int c = tid + i*256;
      float af = tp.w00*mT_b[(size_t)i00*C_+c] + tp.w10*mT_b[(size_t)i10*C_+c]
               + tp.w01*mT_b[(size_t)i01*C_+c] + tp.w11*mT_b[(size_t)i11*C_+c];
      float em = tp.w00*pos[(size_t)i00*C_+c] + tp.w10*pos[(size_t)i10*C_+c]
               + tp.w01*pos[(size_t)i01*C_+c] + tp.w11*pos[(size_t)i11*C_+c];
      embr[a][i] = em;
      s_num += pfv[i]*af;
      s_aa  += af*af;
    }
    num_a[a] = block_reduce_sum_256(s_num, red);
    aa_a[a]  = block_reduce_sum_256(s_aa, red);
  }
  float pn = fmaxf(sqrtf(pp), 1e-8f);
  float w[AROUND_]; float mx = -1e30f;
  #pragma unroll
  for (int a=0;a<AROUND_;++a){ float den = pn * fmaxf(sqrtf(aa_a[a]),1e-8f); w[a]=num_a[a]/den; mx=fmaxf(mx,w[a]); }
  float se = 0.f;
  #pragma unroll
  for (int a=0;a<AROUND_;++a){ w[a]=expf(w[a]-mx); se+=w[a]; }
  float inv = 1.f/se;
  float* mo = memf + ((size_t)b*(MOD_*TOPK_) + mod*TOPK_ + t)*C_;
  #pragma unroll
  for (int i=0;i<3;++i) {
    int c = tid + i*256;
    float o = pfv[i];
    #pragma unroll
    for (int a=0;a<AROUND_;++a) o += embr[a][i]*(w[a]*inv);
    o += mq[(size_t)(mod+1)*C_ + c];
    mo[c] = o;
  }
}

// ---- generic fp32 GEMM (kvm only) ----
#define BM 64
#define BN 64
#define BK 16
__global__ __launch_bounds__(256) void gemm_kernel(const float* __restrict__ A, int lda,
    const float* __restrict__ Bw, int ldb, const float* __restrict__ bias,
    float* __restrict__ Cm, int ldc, int M, int N, int K, int act) {
  __shared__ float As[BK][BM];
  __shared__ float Bs[BK][BN];
  int tid = threadIdx.x;
  int bm = blockIdx.y * BM, bn = blockIdx.x * BN;
  int arw = tid >> 2, acl = (tid & 3) << 2;
  int brw = tid >> 4, bcl = (tid & 15) << 2;
  int ty = tid >> 4, tx = tid & 15;
  float acc[4][4] = {{0.f}};
  for (int k0 = 0; k0 < K; k0 += BK) {
    float a0=0.f,a1=0.f,a2=0.f,a3=0.f;
    if (bm + arw < M) {
      const float* ap = A + (size_t)(bm+arw)*lda + k0 + acl;
      a0=ap[0]; a1=ap[1]; a2=ap[2]; a3=ap[3];
    }
    As[acl+0][arw]=a0; As[acl+1][arw]=a1; As[acl+2][arw]=a2; As[acl+3][arw]=a3;
    const float* bp = Bw + (size_t)(k0+brw)*ldb + bn + bcl;
    Bs[brw][bcl+0]=bp[0]; Bs[brw][bcl+1]=bp[1]; Bs[brw][bcl+2]=bp[2]; Bs[brw][bcl+3]=bp[3];
    __syncthreads();
    #pragma unroll
    for (int kk = 0; kk < BK; ++kk) {
      float4 av = *reinterpret_cast<const float4*>(&As[kk][ty<<2]);
      float4 bv = *reinterpret_cast<const float4*>(&Bs[kk][tx<<2]);
      acc[0][0]+=av.x*bv.x; acc[0][1]+=av.x*bv.y; acc[0][2]+=av.x*bv.z; acc[0][3]+=av.x*bv.w;
      acc[1][0]+=av.y*bv.x; acc[1][1]+=av.y*bv.y; acc[1][2]+=av.y*bv.z; acc[1][3]+=av.y*bv.w;
      acc[2][0]+=av.z*bv.x; acc[2][1]+=av.z*bv.y; acc[2][2]+=av.z*bv.z; acc[2][3]+=av.z*bv.w;
      acc[3][0]+=av.w*bv.x; acc[3][1]+=av.w*bv.y; acc[3][2]+=av.w*bv.z; acc[3][3]+=av.w*bv.w;
    }
    __syncthreads();
  }
  #pragma unroll
  for (int i=0;i<4;++i) {
    int r = bm + (ty<<2) + i;
    if (r >= M) continue;
    float* cp = Cm + (size_t)r*ldc + bn + (tx<<2);
    #pragma unroll
    for (int j=0;j<4;++j) {
      float v = acc[i][j] + bias[bn + (tx<<2) + j];
      if (act) v = fmaxf(v, 0.f);
      cp[j] = v;
    }
  }
}

// ---- bf16 MFMA GEMM, B pre-transposed: C = act(A[M,K] @ Bt[N,K]^T + bias) ----
__global__ __launch_bounds__(256) void gemm_mfma_t(const short* __restrict__ A, int lda,
    const short* __restrict__ Bt, int ldbt, const float* __restrict__ bias,
    hbf16* __restrict__ Cm, int ldc, int K, int act) {
  __shared__ short As[128*40];
  __shared__ short Bs[128*40];
  int tid = threadIdx.x;
  int lane = tid & 63, w = tid >> 6;
  int wr = (w >> 1) * 64, wc = (w & 1) * 64;
  int m16 = lane & 15, q8 = (lane >> 4) * 8;
  int bm = blockIdx.y * 128, bn = blockIdx.x * 128;
  int ar = tid >> 2, ac = (tid & 3) * 8;
  f32x4 acc[4][4] = {};
  for (int k0 = 0; k0 < K; k0 += 32) {
    *(short8v*)&As[ar*40 + ac]      = *(const short8v*)&A[(size_t)(bm+ar)*lda + k0 + ac];
    *(short8v*)&As[(ar+64)*40 + ac] = *(const short8v*)&A[(size_t)(bm+ar+64)*lda + k0 + ac];
    *(short8v*)&Bs[ar*40 + ac]      = *(const short8v*)&Bt[(size_t)(bn+ar)*ldbt + k0 + ac];
    *(short8v*)&Bs[(ar+64)*40 + ac] = *(const short8v*)&Bt[(size_t)(bn+ar+64)*ldbt + k0 + ac];
    __syncthreads();
    short8v af[4], bf[4];
    #pragma unroll
    for (int i=0;i<4;++i) af[i] = *(const short8v*)&As[(wr + i*16 + m16)*40 + q8];
    #pragma unroll
    for (int j=0;j<4;++j) bf[j] = *(const short8v*)&Bs[(wc + j*16 + m16)*40 + q8];
    #pragma unroll
    for (int i=0;i<4;++i)
      #pragma unroll
      for (int j=0;j<4;++j)
        acc[i][j] = __builtin_amdgcn_mfma_f32_16x16x32_bf16(af[i], bf[j], acc[i][j], 0, 0, 0);
    __syncthreads();
  }
  #pragma unroll
  for (int j=0;j<4;++j) {
    int col = bn + wc + j*16 + m16;
    float bs = bias[col];
    #pragma unroll
    for (int i=0;i<4;++i) {
      int row0 = bm + wr + i*16 + (lane>>4)*4;
      #pragma unroll
      for (int r=0;r<4;++r) {
        float v = acc[i][j][r] + bs;
        if (act) v = fmaxf(v, 0.f);
        Cm[(size_t)(row0+r)*ldc + col] = __float2bfloat16(v);
      }
    }
  }
}

// ---- fused flash self-attention (MFMA): grid (qtile=8, head=8, batch=CH), 256 thr ----
__global__ __launch_bounds__(256) void flash_attn_kernel(const hbf16* __restrict__ qkv_all,
    hbf16* __restrict__ o_all) {
  const int q0 = blockIdx.x * 128;
  const int h  = blockIdx.y;
  const int bz = blockIdx.z;
  const short* qkv = (const short*)(qkv_all + (size_t)bz*HW_*2304);
  hbf16* ob = o_all + (size_t)bz*HW_*C_;
  const int tid = threadIdx.x;
  const int lane = tid & 63, w = tid >> 6;
  const int m16 = lane & 15, quad = lane >> 4, q8 = quad * 8;
  const float scale = 0.10206207261596577f;  // 1/sqrt(96)

  __shared__ short Qs[128*104];
  __shared__ short KP[128*72];    // K tile [64][104] (QK) aliased with P [128][72] (PV)
  __shared__ short Vt[96*72];     // V^T tile [d][j]

  for (int idx = tid; idx < 128*12; idx += 256) {
    int row = idx / 12, dc = idx % 12;
    *(short8v*)&Qs[row*104 + dc*8] = *(const short8v*)&qkv[(size_t)(q0+row)*2304 + h*HD_ + dc*8];
  }

  float m_st[2][4], l_st[2][4];
  f32x4 o_acc[2][6] = {};
  #pragma unroll
  for (int i=0;i<2;++i)
    #pragma unroll
    for (int r=0;r<4;++r){ m_st[i][r] = -1e30f; l_st[i][r] = 0.f; }

  for (int t = 0; t < 16; ++t) {
    int j0 = t * 64;
    for (int idx = tid; idx < 64*12; idx += 256) {
      int row = idx / 12, dc = idx % 12;
      *(short8v*)&KP[row*104 + dc*8] = *(const short8v*)&qkv[(size_t)(j0+row)*2304 + C_ + h*HD_ + dc*8];
    }
    // V^T stage: j fast within wave -> conflict-free LDS writes
    for (int idx = tid; idx < 64*12; idx += 256) {
      int j = idx & 63, dc = idx >> 6;
      short8v v = *(const short8v*)&qkv[(size_t)(j0+j)*2304 + 2*C_ + h*HD_ + dc*8];
      #pragma unroll
      for (int s = 0; s < 8; ++s) Vt[(dc*8+s)*72 + j] = v[s];
    }
    __syncthreads();

    f32x4 accs[2][4] = {};
    #pragma unroll
    for (int kk = 0; kk < 96; kk += 32) {
      short8v af[2], bf[4];
      #pragma unroll
      for (int i=0;i<2;++i) af[i] = *(const short8v*)&Qs[(w*32 + i*16 + m16)*104 + q8 + kk];
      #pragma unroll
      for (int n=0;n<4;++n) bf[n] = *(const short8v*)&KP[(n*16 + m16)*104 + q8 + kk];
      #pragma unroll
      for (int i=0;i<2;++i)
        #pragma unroll
        for (int n=0;n<4;++n)
          accs[i][n] = __builtin_amdgcn_mfma_f32_16x16x32_bf16(af[i], bf[n], accs[i][n], 0, 0, 0);
    }
    __syncthreads();

    #pragma unroll
    for (int i=0;i<2;++i) {
      #pragma unroll
      for (int r=0;r<4;++r) {
        float mx = -1e30f;
        #pragma unroll
        for (int n=0;n<4;++n) mx = fmaxf(mx, accs[i][n][r]*scale);
        #pragma unroll
        for (int off=1; off<16; off<<=1) mx = fmaxf(mx, __shfl_xor(mx, off));
        float m_new = fmaxf(m_st[i][r], mx);
        float alpha = expf(m_st[i][r] - m_new);
        float psum = 0.f;
        int prow = (w*32 + i*16 + quad*4 + r)*72 + m16;
        #pragma unroll
        for (int n=0;n<4;++n) {
          float pv = expf(accs[i][n][r]*scale - m_new);
          psum += pv;
          *(hbf16*)&KP[prow + n*16] = __float2bfloat16(pv);
        }
        #pragma unroll
        for (int off=1; off<16; off<<=1) psum += __shfl_xor(psum, off);
        l_st[i][r] = l_st[i][r]*alpha + psum;
        m_st[i][r] = m_new;
        #pragma unroll
        for (int dt=0; dt<6; ++dt) o_acc[i][dt][r] *= alpha;
      }
    }

    #pragma unroll
    for (int k0 = 0; k0 < 64; k0 += 32) {
      short8v pf_[2], vf[6];
      #pragma unroll
      for (int i=0;i<2;++i) pf_[i] = *(const short8v*)&KP[(w*32 + i*16 + m16)*72 + q8 + k0];
      #pragma unroll
      for (int dt=0; dt<6; ++dt) vf[dt] = *(const short8v*)&Vt[(dt*16 + m16)*72 + q8 + k0];
      #pragma unroll
      for (int i=0;i<2;++i)
        #pragma unroll
        for (int dt=0; dt<6; ++dt)
          o_acc[i][dt] = __builtin_amdgcn_mfma_f32_16x16x32_bf16(pf_[i], vf[dt], o_acc[i][dt], 0, 0, 0);
    }
    __syncthreads();
  }

  #pragma unroll
  for (int i=0;i<2;++i) {
    #pragma unroll
    for (int r=0;r<4;++r) {
      float inv = 1.f / l_st[i][r];
      int row = q0 + w*32 + i*16 + quad*4 + r;
      #pragma unroll
      for (int dt=0; dt<6; ++dt)
        ob[(size_t)row*C_ + h*HD_ + dt*16 + m16] = __float2bfloat16(o_acc[i][dt][r]*inv);
    }
  }
}

// ---- cross-attention over 10 memory tokens, grid (1024, CH), IN PLACE on bf16 q rows ----
__global__ __launch_bounds__(128) void cross_attn_kernel(hbf16* __restrict__ qb,
    const float* __restrict__ kvm, int b0) {
  int row = blockIdx.x;
  int lb = blockIdx.y;
  int b = b0 + lb;
  int tid = threadIdx.x;
  __shared__ float sc[16];
  __shared__ float qs[C_];
  hbf16* qp = qb + ((size_t)lb*HW_ + row)*C_;
  for (int c = tid; c < C_; c += 128) qs[c] = b2f(qp[c]);
  __syncthreads();
  const float scale = 0.10206207261596577f;
  for (int h = 0; h < NH_; ++h) {
    if (tid < 10) {
      const float* kp = kvm + (size_t)(b*10 + tid)*1536 + h*HD_;
      float s = 0.f;
      for (int d = 0; d < HD_; ++d) s += qs[h*HD_+d]*kp[d];
      sc[tid] = s*scale;
    }
    __syncthreads();
    if (tid == 0) {
      float m = -1e30f;
      for (int j=0;j<10;++j) m = fmaxf(m, sc[j]);
      float se = 0.f;
      for (int j=0;j<10;++j){ sc[j]=expf(sc[j]-m); se+=sc[j]; }
      float inv = 1.f/se;
      for (int j=0;j<10;++j) sc[j]*=inv;
    }
    __syncthreads();
    if (tid < HD_) {
      const float* vp = kvm + (size_t)(b*10)*1536 + C_ + h*HD_ + tid;
      float acc = 0.f;
      for (int j=0;j<10;++j) acc += sc[j]*vp[(size_t)j*1536];
      qp[h*HD_+tid] = __float2bfloat16(acc);
    }
    __syncthreads();
  }
}

// ---- tgt init: IN PLACE on pre-transposed mainxT (=tgt): += mq[0] + pos ----
__global__ __launch_bounds__(256) void tgt0_kernel(float* __restrict__ tgt,
    const float* __restrict__ mq, const float* __restrict__ pos) {
  size_t i = ((size_t)blockIdx.x*256 + threadIdx.x)*4;
  if (i >= (size_t)TOK_*C_) return;
  int c = (int)(i % C_);
  int tpos = (int)((i / C_) % HW_);
  float4 v = *(float4*)&tgt[i];
  float4 m = *(const float4*)&mq[c];
  float4 pp = *(const float4*)&pos[(size_t)tpos*C_ + c];
  v.x += m.x + pp.x; v.y += m.y + pp.y;
  v.z += m.z + pp.z; v.w += m.w + pp.w;
  *(float4*)&tgt[i] = v;
}

// ---- residual + layernorm (in place on fp32 tgt rows, bf16 add) ----
__global__ __launch_bounds__(256) void ln_res_kernel(float* __restrict__ tgt, const hbf16* __restrict__ add,
    const float* __restrict__ w, const float* __restrict__ bvec) {
  __shared__ float red[256];
  int row = blockIdx.x, tid = threadIdx.x;
  float* tp = tgt + (size_t)row*C_;
  const hbf16* ap = add + (size_t)row*C_;
  float x[3]; float s = 0.f, s2 = 0.f;
  #pragma unroll
  for (int i=0;i<3;++i){ int c=tid+i*256; float v=tp[c]+b2f(ap[c]); x[i]=v; s+=v; s2+=v*v; }
  s  = block_reduce_sum_256(s,  red);
  s2 = block_reduce_sum_256(s2, red);
  float mean = s * (1.f/C_);
  float var  = s2 * (1.f/C_) - mean*mean;
  float rstd = rsqrtf(var + 1e-5f);
  #pragma unroll
  for (int i=0;i<3;++i){ int c=tid+i*256; tp[c] = (x[i]-mean)*rstd*w[c] + bvec[c]; }
}

extern "C" void kernel_launch(void* const* d_in, const int* in_sizes, int n_in,
                              void* d_out, int out_size, void* d_ws, size_t ws_size,
                              hipStream_t stream) {
  const float* mainx   = (const float*)d_in[0];
  const float* other0  = (const float*)d_in[1];
  const float* other1  = (const float*)d_in[2];
  const float* pos     = (const float*)d_in[3];
  const float* mq      = (const float*)d_in[4];
  const float* s_w1    = (const float*)d_in[5];
  const float* s_b1    = (const float*)d_in[6];
  const float* s_w2    = (const float*)d_in[7];
  const float* sa_in_w = (const float*)d_in[9];
  const float* sa_in_b = (const float*)d_in[10];
  const float* sa_out_w= (const float*)d_in[11];
  const float* sa_out_b= (const float*)d_in[12];
  const float* ca_in_w = (const float*)d_in[13];
  const float* ca_in_b = (const float*)d_in[14];
  const float* ca_out_w= (const float*)d_in[15];
  const float* ca_out_b= (const float*)d_in[16];
  const float* ff1_w   = (const float*)d_in[17];
  const float* ff1_b   = (const float*)d_in[18];
  const float* ff2_w   = (const float*)d_in[19];
  const float* ff2_b   = (const float*)d_in[20];
  const float* ln_w    = (const float*)d_in[21];
  const float* ln_b    = (const float*)d_in[22];
  const float* brand   = (const float*)d_in[23];
  const float* arand   = (const float*)d_in[24];

  // ---- workspace layout ----
  char* p = (char*)d_ws;
  auto alloc = [&](size_t bytes) { char* r = p; p += (bytes + 255) & ~(size_t)255; return (void*)r; };
  float* tgt    = (float*)alloc((size_t)TOK_*C_*4);       // 24 MB; holds mainxT during stage A
  hbf16* wb0    = (hbf16*)alloc((size_t)2359296*2);       // 4.5 MB (transposed weights)
  hbf16* wb1    = (hbf16*)alloc((size_t)2359296*2);       // 4.5 MB
  hbf16* w1t_hi = (hbf16*)alloc((size_t)C_*C_*2);
  hbf16* w1t_lo = (hbf16*)alloc((size_t)C_*C_*2);
  float* kvm    = (float*)alloc((size_t)80*1536*4);
  float* memf   = (float*)alloc((size_t)80*C_*4);
  float* coords = (float*)alloc((size_t)16*NPTS*2*4);
  float* logit  = (float*)alloc((size_t)16*NPTS*4);
  int*   idxb   = (int*)alloc(16*8*4);
  char*  S      = p;
  size_t used = (size_t)(p - (char*)d_ws);
  size_t Savail = (ws_size > used) ? ws_size - used : 0;
  int CH = 1;
  if (Savail >= (size_t)8*1024*9216 + 4096) CH = 8;
  else if (Savail >= (size_t)4*1024*9216 + 4096) CH = 4;
  else if (Savail >= (size_t)2*1024*9216 + 4096) CH = 2;
  const size_t R = (size_t)CH*1024;
  const size_t perG = (size_t)NPTS*C_*2*2;  // pf_hi+pf_lo per instance
  // stage-A scratch: oT (one image set, channel-last) at front of S, pf after
  const size_t oTb = (size_t)B_*HW_*C_*4;   // 25.2 MB, 256-aligned
  float* oT = (float*)S;
  char* Spf = S + oTb;
  size_t SA = (Savail > oTb) ? Savail - oTb : 0;
  int G = 1;
  if (SA >= 8*perG) G = 8;
  else if (SA >= 4*perG) G = 4;
  else if (SA >= 2*perG) G = 2;

  // ---- stage A ----
  // mainx [B][C][HW] -> channel-last in tgt (softalign reads it; tgt0 finishes in place)
  btrans_kernel<<<dim3(HW_/32, C_/32, B_), 256, 0, stream>>>(mainx, tgt, C_, HW_);
  wtrans_split_kernel<<<dim3(C_/32, C_/32), 256, 0, stream>>>(s_w1, w1t_hi, w1t_lo, C_, C_);
  zero_kernel<<<16*NPTS/256, 256, 0, stream>>>(logit, 16*NPTS);
  for (int g0 = 0; g0 < 16; g0 += G) {
    if ((g0 & 7) == 0)
      btrans_kernel<<<dim3(HW_/32, C_/32, B_), 256, 0, stream>>>(g0 < 8 ? other0 : other1,
          oT, C_, HW_);
    hbf16* pf_hi = (hbf16*)Spf;
    hbf16* pf_lo = pf_hi + (size_t)G*NPTS*C_;
    sample_all_kernel<<<dim3(G, NPTS/4), 256, 0, stream>>>(oT, brand,
        pf_hi, pf_lo, coords, g0);
    score_gemm_kernel<<<dim3(6, G*16), 256, 0, stream>>>((const short*)pf_hi, (const short*)pf_lo,
        (const short*)w1t_hi, (const short*)w1t_lo, s_b1, s_w2, logit + (size_t)g0*NPTS);
    topk_all_kernel<<<G, 64, 0, stream>>>(logit + (size_t)g0*NPTS, idxb + g0*8);
    softalign_all_kernel<<<dim3(TOPK_, G), 256, 0, stream>>>(tgt, pos, pf_hi, pf_lo,
        coords, idxb + g0*8, arand, mq, memf, g0);
  }

  // ---- stage B ----
  size_t total = (size_t)TOK_*C_;
  tgt0_kernel<<<(int)((total/4+255)/256), 256, 0, stream>>>(tgt, mq, pos);

  for (int l = 0; l < 2; ++l) {
    // ===== self-attention =====
    wtrans_kernel<<<dim3(3*C_/32, C_/32), 256, 0, stream>>>(sa_in_w + (size_t)l*C_*3*C_, wb0, C_, 3*C_);
    wtrans_kernel<<<dim3(C_/32, C_/32), 256, 0, stream>>>(sa_out_w + (size_t)l*C_*C_, wb1, C_, C_);
    for (int c0 = 0; c0 < B_; c0 += CH) {
      float* tgtc = tgt + (size_t)c0*HW_*C_;
      hbf16* abuf = (hbf16*)S;
      hbf16* qkv  = abuf + R*C_;
      hbf16* oatt = qkv + R*3*C_;
      hbf16* tmpb = oatt + R*C_;
      f2b_kernel<<<(int)((R*C_/4+255)/256), 256, 0, stream>>>(tgtc, abuf, (int)(R*C_));
      gemm_mfma_t<<<dim3(3*C_/128, (int)(R/128)), 256, 0, stream>>>((const short*)abuf, C_,
          (const short*)wb0, C_, sa_in_b + (size_t)l*3*C_, qkv, 3*C_, C_, 0);
      flash_attn_kernel<<<dim3(HW_/128, NH_, CH), 256, 0, stream>>>(qkv, oatt);
      gemm_mfma_t<<<dim3(C_/128, (int)(R/128)), 256, 0, stream>>>((const short*)oatt, C_,
          (const short*)wb1, C_, sa_out_b + (size_t)l*C_, tmpb, C_, C_, 0);
      ln_res_kernel<<<(int)R, 256, 0, stream>>>(tgtc, tmpb,
          ln_w + (size_t)(l*3+0)*C_, ln_b + (size_t)(l*3+0)*C_);
    }

    // ===== cross-attention =====
    wtrans_kernel<<<dim3(C_/32, C_/32), 256, 0, stream>>>(ca_in_w + (size_t)l*C_*3*C_, wb0, C_, 3*C_);
    wtrans_kernel<<<dim3(C_/32, C_/32), 256, 0, stream>>>(ca_out_w + (size_t)l*C_*C_, wb1, C_, C_);
    gemm_kernel<<<dim3((2*C_+BN-1)/BN, (80+BM-1)/BM), 256, 0, stream>>>(memf, C_,
        ca_in_w + (size_t)l*C_*3*C_ + C_, 3*C_, ca_in_b + (size_t)l*3*C_ + C_, kvm, 2*C_,
        80, 2*C_, C_, 0);
    for (int c0 = 0; c0 < B_; c0 += CH) {
      float* tgtc = tgt + (size_t)c0*HW_*C_;
      hbf16* abuf = (hbf16*)S;
      hbf16* qb   = abuf + R*C_;
      hbf16* tmpb = qb + R*C_;
      f2b_kernel<<<(int)((R*C_/4+255)/256), 256, 0, stream>>>(tgtc, abuf, (int)(R*C_));
      gemm_mfma_t<<<dim3(C_/128, (int)(R/128)), 256, 0, stream>>>((const short*)abuf, C_,
          (const short*)wb0, C_, ca_in_b + (size_t)l*3*C_, qb, C_, C_, 0);
      cross_attn_kernel<<<dim3(HW_, CH), 128, 0, stream>>>(qb, kvm, c0);
      gemm_mfma_t<<<dim3(C_/128, (int)(R/128)), 256, 0, stream>>>((const short*)qb, C_,
          (const short*)wb1, C_, ca_out_b + (size_t)l*C_, tmpb, C_, C_, 0);
      ln_res_kernel<<<(int)R, 256, 0, stream>>>(tgtc, tmpb,
          ln_w + (size_t)(l*3+1)*C_, ln_b + (size_t)(l*3+1)*C_);
    }

    // ===== FFN =====
    wtrans_kernel<<<dim3(FF_/32, C_/32), 256, 0, stream>>>(ff1_w + (size_t)l*C_*FF_, wb0, C_, FF_);
    wtrans_kernel<<<dim3(C_/32, FF_/32), 256, 0, stream>>>(ff2_w + (size_t)l*FF_*C_, wb1, FF_, C_);
    for (int c0 = 0; c0 < B_; c0 += CH) {
      float* tgtc = tgt + (size_t)c0*HW_*C_;
      hbf16* abuf = (hbf16*)S;
      hbf16* ffh  = abuf + R*C_;
      hbf16* tmpb = ffh + R*FF_;
      f2b_kernel<<<(int)((R*C_/4+255)/256), 256, 0, stream>>>(tgtc, abuf, (int)(R*C_));
      gemm_mfma_t<<<dim3(FF_/128, (int)(R/128)), 256, 0, stream>>>((const short*)abuf, C_,
          (const short*)wb0, C_, ff1_b + (size_t)l*FF_, ffh, FF_, C_, 1);
      gemm_mfma_t<<<dim3(C_/128, (int)(R/128)), 256, 0, stream>>>((const short*)ffh, FF_,
          (const short*)wb1, FF_, ff2_b + (size_t)l*C_, tmpb, C_, FF_, 0);
      ln_res_kernel<<<(int)R, 256, 0, stream>>>(tgtc, tmpb,
          ln_w + (size_t)(l*3+2)*C_, ln_b + (size_t)(l*3+2)*C_);
    }
  }

  // ---- final: tgt [B][HW][C] -> out [B][C][H][W], LDS-tiled transpose ----
  btrans_kernel<<<dim3(C_/32, HW_/32, B_), 256, 0, stream>>>(tgt, (float*)d_out, HW_, C_);
}

// Round 3
// 1622.692 us; speedup vs baseline: 1.1730x; 1.0238x over previous
//
#include <hip/hip_runtime.h>
#include <hip/hip_bf16.h>
#include <math.h>

typedef __hip_bfloat16 hbf16;

#define B_ 8
#define C_ 768
#define HW_ 1024
#define NH_ 8
#define HD_ 96
#define NPTS 2048      // PH*PW*K
#define AROUND_ 5
#define TOPK_ 5
#define MOD_ 2
#define FF_ 3072
#define TOK_ (B_*HW_)  // 8192

typedef __attribute__((ext_vector_type(8))) short short8v;
typedef __attribute__((ext_vector_type(4))) short short4v;
typedef __attribute__((ext_vector_type(4))) float f32x4;

__device__ __forceinline__ float b2f(hbf16 v){ return __bfloat162float(v); }

// ---- bilinear taps, torch grid_sample semantics (align_corners=False, zeros pad), H=W=32 ----
struct Taps { int x0,x1,y0,y1; float w00,w10,w01,w11; };
__device__ __forceinline__ Taps bilin_taps(float gx, float gy) {
  Taps t;
  float ix = ((gx+1.f)*32.f - 1.f)*0.5f;
  float iy = ((gy+1.f)*32.f - 1.f)*0.5f;
  float x0f = floorf(ix), y0f = floorf(iy);
  float wx1 = ix-x0f, wy1 = iy-y0f, wx0 = 1.f-wx1, wy0 = 1.f-wy1;
  int x0=(int)x0f, y0=(int)y0f, x1=x0+1, y1=y0+1;
  bool vx0=(x0>=0)&&(x0<=31), vx1=(x1>=0)&&(x1<=31);
  bool vy0=(y0>=0)&&(y0<=31), vy1=(y1>=0)&&(y1<=31);
  t.w00 = (vx0&&vy0) ? wx0*wy0 : 0.f;
  t.w10 = (vx1&&vy0) ? wx1*wy0 : 0.f;
  t.w01 = (vx0&&vy1) ? wx0*wy1 : 0.f;
  t.w11 = (vx1&&vy1) ? wx1*wy1 : 0.f;
  t.x0 = min(max(x0,0),31); t.x1 = min(max(x1,0),31);
  t.y0 = min(max(y0,0),31); t.y1 = min(max(y1,0),31);
  return t;
}

__device__ __forceinline__ float block_reduce_sum_256(float v, float* red) {
  int tid = threadIdx.x;
  red[tid] = v; __syncthreads();
  for (int s = 128; s > 0; s >>= 1) { if (tid < s) red[tid] += red[tid+s]; __syncthreads(); }
  float r = red[0]; __syncthreads();
  return r;
}

// ---- fp32 -> bf16 elementwise convert (n multiple of 4) ----
__global__ __launch_bounds__(256) void f2b_kernel(const float* __restrict__ in,
    hbf16* __restrict__ out, int n) {
  int i = (blockIdx.x*256 + threadIdx.x)*4;
  if (i >= n) return;
  float4 v = *(const float4*)&in[i];
  out[i+0] = __float2bfloat16(v.x);
  out[i+1] = __float2bfloat16(v.y);
  out[i+2] = __float2bfloat16(v.z);
  out[i+3] = __float2bfloat16(v.w);
}

// ---- transpose+convert: fp32 in[K][N] -> bf16 out[N][K] (K,N multiples of 32) ----
__global__ __launch_bounds__(256) void wtrans_kernel(const float* __restrict__ in,
    hbf16* __restrict__ out, int K, int N) {
  __shared__ float t[32][33];
  int tx = threadIdx.x & 31, ty = threadIdx.x >> 5;
  int k0 = blockIdx.y*32, n0 = blockIdx.x*32;
  #pragma unroll
  for (int i = 0; i < 32; i += 8) t[ty+i][tx] = in[(size_t)(k0+ty+i)*N + n0+tx];
  __syncthreads();
  #pragma unroll
  for (int i = 0; i < 32; i += 8)
    out[(size_t)(n0+ty+i)*K + k0 + tx] = __float2bfloat16(t[tx][ty+i]);
}

// ---- transpose + split-convert: fp32 in[K][N] -> hi[N][K], lo[N][K] ----
__global__ __launch_bounds__(256) void wtrans_split_kernel(const float* __restrict__ in,
    hbf16* __restrict__ hi, hbf16* __restrict__ lo, int K, int N) {
  __shared__ float t[32][33];
  int tx = threadIdx.x & 31, ty = threadIdx.x >> 5;
  int k0 = blockIdx.y*32, n0 = blockIdx.x*32;
  #pragma unroll
  for (int i = 0; i < 32; i += 8) t[ty+i][tx] = in[(size_t)(k0+ty+i)*N + n0+tx];
  __syncthreads();
  #pragma unroll
  for (int i = 0; i < 32; i += 8) {
    float v = t[tx][ty+i];
    hbf16 h = __float2bfloat16(v);
    hi[(size_t)(n0+ty+i)*K + k0 + tx] = h;
    lo[(size_t)(n0+ty+i)*K + k0 + tx] = __float2bfloat16(v - b2f(h));
  }
}

// ---- batched fp32 transpose: per z, in [R][S] -> out [S][R] (R,S multiples of 32) ----
// grid (S/32, R/32, batch)
__global__ __launch_bounds__(256) void btrans_kernel(const float* __restrict__ in,
    float* __restrict__ out, int R, int S) {
  __shared__ float t[32][33];
  int tx = threadIdx.x & 31, ty = threadIdx.x >> 5;
  int r0 = blockIdx.y*32, s0 = blockIdx.x*32;
  const float* ib = in + (size_t)blockIdx.z*R*S;
  float* ob = out + (size_t)blockIdx.z*R*S;
  #pragma unroll
  for (int i = 0; i < 32; i += 8) t[ty+i][tx] = ib[(size_t)(r0+ty+i)*S + s0+tx];
  __syncthreads();
  #pragma unroll
  for (int i = 0; i < 32; i += 8) ob[(size_t)(s0+ty+i)*R + r0+tx] = t[tx][ty+i];
}

__global__ __launch_bounds__(256) void zero_kernel(float* __restrict__ p, int n) {
  int i = blockIdx.x*256 + threadIdx.x;
  if (i < n) p[i] = 0.f;
}

// ---- stage A: blockwise sample from CHANNEL-LAST image oT [B][HW][C] ----
// grid (G, NPTS/4): blockIdx.x = instance (XCD-pinned), 4 points per block.
__global__ __launch_bounds__(256) void sample_all_kernel(const float* __restrict__ oT,
    const float* __restrict__ brand, hbf16* __restrict__ pf_hi, hbf16* __restrict__ pf_lo,
    float* __restrict__ coords_all, int g0) {
  int ly = blockIdx.x;
  int inst = g0 + ly;
  int b = inst & 7;
  const float* xT = oT + (size_t)b*HW_*C_;
  int tid = threadIdx.x;
  int p = tid >> 6, lane = tid & 63;
  int n = blockIdx.y*4 + p;
  int k = n & 1, pw = (n >> 1) & 31, ph = n >> 6;
  const float* br = brand + (size_t)inst*4096;
  int roff = ((ph*32 + pw)*2 + k)*2;
  float r0 = br[roff], r1 = br[roff+1];
  const float bs = 0.0625f;
  float c0 = r0*bs + ((float)ph*bs - 1.0f);
  float c1 = r1*bs + ((float)pw*bs - 1.0f);
  Taps t = bilin_taps(c0, c1);
  const float* r00 = xT + (size_t)(t.y0*32+t.x0)*C_;
  const float* r10 = xT + (size_t)(t.y0*32+t.x1)*C_;
  const float* r01 = xT + (size_t)(t.y1*32+t.x0)*C_;
  const float* r11 = xT + (size_t)(t.y1*32+t.x1)*C_;
  size_t base = ((size_t)ly*NPTS + n)*C_;
  short* ph_ = (short*)pf_hi;
  short* pl_ = (short*)pf_lo;
  #pragma unroll
  for (int kk = 0; kk < 3; ++kk) {
    int c = kk*256 + lane*4;
    float4 v00 = *(const float4*)(r00 + c);
    float4 v10 = *(const float4*)(r10 + c);
    float4 v01 = *(const float4*)(r01 + c);
    float4 v11 = *(const float4*)(r11 + c);
    float o[4];
    o[0] = t.w00*v00.x + t.w10*v10.x + t.w01*v01.x + t.w11*v11.x;
    o[1] = t.w00*v00.y + t.w10*v10.y + t.w01*v01.y + t.w11*v11.y;
    o[2] = t.w00*v00.z + t.w10*v10.z + t.w01*v01.z + t.w11*v11.z;
    o[3] = t.w00*v00.w + t.w10*v10.w + t.w01*v01.w + t.w11*v11.w;
    short4v hs, ls;
    #pragma unroll
    for (int e = 0; e < 4; ++e) {
      hbf16 h = __float2bfloat16(o[e]);
      hs[e] = *(short*)&h;
      hbf16 l = __float2bfloat16(o[e] - b2f(h));
      ls[e] = *(short*)&l;
    }
    *(short4v*)&ph_[base + c] = hs;
    *(short4v*)&pl_[base + c] = ls;
  }
  if (lane == 0) {
    size_t co = ((size_t)inst*NPTS + n)*2;
    coords_all[co] = c0; coords_all[co+1] = c1;
  }
}

// ---- fused score GEMM (split-bf16, 3-term) + relu + w2-dot -> atomicAdd logits ----
__global__ __launch_bounds__(256) void score_gemm_kernel(const short* __restrict__ Ahi,
    const short* __restrict__ Alo, const short* __restrict__ Bhi, const short* __restrict__ Blo,
    const float* __restrict__ b1, const float* __restrict__ w2, float* __restrict__ logit) {
  __shared__ short AsH[128*40];
  __shared__ short AsL[128*40];
  __shared__ short BsH[128*40];
  __shared__ short BsL[128*40];
  int tid = threadIdx.x;
  int lane = tid & 63, w = tid >> 6;
  int wr = (w >> 1) * 64, wc = (w & 1) * 64;
  int m16 = lane & 15, quad = lane >> 4, q8 = quad * 8;
  int bm = blockIdx.y * 128, bn = blockIdx.x * 128;
  int ar = tid >> 2, ac = (tid & 3) * 8;
  f32x4 acc[4][4] = {};
  for (int k0 = 0; k0 < 768; k0 += 32) {
    *(short8v*)&AsH[ar*40 + ac]      = *(const short8v*)&Ahi[(size_t)(bm+ar)*768 + k0 + ac];
    *(short8v*)&AsH[(ar+64)*40 + ac] = *(const short8v*)&Ahi[(size_t)(bm+ar+64)*768 + k0 + ac];
    *(short8v*)&AsL[ar*40 + ac]      = *(const short8v*)&Alo[(size_t)(bm+ar)*768 + k0 + ac];
    *(short8v*)&AsL[(ar+64)*40 + ac] = *(const short8v*)&Alo[(size_t)(bm+ar+64)*768 + k0 + ac];
    *(short8v*)&BsH[ar*40 + ac]      = *(const short8v*)&Bhi[(size_t)(bn+ar)*768 + k0 + ac];
    *(short8v*)&BsH[(ar+64)*40 + ac] = *(const short8v*)&Bhi[(size_t)(bn+ar+64)*768 + k0 + ac];
    *(short8v*)&BsL[ar*40 + ac]      = *(const short8v*)&Blo[(size_t)(bn+ar)*768 + k0 + ac];
    *(short8v*)&BsL[(ar+64)*40 + ac] = *(const short8v*)&Blo[(size_t)(bn+ar+64)*768 + k0 + ac];
    __syncthreads();
    short8v ah[4], al[4], bh[4], bl[4];
    #pragma unroll
    for (int i=0;i<4;++i) {
      ah[i] = *(const short8v*)&AsH[(wr + i*16 + m16)*40 + q8];
      al[i] = *(const short8v*)&AsL[(wr + i*16 + m16)*40 + q8];
      bh[i] = *(const short8v*)&BsH[(wc + i*16 + m16)*40 + q8];
      bl[i] = *(const short8v*)&BsL[(wc + i*16 + m16)*40 + q8];
    }
    #pragma unroll
    for (int i=0;i<4;++i)
      #pragma unroll
      for (int j=0;j<4;++j) {
        acc[i][j] = __builtin_amdgcn_mfma_f32_16x16x32_bf16(ah[i], bh[j], acc[i][j], 0, 0, 0);
        acc[i][j] = __builtin_amdgcn_mfma_f32_16x16x32_bf16(ah[i], bl[j], acc[i][j], 0, 0, 0);
        acc[i][j] = __builtin_amdgcn_mfma_f32_16x16x32_bf16(al[i], bh[j], acc[i][j], 0, 0, 0);
      }
    __syncthreads();
  }
  float b1v[4], w2v[4];
  #pragma unroll
  for (int j=0;j<4;++j) {
    int col = bn + wc + j*16 + m16;
    b1v[j] = b1[col]; w2v[j] = w2[col];
  }
  #pragma unroll
  for (int i=0;i<4;++i) {
    #pragma unroll
    for (int r=0;r<4;++r) {
      float v = 0.f;
      #pragma unroll
      for (int j=0;j<4;++j) {
        float h = fmaxf(acc[i][j][r] + b1v[j], 0.f);
        v += h * w2v[j];
      }
      v += __shfl_xor(v, 1); v += __shfl_xor(v, 2);
      v += __shfl_xor(v, 4); v += __shfl_xor(v, 8);
      if (m16 == 0) atomicAdd(&logit[bm + wr + i*16 + quad*4 + r], v);
    }
  }
}

// ---- top-5 of 2048 per instance (on logits; sigmoid monotone), jax tie semantics ----
__global__ void topk_all_kernel(const float* __restrict__ logit, int* __restrict__ idx) {
  int lane = threadIdx.x;   // 64 lanes
  const float* score = logit + (size_t)blockIdx.x*NPTS;
  float v[32];
  #pragma unroll
  for (int i = 0; i < 32; ++i) v[i] = score[(i<<6) | lane];
  for (int t = 0; t < TOPK_; ++t) {
    float bv = v[0]; int bi = lane;
    #pragma unroll
    for (int i = 1; i < 32; ++i) { if (v[i] > bv) { bv = v[i]; bi = (i<<6)|lane; } }
    for (int off = 32; off; off >>= 1) {
      float ov = __shfl_xor(bv, off);
      int   oi = __shfl_xor(bi, off);
      if (ov > bv || (ov == bv && oi < bi)) { bv = ov; bi = oi; }
    }
    if (lane == 0) idx[blockIdx.x*8 + t] = bi;
    if ((bi & 63) == lane) v[bi >> 6] = -1e30f;
  }
}

// ---- soft_align + modality query -> memf rows; grid (TOPK, G) ----
// mainxT is channel-last [B][HW][C] (the tgt buffer, pre-tgt0)
__global__ __launch_bounds__(256) void softalign_all_kernel(const float* __restrict__ mainxT,
    const float* __restrict__ pos, const hbf16* __restrict__ pf_hi, const hbf16* __restrict__ pf_lo,
    const float* __restrict__ coords_all, const int* __restrict__ idx_all,
    const float* __restrict__ arand, const float* __restrict__ mq,
    float* __restrict__ memf, int g0) {
  int t = blockIdx.x;
  int ly = blockIdx.y;
  int inst = g0 + ly;
  int mod = inst >> 3, b = inst & 7;
  const float* mT_b = mainxT + (size_t)b*HW_*C_;
  const float* arand_ib = arand + (size_t)inst*AROUND_*TOPK_*2;
  const float* coords = coords_all + (size_t)inst*NPTS*2;
  int tid = threadIdx.x;
  int n = idx_all[ly*8 + t];
  float px0 = coords[n*2], px1 = coords[n*2+1];
  size_t pfb = ((size_t)ly*NPTS + n)*C_;
  float pfv[3];
  #pragma unroll
  for (int i=0;i<3;++i) {
    int c = tid + i*256;
    pfv[i] = b2f(pf_hi[pfb + c]) + b2f(pf_lo[pfb + c]);
  }
  __shared__ float red[256];
  float pp = block_reduce_sum_256(pfv[0]*pfv[0]+pfv[1]*pfv[1]+pfv[2]*pfv[2], red);
  float embr[AROUND_][3];
  float num_a[AROUND_], aa_a[AROUND_];
  for (int a=0; a<AROUND_; ++a) {
    int ar = (a*TOPK_ + t)*2;
    float g0c = px0 + (arand_ib[ar]*2.f - 0.5f)*0.2f;
    float g1c = px1 + (arand_ib[ar+1]*2.f - 0.5f)*0.2f;
    g0c = fminf(fmaxf(g0c,-1.f),1.f);
    g1c = fminf(fmaxf(g1c,-1.f),1.f);
    Taps tp = bilin_taps(g0c, g1c);
    int i00=tp.y0*32+tp.x0, i10=tp.y0*32+tp.x1, i01=tp.y1*32+tp.x0, i11=tp.y1*32+tp.x1;
    float s_num = 0.f, s_aa = 0.f;
    #pragma unroll
    for (int i=0;i<3;++i) {
      int c = tid + i*256;
      float af = tp.w00*mT_b[(size_t)i00*C_+c] + tp.w10*mT_b[(size_t)i10*C_+c]
               + tp.w01*mT_b[(size_t)i01*C_+c] + tp.w11*mT_b[(size_t)i11*C_+c];
      float em = tp.w00*pos[(size_t)i00*C_+c] + tp.w10*pos[(size_t)i10*C_+c]
               + tp.w01*pos[(size_t)i01*C_+c] + tp.w11*pos[(size_t)i11*C_+c];
      embr[a][i] = em;
      s_num += pfv[i]*af;
      s_aa  += af*af;
    }
    num_a[a] = block_reduce_sum_256(s_num, red);
    aa_a[a]  = block_reduce_sum_256(s_aa, red);
  }
  float pn = fmaxf(sqrtf(pp), 1e-8f);
  float w[AROUND_]; float mx = -1e30f;
  #pragma unroll
  for (int a=0;a<AROUND_;++a){ float den = pn * fmaxf(sqrtf(aa_a[a]),1e-8f); w[a]=num_a[a]/den; mx=fmaxf(mx,w[a]); }
  float se = 0.f;
  #pragma unroll
  for (int a=0;a<AROUND_;++a){ w[a]=expf(w[a]-mx); se+=w[a]; }
  float inv = 1.f/se;
  float* mo = memf + ((size_t)b*(MOD_*TOPK_) + mod*TOPK_ + t)*C_;
  #pragma unroll
  for (int i=0;i<3;++i) {
    int c = tid + i*256;
    float o = pfv[i];
    #pragma unroll
    for (int a=0;a<AROUND_;++a) o += embr[a][i]*(w[a]*inv);
    o += mq[(size_t)(mod+1)*C_ + c];
    mo[c] = o;
  }
}

// ---- generic fp32 GEMM (kvm only) ----
#define BM 64
#define BN 64
#define BK 16
__global__ __launch_bounds__(256) void gemm_kernel(const float* __restrict__ A, int lda,
    const float* __restrict__ Bw, int ldb, const float* __restrict__ bias,
    float* __restrict__ Cm, int ldc, int M, int N, int K, int act) {
  __shared__ float As[BK][BM];
  __shared__ float Bs[BK][BN];
  int tid = threadIdx.x;
  int bm = blockIdx.y * BM, bn = blockIdx.x * BN;
  int arw = tid >> 2, acl = (tid & 3) << 2;
  int brw = tid >> 4, bcl = (tid & 15) << 2;
  int ty = tid >> 4, tx = tid & 15;
  float acc[4][4] = {{0.f}};
  for (int k0 = 0; k0 < K; k0 += BK) {
    float a0=0.f,a1=0.f,a2=0.f,a3=0.f;
    if (bm + arw < M) {
      const float* ap = A + (size_t)(bm+arw)*lda + k0 + acl;
      a0=ap[0]; a1=ap[1]; a2=ap[2]; a3=ap[3];
    }
    As[acl+0][arw]=a0; As[acl+1][arw]=a1; As[acl+2][arw]=a2; As[acl+3][arw]=a3;
    const float* bp = Bw + (size_t)(k0+brw)*ldb + bn + bcl;
    Bs[brw][bcl+0]=bp[0]; Bs[brw][bcl+1]=bp[1]; Bs[brw][bcl+2]=bp[2]; Bs[brw][bcl+3]=bp[3];
    __syncthreads();
    #pragma unroll
    for (int kk = 0; kk < BK; ++kk) {
      float4 av = *reinterpret_cast<const float4*>(&As[kk][ty<<2]);
      float4 bv = *reinterpret_cast<const float4*>(&Bs[kk][tx<<2]);
      acc[0][0]+=av.x*bv.x; acc[0][1]+=av.x*bv.y; acc[0][2]+=av.x*bv.z; acc[0][3]+=av.x*bv.w;
      acc[1][0]+=av.y*bv.x; acc[1][1]+=av.y*bv.y; acc[1][2]+=av.y*bv.z; acc[1][3]+=av.y*bv.w;
      acc[2][0]+=av.z*bv.x; acc[2][1]+=av.z*bv.y; acc[2][2]+=av.z*bv.z; acc[2][3]+=av.z*bv.w;
      acc[3][0]+=av.w*bv.x; acc[3][1]+=av.w*bv.y; acc[3][2]+=av.w*bv.z; acc[3][3]+=av.w*bv.w;
    }
    __syncthreads();
  }
  #pragma unroll
  for (int i=0;i<4;++i) {
    int r = bm + (ty<<2) + i;
    if (r >= M) continue;
    float* cp = Cm + (size_t)r*ldc + bn + (tx<<2);
    #pragma unroll
    for (int j=0;j<4;++j) {
      float v = acc[i][j] + bias[bn + (tx<<2) + j];
      if (act) v = fmaxf(v, 0.f);
      cp[j] = v;
    }
  }
}

// ---- bf16 MFMA GEMM, B pre-transposed: C = act(A[M,K] @ Bt[N,K]^T + bias) ----
__global__ __launch_bounds__(256) void gemm_mfma_t(const short* __restrict__ A, int lda,
    const short* __restrict__ Bt, int ldbt, const float* __restrict__ bias,
    hbf16* __restrict__ Cm, int ldc, int K, int act) {
  __shared__ short As[128*40];
  __shared__ short Bs[128*40];
  int tid = threadIdx.x;
  int lane = tid & 63, w = tid >> 6;
  int wr = (w >> 1) * 64, wc = (w & 1) * 64;
  int m16 = lane & 15, q8 = (lane >> 4) * 8;
  int bm = blockIdx.y * 128, bn = blockIdx.x * 128;
  int ar = tid >> 2, ac = (tid & 3) * 8;
  f32x4 acc[4][4] = {};
  for (int k0 = 0; k0 < K; k0 += 32) {
    *(short8v*)&As[ar*40 + ac]      = *(const short8v*)&A[(size_t)(bm+ar)*lda + k0 + ac];
    *(short8v*)&As[(ar+64)*40 + ac] = *(const short8v*)&A[(size_t)(bm+ar+64)*lda + k0 + ac];
    *(short8v*)&Bs[ar*40 + ac]      = *(const short8v*)&Bt[(size_t)(bn+ar)*ldbt + k0 + ac];
    *(short8v*)&Bs[(ar+64)*40 + ac] = *(const short8v*)&Bt[(size_t)(bn+ar+64)*ldbt + k0 + ac];
    __syncthreads();
    short8v af[4], bf[4];
    #pragma unroll
    for (int i=0;i<4;++i) af[i] = *(const short8v*)&As[(wr + i*16 + m16)*40 + q8];
    #pragma unroll
    for (int j=0;j<4;++j) bf[j] = *(const short8v*)&Bs[(wc + j*16 + m16)*40 + q8];
    #pragma unroll
    for (int i=0;i<4;++i)
      #pragma unroll
      for (int j=0;j<4;++j)
        acc[i][j] = __builtin_amdgcn_mfma_f32_16x16x32_bf16(af[i], bf[j], acc[i][j], 0, 0, 0);
    __syncthreads();
  }
  #pragma unroll
  for (int j=0;j<4;++j) {
    int col = bn + wc + j*16 + m16;
    float bs = bias[col];
    #pragma unroll
    for (int i=0;i<4;++i) {
      int row0 = bm + wr + i*16 + (lane>>4)*4;
      #pragma unroll
      for (int r=0;r<4;++r) {
        float v = acc[i][j][r] + bs;
        if (act) v = fmaxf(v, 0.f);
        Cm[(size_t)(row0+r)*ldc + col] = __float2bfloat16(v);
      }
    }
  }
}

// ---- fused flash self-attention (MFMA): grid (head+batch, qtile=8), 256 thr ----
// x = h + NH_*bz so all q-tiles of one (b,h) share an XCD (ids congruent mod 8).
// Q fragments live in registers; LDS = KP ∪ Vt only (32.3 KB -> 3-4 blocks/CU).
__global__ __launch_bounds__(256, 3) void flash_attn_kernel(const hbf16* __restrict__ qkv_all,
    hbf16* __restrict__ o_all) {
  const int hb = blockIdx.x;
  const int h  = hb & 7;
  const int bz = hb >> 3;
  const int q0 = blockIdx.y * 128;
  const short* qkv = (const short*)(qkv_all + (size_t)bz*HW_*2304);
  hbf16* ob = o_all + (size_t)bz*HW_*C_;
  const int tid = threadIdx.x;
  const int lane = tid & 63, w = tid >> 6;
  const int m16 = lane & 15, quad = lane >> 4, q8 = quad * 8;
  const float scale = 0.10206207261596577f;  // 1/sqrt(96)

  // 16128 shorts = 32256 B. KP = lds[0..9216): K tile [64][104] (QK) / P [128][72] (PV).
  // Vt = lds[9216..16128): V^T [96][72]. Q staging [128][104]=13312 aliases both.
  __shared__ short lds[16128];
  short* KP = lds;
  short* Vt = lds + 9216;

  // stage Q -> LDS (coalesced), then hoist this wave's fragments to registers
  for (int idx = tid; idx < 128*12; idx += 256) {
    int row = idx / 12, dc = idx % 12;
    *(short8v*)&lds[row*104 + dc*8] = *(const short8v*)&qkv[(size_t)(q0+row)*2304 + h*HD_ + dc*8];
  }
  __syncthreads();
  short8v qf[2][3];
  #pragma unroll
  for (int i=0;i<2;++i)
    #pragma unroll
    for (int kkk=0;kkk<3;++kkk)
      qf[i][kkk] = *(const short8v*)&lds[(w*32 + i*16 + m16)*104 + q8 + kkk*32];
  __syncthreads();

  float m_st[2][4], l_st[2][4];
  f32x4 o_acc[2][6] = {};
  #pragma unroll
  for (int i=0;i<2;++i)
    #pragma unroll
    for (int r=0;r<4;++r){ m_st[i][r] = -1e30f; l_st[i][r] = 0.f; }

  for (int t = 0; t < 16; ++t) {
    int j0 = t * 64;
    for (int idx = tid; idx < 64*12; idx += 256) {
      int row = idx / 12, dc = idx % 12;
      *(short8v*)&KP[row*104 + dc*8] = *(const short8v*)&qkv[(size_t)(j0+row)*2304 + C_ + h*HD_ + dc*8];
    }
    // V^T stage: j fast within wave -> conflict-free LDS writes
    for (int idx = tid; idx < 64*12; idx += 256) {
      int j = idx & 63, dc = idx >> 6;
      short8v v = *(const short8v*)&qkv[(size_t)(j0+j)*2304 + 2*C_ + h*HD_ + dc*8];
      #pragma unroll
      for (int s = 0; s < 8; ++s) Vt[(dc*8+s)*72 + j] = v[s];
    }
    __syncthreads();

    f32x4 accs[2][4] = {};
    #pragma unroll
    for (int kkk = 0; kkk < 3; ++kkk) {
      int kk = kkk*32;
      short8v bf[4];
      #pragma unroll
      for (int n=0;n<4;++n) bf[n] = *(const short8v*)&KP[(n*16 + m16)*104 + q8 + kk];
      #pragma unroll
      for (int i=0;i<2;++i)
        #pragma unroll
        for (int n=0;n<4;++n)
          accs[i][n] = __builtin_amdgcn_mfma_f32_16x16x32_bf16(qf[i][kkk], bf[n], accs[i][n], 0, 0, 0);
    }
    __syncthreads();

    #pragma unroll
    for (int i=0;i<2;++i) {
      #pragma unroll
      for (int r=0;r<4;++r) {
        float mx = -1e30f;
        #pragma unroll
        for (int n=0;n<4;++n) mx = fmaxf(mx, accs[i][n][r]*scale);
        #pragma unroll
        for (int off=1; off<16; off<<=1) mx = fmaxf(mx, __shfl_xor(mx, off));
        float m_new = fmaxf(m_st[i][r], mx);
        float alpha = __expf(m_st[i][r] - m_new);
        float psum = 0.f;
        int prow = (w*32 + i*16 + quad*4 + r)*72 + m16;
        #pragma unroll
        for (int n=0;n<4;++n) {
          float pv = __expf(accs[i][n][r]*scale - m_new);
          psum += pv;
          *(hbf16*)&KP[prow + n*16] = __float2bfloat16(pv);
        }
        #pragma unroll
        for (int off=1; off<16; off<<=1) psum += __shfl_xor(psum, off);
        l_st[i][r] = l_st[i][r]*alpha + psum;
        m_st[i][r] = m_new;
        #pragma unroll
        for (int dt=0; dt<6; ++dt) o_acc[i][dt][r] *= alpha;
      }
    }

    #pragma unroll
    for (int k0 = 0; k0 < 64; k0 += 32) {
      short8v pf_[2], vf[6];
      #pragma unroll
      for (int i=0;i<2;++i) pf_[i] = *(const short8v*)&KP[(w*32 + i*16 + m16)*72 + q8 + k0];
      #pragma unroll
      for (int dt=0; dt<6; ++dt) vf[dt] = *(const short8v*)&Vt[(dt*16 + m16)*72 + q8 + k0];
      #pragma unroll
      for (int i=0;i<2;++i)
        #pragma unroll
        for (int dt=0; dt<6; ++dt)
          o_acc[i][dt] = __builtin_amdgcn_mfma_f32_16x16x32_bf16(pf_[i], vf[dt], o_acc[i][dt], 0, 0, 0);
    }
    __syncthreads();
  }

  #pragma unroll
  for (int i=0;i<2;++i) {
    #pragma unroll
    for (int r=0;r<4;++r) {
      float inv = 1.f / l_st[i][r];
      int row = q0 + w*32 + i*16 + quad*4 + r;
      #pragma unroll
      for (int dt=0; dt<6; ++dt)
        ob[(size_t)row*C_ + h*HD_ + dt*16 + m16] = __float2bfloat16(o_acc[i][dt][r]*inv);
    }
  }
}

// ---- cross-attention over 10 memory tokens, grid (1024, CH), IN PLACE on bf16 q rows ----
__global__ __launch_bounds__(128) void cross_attn_kernel(hbf16* __restrict__ qb,
    const float* __restrict__ kvm, int b0) {
  int row = blockIdx.x;
  int lb = blockIdx.y;
  int b = b0 + lb;
  int tid = threadIdx.x;
  __shared__ float sc[16];
  __shared__ float qs[C_];
  hbf16* qp = qb + ((size_t)lb*HW_ + row)*C_;
  for (int c = tid; c < C_; c += 128) qs[c] = b2f(qp[c]);
  __syncthreads();
  const float scale = 0.10206207261596577f;
  for (int h = 0; h < NH_; ++h) {
    if (tid < 10) {
      const float* kp = kvm + (size_t)(b*10 + tid)*1536 + h*HD_;
      float s = 0.f;
      for (int d = 0; d < HD_; ++d) s += qs[h*HD_+d]*kp[d];
      sc[tid] = s*scale;
    }
    __syncthreads();
    if (tid == 0) {
      float m = -1e30f;
      for (int j=0;j<10;++j) m = fmaxf(m, sc[j]);
      float se = 0.f;
      for (int j=0;j<10;++j){ sc[j]=expf(sc[j]-m); se+=sc[j]; }
      float inv = 1.f/se;
      for (int j=0;j<10;++j) sc[j]*=inv;
    }
    __syncthreads();
    if (tid < HD_) {
      const float* vp = kvm + (size_t)(b*10)*1536 + C_ + h*HD_ + tid;
      float acc = 0.f;
      for (int j=0;j<10;++j) acc += sc[j]*vp[(size_t)j*1536];
      qp[h*HD_+tid] = __float2bfloat16(acc);
    }
    __syncthreads();
  }
}

// ---- tgt init: IN PLACE on pre-transposed mainxT (=tgt): += mq[0] + pos ----
__global__ __launch_bounds__(256) void tgt0_kernel(float* __restrict__ tgt,
    const float* __restrict__ mq, const float* __restrict__ pos) {
  size_t i = ((size_t)blockIdx.x*256 + threadIdx.x)*4;
  if (i >= (size_t)TOK_*C_) return;
  int c = (int)(i % C_);
  int tpos = (int)((i / C_) % HW_);
  float4 v = *(float4*)&tgt[i];
  float4 m = *(const float4*)&mq[c];
  float4 pp = *(const float4*)&pos[(size_t)tpos*C_ + c];
  v.x += m.x + pp.x; v.y += m.y + pp.y;
  v.z += m.z + pp.z; v.w += m.w + pp.w;
  *(float4*)&tgt[i] = v;
}

// ---- residual + layernorm (in place on fp32 tgt rows, bf16 add) ----
__global__ __launch_bounds__(256) void ln_res_kernel(float* __restrict__ tgt, const hbf16* __restrict__ add,
    const float* __restrict__ w, const float* __restrict__ bvec) {
  __shared__ float red[256];
  int row = blockIdx.x, tid = threadIdx.x;
  float* tp = tgt + (size_t)row*C_;
  const hbf16* ap = add + (size_t)row*C_;
  float x[3]; float s = 0.f, s2 = 0.f;
  #pragma unroll
  for (int i=0;i<3;++i){ int c=tid+i*256; float v=tp[c]+b2f(ap[c]); x[i]=v; s+=v; s2+=v*v; }
  s  = block_reduce_sum_256(s,  red);
  s2 = block_reduce_sum_256(s2, red);
  float mean = s * (1.f/C_);
  float var  = s2 * (1.f/C_) - mean*mean;
  float rstd = rsqrtf(var + 1e-5f);
  #pragma unroll
  for (int i=0;i<3;++i){ int c=tid+i*256; tp[c] = (x[i]-mean)*rstd*w[c] + bvec[c]; }
}

extern "C" void kernel_launch(void* const* d_in, const int* in_sizes, int n_in,
                              void* d_out, int out_size, void* d_ws, size_t ws_size,
                              hipStream_t stream) {
  const float* mainx   = (const float*)d_in[0];
  const float* other0  = (const float*)d_in[1];
  const float* other1  = (const float*)d_in[2];
  const float* pos     = (const float*)d_in[3];
  const float* mq      = (const float*)d_in[4];
  const float* s_w1    = (const float*)d_in[5];
  const float* s_b1    = (const float*)d_in[6];
  const float* s_w2    = (const float*)d_in[7];
  const float* sa_in_w = (const float*)d_in[9];
  const float* sa_in_b = (const float*)d_in[10];
  const float* sa_out_w= (const float*)d_in[11];
  const float* sa_out_b= (const float*)d_in[12];
  const float* ca_in_w = (const float*)d_in[13];
  const float* ca_in_b = (const float*)d_in[14];
  const float* ca_out_w= (const float*)d_in[15];
  const float* ca_out_b= (const float*)d_in[16];
  const float* ff1_w   = (const float*)d_in[17];
  const float* ff1_b   = (const float*)d_in[18];
  const float* ff2_w   = (const float*)d_in[19];
  const float* ff2_b   = (const float*)d_in[20];
  const float* ln_w    = (const float*)d_in[21];
  const float* ln_b    = (const float*)d_in[22];
  const float* brand   = (const float*)d_in[23];
  const float* arand   = (const float*)d_in[24];

  // ---- workspace layout ----
  char* p = (char*)d_ws;
  auto alloc = [&](size_t bytes) { char* r = p; p += (bytes + 255) & ~(size_t)255; return (void*)r; };
  float* tgt    = (float*)alloc((size_t)TOK_*C_*4);       // 24 MB; holds mainxT during stage A
  hbf16* wb0    = (hbf16*)alloc((size_t)2359296*2);       // 4.5 MB (transposed weights)
  hbf16* wb1    = (hbf16*)alloc((size_t)2359296*2);       // 4.5 MB
  hbf16* w1t_hi = (hbf16*)alloc((size_t)C_*C_*2);
  hbf16* w1t_lo = (hbf16*)alloc((size_t)C_*C_*2);
  float* kvm    = (float*)alloc((size_t)80*1536*4);
  float* memf   = (float*)alloc((size_t)80*C_*4);
  float* coords = (float*)alloc((size_t)16*NPTS*2*4);
  float* logit  = (float*)alloc((size_t)16*NPTS*4);
  int*   idxb   = (int*)alloc(16*8*4);
  char*  S      = p;
  size_t used = (size_t)(p - (char*)d_ws);
  size_t Savail = (ws_size > used) ? ws_size - used : 0;
  int CH = 1;
  if (Savail >= (size_t)8*1024*9216 + 4096) CH = 8;
  else if (Savail >= (size_t)4*1024*9216 + 4096) CH = 4;
  else if (Savail >= (size_t)2*1024*9216 + 4096) CH = 2;
  const size_t R = (size_t)CH*1024;
  const size_t perG = (size_t)NPTS*C_*2*2;  // pf_hi+pf_lo per instance
  // stage-A scratch: oT (one image set, channel-last) at front of S, pf after
  const size_t oTb = (size_t)B_*HW_*C_*4;   // 25.2 MB, 256-aligned
  float* oT = (float*)S;
  char* Spf = S + oTb;
  size_t SA = (Savail > oTb) ? Savail - oTb : 0;
  int G = 1;
  if (SA >= 8*perG) G = 8;
  else if (SA >= 4*perG) G = 4;
  else if (SA >= 2*perG) G = 2;

  // ---- stage A ----
  // mainx [B][C][HW] -> channel-last in tgt (softalign reads it; tgt0 finishes in place)
  btrans_kernel<<<dim3(HW_/32, C_/32, B_), 256, 0, stream>>>(mainx, tgt, C_, HW_);
  wtrans_split_kernel<<<dim3(C_/32, C_/32), 256, 0, stream>>>(s_w1, w1t_hi, w1t_lo, C_, C_);
  zero_kernel<<<16*NPTS/256, 256, 0, stream>>>(logit, 16*NPTS);
  for (int g0 = 0; g0 < 16; g0 += G) {
    if ((g0 & 7) == 0)
      btrans_kernel<<<dim3(HW_/32, C_/32, B_), 256, 0, stream>>>(g0 < 8 ? other0 : other1,
          oT, C_, HW_);
    hbf16* pf_hi = (hbf16*)Spf;
    hbf16* pf_lo = pf_hi + (size_t)G*NPTS*C_;
    sample_all_kernel<<<dim3(G, NPTS/4), 256, 0, stream>>>(oT, brand,
        pf_hi, pf_lo, coords, g0);
    score_gemm_kernel<<<dim3(6, G*16), 256, 0, stream>>>((const short*)pf_hi, (const short*)pf_lo,
        (const short*)w1t_hi, (const short*)w1t_lo, s_b1, s_w2, logit + (size_t)g0*NPTS);
    topk_all_kernel<<<G, 64, 0, stream>>>(logit + (size_t)g0*NPTS, idxb + g0*8);
    softalign_all_kernel<<<dim3(TOPK_, G), 256, 0, stream>>>(tgt, pos, pf_hi, pf_lo,
        coords, idxb + g0*8, arand, mq, memf, g0);
  }

  // ---- stage B ----
  size_t total = (size_t)TOK_*C_;
  tgt0_kernel<<<(int)((total/4+255)/256), 256, 0, stream>>>(tgt, mq, pos);

  for (int l = 0; l < 2; ++l) {
    // ===== self-attention =====
    wtrans_kernel<<<dim3(3*C_/32, C_/32), 256, 0, stream>>>(sa_in_w + (size_t)l*C_*3*C_, wb0, C_, 3*C_);
    wtrans_kernel<<<dim3(C_/32, C_/32), 256, 0, stream>>>(sa_out_w + (size_t)l*C_*C_, wb1, C_, C_);
    for (int c0 = 0; c0 < B_; c0 += CH) {
      float* tgtc = tgt + (size_t)c0*HW_*C_;
      hbf16* abuf = (hbf16*)S;
      hbf16* qkv  = abuf + R*C_;
      hbf16* oatt = qkv + R*3*C_;
      hbf16* tmpb = oatt + R*C_;
      f2b_kernel<<<(int)((R*C_/4+255)/256), 256, 0, stream>>>(tgtc, abuf, (int)(R*C_));
      gemm_mfma_t<<<dim3(3*C_/128, (int)(R/128)), 256, 0, stream>>>((const short*)abuf, C_,
          (const short*)wb0, C_, sa_in_b + (size_t)l*3*C_, qkv, 3*C_, C_, 0);
      flash_attn_kernel<<<dim3(NH_*CH, HW_/128), 256, 0, stream>>>(qkv, oatt);
      gemm_mfma_t<<<dim3(C_/128, (int)(R/128)), 256, 0, stream>>>((const short*)oatt, C_,
          (const short*)wb1, C_, sa_out_b + (size_t)l*C_, tmpb, C_, C_, 0);
      ln_res_kernel<<<(int)R, 256, 0, stream>>>(tgtc, tmpb,
          ln_w + (size_t)(l*3+0)*C_, ln_b + (size_t)(l*3+0)*C_);
    }

    // ===== cross-attention =====
    wtrans_kernel<<<dim3(C_/32, C_/32), 256, 0, stream>>>(ca_in_w + (size_t)l*C_*3*C_, wb0, C_, 3*C_);
    wtrans_kernel<<<dim3(C_/32, C_/32), 256, 0, stream>>>(ca_out_w + (size_t)l*C_*C_, wb1, C_, C_);
    gemm_kernel<<<dim3((2*C_+BN-1)/BN, (80+BM-1)/BM), 256, 0, stream>>>(memf, C_,
        ca_in_w + (size_t)l*C_*3*C_ + C_, 3*C_, ca_in_b + (size_t)l*3*C_ + C_, kvm, 2*C_,
        80, 2*C_, C_, 0);
    for (int c0 = 0; c0 < B_; c0 += CH) {
      float* tgtc = tgt + (size_t)c0*HW_*C_;
      hbf16* abuf = (hbf16*)S;
      hbf16* qb   = abuf + R*C_;
      hbf16* tmpb = qb + R*C_;
      f2b_kernel<<<(int)((R*C_/4+255)/256), 256, 0, stream>>>(tgtc, abuf, (int)(R*C_));
      gemm_mfma_t<<<dim3(C_/128, (int)(R/128)), 256, 0, stream>>>((const short*)abuf, C_,
          (const short*)wb0, C_, ca_in_b + (size_t)l*3*C_, qb, C_, C_, 0);
      cross_attn_kernel<<<dim3(HW_, CH), 128, 0, stream>>>(qb, kvm, c0);
      gemm_mfma_t<<<dim3(C_/128, (int)(R/128)), 256, 0, stream>>>((const short*)qb, C_,
          (const short*)wb1, C_, ca_out_b + (size_t)l*C_, tmpb, C_, C_, 0);
      ln_res_kernel<<<(int)R, 256, 0, stream>>>(tgtc, tmpb,
          ln_w + (size_t)(l*3+1)*C_, ln_b + (size_t)(l*3+1)*C_);
    }

    // ===== FFN =====
    wtrans_kernel<<<dim3(FF_/32, C_/32), 256, 0, stream>>>(ff1_w + (size_t)l*C_*FF_, wb0, C_, FF_);
    wtrans_kernel<<<dim3(C_/32, FF_/32), 256, 0, stream>>>(ff2_w + (size_t)l*FF_*C_, wb1, FF_, C_);
    for (int c0 = 0; c0 < B_; c0 += CH) {
      float* tgtc = tgt + (size_t)c0*HW_*C_;
      hbf16* abuf = (hbf16*)S;
      hbf16* ffh  = abuf + R*C_;
      hbf16* tmpb = ffh + R*FF_;
      f2b_kernel<<<(int)((R*C_/4+255)/256), 256, 0, stream>>>(tgtc, abuf, (int)(R*C_));
      gemm_mfma_t<<<dim3(FF_/128, (int)(R/128)), 256, 0, stream>>>((const short*)abuf, C_,
          (const short*)wb0, C_, ff1_b + (size_t)l*FF_, ffh, FF_, C_, 1);
      gemm_mfma_t<<<dim3(C_/128, (int)(R/128)), 256, 0, stream>>>((const short*)ffh, FF_,
          (const short*)wb1, FF_, ff2_b + (size_t)l*C_, tmpb, C_, FF_, 0);
      ln_res_kernel<<<(int)R, 256, 0, stream>>>(tgtc, tmpb,
          ln_w + (size_t)(l*3+2)*C_, ln_b + (size_t)(l*3+2)*C_);
    }
  }

  // ---- final: tgt [B][HW][C] -> out [B][C][H][W], LDS-tiled transpose ----
  btrans_kernel<<<dim3(C_/32, HW_/32, B_), 256, 0, stream>>>(tgt, (float*)d_out, HW_, C_);
}

// Round 4
// 1593.901 us; speedup vs baseline: 1.1942x; 1.0181x over previous
//
#include <hip/hip_runtime.h>
#include <hip/hip_bf16.h>
#include <math.h>

typedef __hip_bfloat16 hbf16;

#define B_ 8
#define C_ 768
#define HW_ 1024
#define NH_ 8
#define HD_ 96
#define NPTS 2048      // PH*PW*K
#define AROUND_ 5
#define TOPK_ 5
#define MOD_ 2
#define FF_ 3072
#define TOK_ (B_*HW_)  // 8192

typedef __attribute__((ext_vector_type(8))) short short8v;
typedef __attribute__((ext_vector_type(4))) short short4v;
typedef __attribute__((ext_vector_type(4))) float f32x4;

__device__ __forceinline__ float b2f(hbf16 v){ return __bfloat162float(v); }

// ---- bilinear taps, torch grid_sample semantics (align_corners=False, zeros pad), H=W=32 ----
struct Taps { int x0,x1,y0,y1; float w00,w10,w01,w11; };
__device__ __forceinline__ Taps bilin_taps(float gx, float gy) {
  Taps t;
  float ix = ((gx+1.f)*32.f - 1.f)*0.5f;
  float iy = ((gy+1.f)*32.f - 1.f)*0.5f;
  float x0f = floorf(ix), y0f = floorf(iy);
  float wx1 = ix-x0f, wy1 = iy-y0f, wx0 = 1.f-wx1, wy0 = 1.f-wy1;
  int x0=(int)x0f, y0=(int)y0f, x1=x0+1, y1=y0+1;
  bool vx0=(x0>=0)&&(x0<=31), vx1=(x1>=0)&&(x1<=31);
  bool vy0=(y0>=0)&&(y0<=31), vy1=(y1>=0)&&(y1<=31);
  t.w00 = (vx0&&vy0) ? wx0*wy0 : 0.f;
  t.w10 = (vx1&&vy0) ? wx1*wy0 : 0.f;
  t.w01 = (vx0&&vy1) ? wx0*wy1 : 0.f;
  t.w11 = (vx1&&vy1) ? wx1*wy1 : 0.f;
  t.x0 = min(max(x0,0),31); t.x1 = min(max(x1,0),31);
  t.y0 = min(max(y0,0),31); t.y1 = min(max(y1,0),31);
  return t;
}

__device__ __forceinline__ float block_reduce_sum_256(float v, float* red) {
  int tid = threadIdx.x;
  red[tid] = v; __syncthreads();
  for (int s = 128; s > 0; s >>= 1) { if (tid < s) red[tid] += red[tid+s]; __syncthreads(); }
  float r = red[0]; __syncthreads();
  return r;
}

// ---- fp32 -> bf16 elementwise convert (n multiple of 4) ----
__global__ __launch_bounds__(256) void f2b_kernel(const float* __restrict__ in,
    hbf16* __restrict__ out, int n) {
  int i = (blockIdx.x*256 + threadIdx.x)*4;
  if (i >= n) return;
  float4 v = *(const float4*)&in[i];
  out[i+0] = __float2bfloat16(v.x);
  out[i+1] = __float2bfloat16(v.y);
  out[i+2] = __float2bfloat16(v.z);
  out[i+3] = __float2bfloat16(v.w);
}

// ---- transpose+convert: fp32 in[K][N] -> bf16 out[N][K] (K,N multiples of 32) ----
__global__ __launch_bounds__(256) void wtrans_kernel(const float* __restrict__ in,
    hbf16* __restrict__ out, int K, int N) {
  __shared__ float t[32][33];
  int tx = threadIdx.x & 31, ty = threadIdx.x >> 5;
  int k0 = blockIdx.y*32, n0 = blockIdx.x*32;
  #pragma unroll
  for (int i = 0; i < 32; i += 8) t[ty+i][tx] = in[(size_t)(k0+ty+i)*N + n0+tx];
  __syncthreads();
  #pragma unroll
  for (int i = 0; i < 32; i += 8)
    out[(size_t)(n0+ty+i)*K + k0 + tx] = __float2bfloat16(t[tx][ty+i]);
}

// ---- transpose + split-convert: fp32 in[K][N] -> hi[N][K], lo[N][K] ----
__global__ __launch_bounds__(256) void wtrans_split_kernel(const float* __restrict__ in,
    hbf16* __restrict__ hi, hbf16* __restrict__ lo, int K, int N) {
  __shared__ float t[32][33];
  int tx = threadIdx.x & 31, ty = threadIdx.x >> 5;
  int k0 = blockIdx.y*32, n0 = blockIdx.x*32;
  #pragma unroll
  for (int i = 0; i < 32; i += 8) t[ty+i][tx] = in[(size_t)(k0+ty+i)*N + n0+tx];
  __syncthreads();
  #pragma unroll
  for (int i = 0; i < 32; i += 8) {
    float v = t[tx][ty+i];
    hbf16 h = __float2bfloat16(v);
    hi[(size_t)(n0+ty+i)*K + k0 + tx] = h;
    lo[(size_t)(n0+ty+i)*K + k0 + tx] = __float2bfloat16(v - b2f(h));
  }
}

// ---- batched fp32 transpose: per z, in [R][S] -> out [S][R] (R,S multiples of 32) ----
// grid (S/32, R/32, batch)
__global__ __launch_bounds__(256) void btrans_kernel(const float* __restrict__ in,
    float* __restrict__ out, int R, int S) {
  __shared__ float t[32][33];
  int tx = threadIdx.x & 31, ty = threadIdx.x >> 5;
  int r0 = blockIdx.y*32, s0 = blockIdx.x*32;
  const float* ib = in + (size_t)blockIdx.z*R*S;
  float* ob = out + (size_t)blockIdx.z*R*S;
  #pragma unroll
  for (int i = 0; i < 32; i += 8) t[ty+i][tx] = ib[(size_t)(r0+ty+i)*S + s0+tx];
  __syncthreads();
  #pragma unroll
  for (int i = 0; i < 32; i += 8) ob[(size_t)(s0+ty+i)*R + r0+tx] = t[tx][ty+i];
}

__global__ __launch_bounds__(256) void zero_kernel(float* __restrict__ p, int n) {
  int i = blockIdx.x*256 + threadIdx.x;
  if (i < n) p[i] = 0.f;
}

// ---- stage A: blockwise sample from CHANNEL-LAST image oT [B][HW][C] ----
// grid (G, NPTS/4): blockIdx.x = instance (XCD-pinned), 4 points per block.
__global__ __launch_bounds__(256) void sample_all_kernel(const float* __restrict__ oT,
    const float* __restrict__ brand, hbf16* __restrict__ pf_hi, hbf16* __restrict__ pf_lo,
    float* __restrict__ coords_all, int g0) {
  int ly = blockIdx.x;
  int inst = g0 + ly;
  int b = inst & 7;
  const float* xT = oT + (size_t)b*HW_*C_;
  int tid = threadIdx.x;
  int p = tid >> 6, lane = tid & 63;
  int n = blockIdx.y*4 + p;
  int k = n & 1, pw = (n >> 1) & 31, ph = n >> 6;
  const float* br = brand + (size_t)inst*4096;
  int roff = ((ph*32 + pw)*2 + k)*2;
  float r0 = br[roff], r1 = br[roff+1];
  const float bs = 0.0625f;
  float c0 = r0*bs + ((float)ph*bs - 1.0f);
  float c1 = r1*bs + ((float)pw*bs - 1.0f);
  Taps t = bilin_taps(c0, c1);
  const float* r00 = xT + (size_t)(t.y0*32+t.x0)*C_;
  const float* r10 = xT + (size_t)(t.y0*32+t.x1)*C_;
  const float* r01 = xT + (size_t)(t.y1*32+t.x0)*C_;
  const float* r11 = xT + (size_t)(t.y1*32+t.x1)*C_;
  size_t base = ((size_t)ly*NPTS + n)*C_;
  short* ph_ = (short*)pf_hi;
  short* pl_ = (short*)pf_lo;
  #pragma unroll
  for (int kk = 0; kk < 3; ++kk) {
    int c = kk*256 + lane*4;
    float4 v00 = *(const float4*)(r00 + c);
    float4 v10 = *(const float4*)(r10 + c);
    float4 v01 = *(const float4*)(r01 + c);
    float4 v11 = *(const float4*)(r11 + c);
    float o[4];
    o[0] = t.w00*v00.x + t.w10*v10.x + t.w01*v01.x + t.w11*v11.x;
    o[1] = t.w00*v00.y + t.w10*v10.y + t.w01*v01.y + t.w11*v11.y;
    o[2] = t.w00*v00.z + t.w10*v10.z + t.w01*v01.z + t.w11*v11.z;
    o[3] = t.w00*v00.w + t.w10*v10.w + t.w01*v01.w + t.w11*v11.w;
    short4v hs, ls;
    #pragma unroll
    for (int e = 0; e < 4; ++e) {
      hbf16 h = __float2bfloat16(o[e]);
      hs[e] = *(short*)&h;
      hbf16 l = __float2bfloat16(o[e] - b2f(h));
      ls[e] = *(short*)&l;
    }
    *(short4v*)&ph_[base + c] = hs;
    *(short4v*)&pl_[base + c] = ls;
  }
  if (lane == 0) {
    size_t co = ((size_t)inst*NPTS + n)*2;
    coords_all[co] = c0; coords_all[co+1] = c1;
  }
}

// ---- fused score GEMM (split-bf16, 3-term) + relu + w2-dot -> atomicAdd logits ----
__global__ __launch_bounds__(256) void score_gemm_kernel(const short* __restrict__ Ahi,
    const short* __restrict__ Alo, const short* __restrict__ Bhi, const short* __restrict__ Blo,
    const float* __restrict__ b1, const float* __restrict__ w2, float* __restrict__ logit) {
  __shared__ short AsH[128*40];
  __shared__ short AsL[128*40];
  __shared__ short BsH[128*40];
  __shared__ short BsL[128*40];
  int tid = threadIdx.x;
  int lane = tid & 63, w = tid >> 6;
  int wr = (w >> 1) * 64, wc = (w & 1) * 64;
  int m16 = lane & 15, quad = lane >> 4, q8 = quad * 8;
  int bm = blockIdx.y * 128, bn = blockIdx.x * 128;
  int ar = tid >> 2, ac = (tid & 3) * 8;
  f32x4 acc[4][4] = {};
  for (int k0 = 0; k0 < 768; k0 += 32) {
    *(short8v*)&AsH[ar*40 + ac]      = *(const short8v*)&Ahi[(size_t)(bm+ar)*768 + k0 + ac];
    *(short8v*)&AsH[(ar+64)*40 + ac] = *(const short8v*)&Ahi[(size_t)(bm+ar+64)*768 + k0 + ac];
    *(short8v*)&AsL[ar*40 + ac]      = *(const short8v*)&Alo[(size_t)(bm+ar)*768 + k0 + ac];
    *(short8v*)&AsL[(ar+64)*40 + ac] = *(const short8v*)&Alo[(size_t)(bm+ar+64)*768 + k0 + ac];
    *(short8v*)&BsH[ar*40 + ac]      = *(const short8v*)&Bhi[(size_t)(bn+ar)*768 + k0 + ac];
    *(short8v*)&BsH[(ar+64)*40 + ac] = *(const short8v*)&Bhi[(size_t)(bn+ar+64)*768 + k0 + ac];
    *(short8v*)&BsL[ar*40 + ac]      = *(const short8v*)&Blo[(size_t)(bn+ar)*768 + k0 + ac];
    *(short8v*)&BsL[(ar+64)*40 + ac] = *(const short8v*)&Blo[(size_t)(bn+ar+64)*768 + k0 + ac];
    __syncthreads();
    short8v ah[4], al[4], bh[4], bl[4];
    #pragma unroll
    for (int i=0;i<4;++i) {
      ah[i] = *(const short8v*)&AsH[(wr + i*16 + m16)*40 + q8];
      al[i] = *(const short8v*)&AsL[(wr + i*16 + m16)*40 + q8];
      bh[i] = *(const short8v*)&BsH[(wc + i*16 + m16)*40 + q8];
      bl[i] = *(const short8v*)&BsL[(wc + i*16 + m16)*40 + q8];
    }
    #pragma unroll
    for (int i=0;i<4;++i)
      #pragma unroll
      for (int j=0;j<4;++j) {
        acc[i][j] = __builtin_amdgcn_mfma_f32_16x16x32_bf16(ah[i], bh[j], acc[i][j], 0, 0, 0);
        acc[i][j] = __builtin_amdgcn_mfma_f32_16x16x32_bf16(ah[i], bl[j], acc[i][j], 0, 0, 0);
        acc[i][j] = __builtin_amdgcn_mfma_f32_16x16x32_bf16(al[i], bh[j], acc[i][j], 0, 0, 0);
      }
    __syncthreads();
  }
  float b1v[4], w2v[4];
  #pragma unroll
  for (int j=0;j<4;++j) {
    int col = bn + wc + j*16 + m16;
    b1v[j] = b1[col]; w2v[j] = w2[col];
  }
  #pragma unroll
  for (int i=0;i<4;++i) {
    #pragma unroll
    for (int r=0;r<4;++r) {
      float v = 0.f;
      #pragma unroll
      for (int j=0;j<4;++j) {
        float h = fmaxf(acc[i][j][r] + b1v[j], 0.f);
        v += h * w2v[j];
      }
      v += __shfl_xor(v, 1); v += __shfl_xor(v, 2);
      v += __shfl_xor(v, 4); v += __shfl_xor(v, 8);
      if (m16 == 0) atomicAdd(&logit[bm + wr + i*16 + quad*4 + r], v);
    }
  }
}

// ---- top-5 of 2048 per instance (on logits; sigmoid monotone), jax tie semantics ----
__global__ void topk_all_kernel(const float* __restrict__ logit, int* __restrict__ idx) {
  int lane = threadIdx.x;   // 64 lanes
  const float* score = logit + (size_t)blockIdx.x*NPTS;
  float v[32];
  #pragma unroll
  for (int i = 0; i < 32; ++i) v[i] = score[(i<<6) | lane];
  for (int t = 0; t < TOPK_; ++t) {
    float bv = v[0]; int bi = lane;
    #pragma unroll
    for (int i = 1; i < 32; ++i) { if (v[i] > bv) { bv = v[i]; bi = (i<<6)|lane; } }
    for (int off = 32; off; off >>= 1) {
      float ov = __shfl_xor(bv, off);
      int   oi = __shfl_xor(bi, off);
      if (ov > bv || (ov == bv && oi < bi)) { bv = ov; bi = oi; }
    }
    if (lane == 0) idx[blockIdx.x*8 + t] = bi;
    if ((bi & 63) == lane) v[bi >> 6] = -1e30f;
  }
}

// ---- soft_align + modality query -> memf rows; grid (TOPK, G) ----
// mainxT is channel-last [B][HW][C] (the tgt buffer, pre-tgt0)
__global__ __launch_bounds__(256) void softalign_all_kernel(const float* __restrict__ mainxT,
    const float* __restrict__ pos, const hbf16* __restrict__ pf_hi, const hbf16* __restrict__ pf_lo,
    const float* __restrict__ coords_all, const int* __restrict__ idx_all,
    const float* __restrict__ arand, const float* __restrict__ mq,
    float* __restrict__ memf, int g0) {
  int t = blockIdx.x;
  int ly = blockIdx.y;
  int inst = g0 + ly;
  int mod = inst >> 3, b = inst & 7;
  const float* mT_b = mainxT + (size_t)b*HW_*C_;
  const float* arand_ib = arand + (size_t)inst*AROUND_*TOPK_*2;
  const float* coords = coords_all + (size_t)inst*NPTS*2;
  int tid = threadIdx.x;
  int n = idx_all[ly*8 + t];
  float px0 = coords[n*2], px1 = coords[n*2+1];
  size_t pfb = ((size_t)ly*NPTS + n)*C_;
  float pfv[3];
  #pragma unroll
  for (int i=0;i<3;++i) {
    int c = tid + i*256;
    pfv[i] = b2f(pf_hi[pfb + c]) + b2f(pf_lo[pfb + c]);
  }
  __shared__ float red[256];
  float pp = block_reduce_sum_256(pfv[0]*pfv[0]+pfv[1]*pfv[1]+pfv[2]*pfv[2], red);
  float embr[AROUND_][3];
  float num_a[AROUND_], aa_a[AROUND_];
  for (int a=0; a<AROUND_; ++a) {
    int ar = (a*TOPK_ + t)*2;
    float g0c = px0 + (arand_ib[ar]*2.f - 0.5f)*0.2f;
    float g1c = px1 + (arand_ib[ar+1]*2.f - 0.5f)*0.2f;
    g0c = fminf(fmaxf(g0c,-1.f),1.f);
    g1c = fminf(fmaxf(g1c,-1.f),1.f);
    Taps tp = bilin_taps(g0c, g1c);
    int i00=tp.y0*32+tp.x0, i10=tp.y0*32+tp.x1, i01=tp.y1*32+tp.x0, i11=tp.y1*32+tp.x1;
    float s_num = 0.f, s_aa = 0.f;
    #pragma unroll
    for (int i=0;i<3;++i) {
      int c = tid + i*256;
      float af = tp.w00*mT_b[(size_t)i00*C_+c] + tp.w10*mT_b[(size_t)i10*C_+c]
               + tp.w01*mT_b[(size_t)i01*C_+c] + tp.w11*mT_b[(size_t)i11*C_+c];
      float em = tp.w00*pos[(size_t)i00*C_+c] + tp.w10*pos[(size_t)i10*C_+c]
               + tp.w01*pos[(size_t)i01*C_+c] + tp.w11*pos[(size_t)i11*C_+c];
      embr[a][i] = em;
      s_num += pfv[i]*af;
      s_aa  += af*af;
    }
    num_a[a] = block_reduce_sum_256(s_num, red);
    aa_a[a]  = block_reduce_sum_256(s_aa, red);
  }
  float pn = fmaxf(sqrtf(pp), 1e-8f);
  float w[AROUND_]; float mx = -1e30f;
  #pragma unroll
  for (int a=0;a<AROUND_;++a){ float den = pn * fmaxf(sqrtf(aa_a[a]),1e-8f); w[a]=num_a[a]/den; mx=fmaxf(mx,w[a]); }
  float se = 0.f;
  #pragma unroll
  for (int a=0;a<AROUND_;++a){ w[a]=expf(w[a]-mx); se+=w[a]; }
  float inv = 1.f/se;
  float* mo = memf + ((size_t)b*(MOD_*TOPK_) + mod*TOPK_ + t)*C_;
  #pragma unroll
  for (int i=0;i<3;++i) {
    int c = tid + i*256;
    float o = pfv[i];
    #pragma unroll
    for (int a=0;a<AROUND_;++a) o += embr[a][i]*(w[a]*inv);
    o += mq[(size_t)(mod+1)*C_ + c];
    mo[c] = o;
  }
}

// ---- generic fp32 GEMM (kvm only) ----
#define BM 64
#define BN 64
#define BK 16
__global__ __launch_bounds__(256) void gemm_kernel(const float* __restrict__ A, int lda,
    const float* __restrict__ Bw, int ldb, const float* __restrict__ bias,
    float* __restrict__ Cm, int ldc, int M, int N, int K, int act) {
  __shared__ float As[BK][BM];
  __shared__ float Bs[BK][BN];
  int tid = threadIdx.x;
  int bm = blockIdx.y * BM, bn = blockIdx.x * BN;
  int arw = tid >> 2, acl = (tid & 3) << 2;
  int brw = tid >> 4, bcl = (tid & 15) << 2;
  int ty = tid >> 4, tx = tid & 15;
  float acc[4][4] = {{0.f}};
  for (int k0 = 0; k0 < K; k0 += BK) {
    float a0=0.f,a1=0.f,a2=0.f,a3=0.f;
    if (bm + arw < M) {
      const float* ap = A + (size_t)(bm+arw)*lda + k0 + acl;
      a0=ap[0]; a1=ap[1]; a2=ap[2]; a3=ap[3];
    }
    As[acl+0][arw]=a0; As[acl+1][arw]=a1; As[acl+2][arw]=a2; As[acl+3][arw]=a3;
    const float* bp = Bw + (size_t)(k0+brw)*ldb + bn + bcl;
    Bs[brw][bcl+0]=bp[0]; Bs[brw][bcl+1]=bp[1]; Bs[brw][bcl+2]=bp[2]; Bs[brw][bcl+3]=bp[3];
    __syncthreads();
    #pragma unroll
    for (int kk = 0; kk < BK; ++kk) {
      float4 av = *reinterpret_cast<const float4*>(&As[kk][ty<<2]);
      float4 bv = *reinterpret_cast<const float4*>(&Bs[kk][tx<<2]);
      acc[0][0]+=av.x*bv.x; acc[0][1]+=av.x*bv.y; acc[0][2]+=av.x*bv.z; acc[0][3]+=av.x*bv.w;
      acc[1][0]+=av.y*bv.x; acc[1][1]+=av.y*bv.y; acc[1][2]+=av.y*bv.z; acc[1][3]+=av.y*bv.w;
      acc[2][0]+=av.z*bv.x; acc[2][1]+=av.z*bv.y; acc[2][2]+=av.z*bv.z; acc[2][3]+=av.z*bv.w;
      acc[3][0]+=av.w*bv.x; acc[3][1]+=av.w*bv.y; acc[3][2]+=av.w*bv.z; acc[3][3]+=av.w*bv.w;
    }
    __syncthreads();
  }
  #pragma unroll
  for (int i=0;i<4;++i) {
    int r = bm + (ty<<2) + i;
    if (r >= M) continue;
    float* cp = Cm + (size_t)r*ldc + bn + (tx<<2);
    #pragma unroll
    for (int j=0;j<4;++j) {
      float v = acc[i][j] + bias[bn + (tx<<2) + j];
      if (act) v = fmaxf(v, 0.f);
      cp[j] = v;
    }
  }
}

// ---- bf16 MFMA GEMM, B pre-transposed: C = act(A[M,K] @ Bt[N,K]^T + bias) ----
__global__ __launch_bounds__(256) void gemm_mfma_t(const short* __restrict__ A, int lda,
    const short* __restrict__ Bt, int ldbt, const float* __restrict__ bias,
    hbf16* __restrict__ Cm, int ldc, int K, int act) {
  __shared__ short As[128*40];
  __shared__ short Bs[128*40];
  int tid = threadIdx.x;
  int lane = tid & 63, w = tid >> 6;
  int wr = (w >> 1) * 64, wc = (w & 1) * 64;
  int m16 = lane & 15, q8 = (lane >> 4) * 8;
  int bm = blockIdx.y * 128, bn = blockIdx.x * 128;
  int ar = tid >> 2, ac = (tid & 3) * 8;
  f32x4 acc[4][4] = {};
  for (int k0 = 0; k0 < K; k0 += 32) {
    *(short8v*)&As[ar*40 + ac]      = *(const short8v*)&A[(size_t)(bm+ar)*lda + k0 + ac];
    *(short8v*)&As[(ar+64)*40 + ac] = *(const short8v*)&A[(size_t)(bm+ar+64)*lda + k0 + ac];
    *(short8v*)&Bs[ar*40 + ac]      = *(const short8v*)&Bt[(size_t)(bn+ar)*ldbt + k0 + ac];
    *(short8v*)&Bs[(ar+64)*40 + ac] = *(const short8v*)&Bt[(size_t)(bn+ar+64)*ldbt + k0 + ac];
    __syncthreads();
    short8v af[4], bf[4];
    #pragma unroll
    for (int i=0;i<4;++i) af[i] = *(const short8v*)&As[(wr + i*16 + m16)*40 + q8];
    #pragma unroll
    for (int j=0;j<4;++j) bf[j] = *(const short8v*)&Bs[(wc + j*16 + m16)*40 + q8];
    #pragma unroll
    for (int i=0;i<4;++i)
      #pragma unroll
      for (int j=0;j<4;++j)
        acc[i][j] = __builtin_amdgcn_mfma_f32_16x16x32_bf16(af[i], bf[j], acc[i][j], 0, 0, 0);
    __syncthreads();
  }
  #pragma unroll
  for (int j=0;j<4;++j) {
    int col = bn + wc + j*16 + m16;
    float bs = bias[col];
    #pragma unroll
    for (int i=0;i<4;++i) {
      int row0 = bm + wr + i*16 + (lane>>4)*4;
      #pragma unroll
      for (int r=0;r<4;++r) {
        float v = acc[i][j][r] + bs;
        if (act) v = fmaxf(v, 0.f);
        Cm[(size_t)(row0+r)*ldc + col] = __float2bfloat16(v);
      }
    }
  }
}

// ---- fused flash self-attention (MFMA): grid (head+batch, qtile=8), 512 thr / 8 waves ----
// x = h + NH_*bz so all q-tiles of one (b,h) share an XCD (ids congruent mod 8).
// 8 waves x 16 q-rows each; Q fragments in registers; LDS = KP ∪ Vt (32.3 KB).
// Grid 512 blocks x 8 waves = 4096 waves = 16 waves/CU (2 blocks/CU).
__global__ __launch_bounds__(512, 4) void flash_attn_kernel(const hbf16* __restrict__ qkv_all,
    hbf16* __restrict__ o_all) {
  const int hb = blockIdx.x;
  const int h  = hb & 7;
  const int bz = hb >> 3;
  const int q0 = blockIdx.y * 128;
  const short* qkv = (const short*)(qkv_all + (size_t)bz*HW_*2304);
  hbf16* ob = o_all + (size_t)bz*HW_*C_;
  const int tid = threadIdx.x;
  const int lane = tid & 63, w = tid >> 6;
  const int m16 = lane & 15, quad = lane >> 4, q8 = quad * 8;
  const float scale = 0.10206207261596577f;  // 1/sqrt(96)

  // 16128 shorts = 32256 B. KP = lds[0..9216): K tile [64][104] (QK) / P [128][72] (PV).
  // Vt = lds[9216..16128): V^T [96][72]. Q staging [128][104]=13312 aliases both.
  __shared__ short lds[16128];
  short* KP = lds;
  short* Vt = lds + 9216;

  // stage Q -> LDS (coalesced), then hoist this wave's 16-row fragments to registers
  for (int idx = tid; idx < 128*12; idx += 512) {
    int row = idx / 12, dc = idx % 12;
    *(short8v*)&lds[row*104 + dc*8] = *(const short8v*)&qkv[(size_t)(q0+row)*2304 + h*HD_ + dc*8];
  }
  __syncthreads();
  short8v qf[3];
  #pragma unroll
  for (int kkk=0;kkk<3;++kkk)
    qf[kkk] = *(const short8v*)&lds[(w*16 + m16)*104 + q8 + kkk*32];
  __syncthreads();

  float m_st[4], l_st[4];
  f32x4 o_acc[6] = {};
  #pragma unroll
  for (int r=0;r<4;++r){ m_st[r] = -1e30f; l_st[r] = 0.f; }

  for (int t = 0; t < 16; ++t) {
    int j0 = t * 64;
    for (int idx = tid; idx < 64*12; idx += 512) {
      int row = idx / 12, dc = idx % 12;
      *(short8v*)&KP[row*104 + dc*8] = *(const short8v*)&qkv[(size_t)(j0+row)*2304 + C_ + h*HD_ + dc*8];
    }
    // V^T stage: j fast within wave -> conflict-free LDS writes
    for (int idx = tid; idx < 64*12; idx += 512) {
      int j = idx & 63, dc = idx >> 6;
      short8v v = *(const short8v*)&qkv[(size_t)(j0+j)*2304 + 2*C_ + h*HD_ + dc*8];
      #pragma unroll
      for (int s = 0; s < 8; ++s) Vt[(dc*8+s)*72 + j] = v[s];
    }
    __syncthreads();

    f32x4 accs[4] = {};
    #pragma unroll
    for (int kkk = 0; kkk < 3; ++kkk) {
      int kk = kkk*32;
      short8v bf[4];
      #pragma unroll
      for (int n=0;n<4;++n) bf[n] = *(const short8v*)&KP[(n*16 + m16)*104 + q8 + kk];
      #pragma unroll
      for (int n=0;n<4;++n)
        accs[n] = __builtin_amdgcn_mfma_f32_16x16x32_bf16(qf[kkk], bf[n], accs[n], 0, 0, 0);
    }
    __syncthreads();

    #pragma unroll
    for (int r=0;r<4;++r) {
      float mx = -1e30f;
      #pragma unroll
      for (int n=0;n<4;++n) mx = fmaxf(mx, accs[n][r]*scale);
      #pragma unroll
      for (int off=1; off<16; off<<=1) mx = fmaxf(mx, __shfl_xor(mx, off));
      float m_new = fmaxf(m_st[r], mx);
      float alpha = __expf(m_st[r] - m_new);
      float psum = 0.f;
      int prow = (w*16 + quad*4 + r)*72 + m16;
      #pragma unroll
      for (int n=0;n<4;++n) {
        float pv = __expf(accs[n][r]*scale - m_new);
        psum += pv;
        *(hbf16*)&KP[prow + n*16] = __float2bfloat16(pv);
      }
      #pragma unroll
      for (int off=1; off<16; off<<=1) psum += __shfl_xor(psum, off);
      l_st[r] = l_st[r]*alpha + psum;
      m_st[r] = m_new;
      #pragma unroll
      for (int dt=0; dt<6; ++dt) o_acc[dt][r] *= alpha;
    }

    #pragma unroll
    for (int k0 = 0; k0 < 64; k0 += 32) {
      short8v pf_, vf[6];
      pf_ = *(const short8v*)&KP[(w*16 + m16)*72 + q8 + k0];
      #pragma unroll
      for (int dt=0; dt<6; ++dt) vf[dt] = *(const short8v*)&Vt[(dt*16 + m16)*72 + q8 + k0];
      #pragma unroll
      for (int dt=0; dt<6; ++dt)
        o_acc[dt] = __builtin_amdgcn_mfma_f32_16x16x32_bf16(pf_, vf[dt], o_acc[dt], 0, 0, 0);
    }
    __syncthreads();
  }

  #pragma unroll
  for (int r=0;r<4;++r) {
    float inv = 1.f / l_st[r];
    int row = q0 + w*16 + quad*4 + r;
    #pragma unroll
    for (int dt=0; dt<6; ++dt)
      ob[(size_t)row*C_ + h*HD_ + dt*16 + m16] = __float2bfloat16(o_acc[dt][r]*inv);
  }
}

// ---- cross-attention over 10 memory tokens, grid (1024, CH), IN PLACE on bf16 q rows ----
__global__ __launch_bounds__(128) void cross_attn_kernel(hbf16* __restrict__ qb,
    const float* __restrict__ kvm, int b0) {
  int row = blockIdx.x;
  int lb = blockIdx.y;
  int b = b0 + lb;
  int tid = threadIdx.x;
  __shared__ float sc[16];
  __shared__ float qs[C_];
  hbf16* qp = qb + ((size_t)lb*HW_ + row)*C_;
  for (int c = tid; c < C_; c += 128) qs[c] = b2f(qp[c]);
  __syncthreads();
  const float scale = 0.10206207261596577f;
  for (int h = 0; h < NH_; ++h) {
    if (tid < 10) {
      const float* kp = kvm + (size_t)(b*10 + tid)*1536 + h*HD_;
      float s = 0.f;
      for (int d = 0; d < HD_; ++d) s += qs[h*HD_+d]*kp[d];
      sc[tid] = s*scale;
    }
    __syncthreads();
    if (tid == 0) {
      float m = -1e30f;
      for (int j=0;j<10;++j) m = fmaxf(m, sc[j]);
      float se = 0.f;
      for (int j=0;j<10;++j){ sc[j]=expf(sc[j]-m); se+=sc[j]; }
      float inv = 1.f/se;
      for (int j=0;j<10;++j) sc[j]*=inv;
    }
    __syncthreads();
    if (tid < HD_) {
      const float* vp = kvm + (size_t)(b*10)*1536 + C_ + h*HD_ + tid;
      float acc = 0.f;
      for (int j=0;j<10;++j) acc += sc[j]*vp[(size_t)j*1536];
      qp[h*HD_+tid] = __float2bfloat16(acc);
    }
    __syncthreads();
  }
}

// ---- tgt init: IN PLACE on pre-transposed mainxT (=tgt): += mq[0] + pos ----
__global__ __launch_bounds__(256) void tgt0_kernel(float* __restrict__ tgt,
    const float* __restrict__ mq, const float* __restrict__ pos) {
  size_t i = ((size_t)blockIdx.x*256 + threadIdx.x)*4;
  if (i >= (size_t)TOK_*C_) return;
  int c = (int)(i % C_);
  int tpos = (int)((i / C_) % HW_);
  float4 v = *(float4*)&tgt[i];
  float4 m = *(const float4*)&mq[c];
  float4 pp = *(const float4*)&pos[(size_t)tpos*C_ + c];
  v.x += m.x + pp.x; v.y += m.y + pp.y;
  v.z += m.z + pp.z; v.w += m.w + pp.w;
  *(float4*)&tgt[i] = v;
}

// ---- residual + layernorm (in place on fp32 tgt rows, bf16 add) ----
__global__ __launch_bounds__(256) void ln_res_kernel(float* __restrict__ tgt, const hbf16* __restrict__ add,
    const float* __restrict__ w, const float* __restrict__ bvec) {
  __shared__ float red[256];
  int row = blockIdx.x, tid = threadIdx.x;
  float* tp = tgt + (size_t)row*C_;
  const hbf16* ap = add + (size_t)row*C_;
  float x[3]; float s = 0.f, s2 = 0.f;
  #pragma unroll
  for (int i=0;i<3;++i){ int c=tid+i*256; float v=tp[c]+b2f(ap[c]); x[i]=v; s+=v; s2+=v*v; }
  s  = block_reduce_sum_256(s,  red);
  s2 = block_reduce_sum_256(s2, red);
  float mean = s * (1.f/C_);
  float var  = s2 * (1.f/C_) - mean*mean;
  float rstd = rsqrtf(var + 1e-5f);
  #pragma unroll
  for (int i=0;i<3;++i){ int c=tid+i*256; tp[c] = (x[i]-mean)*rstd*w[c] + bvec[c]; }
}

extern "C" void kernel_launch(void* const* d_in, const int* in_sizes, int n_in,
                              void* d_out, int out_size, void* d_ws, size_t ws_size,
                              hipStream_t stream) {
  const float* mainx   = (const float*)d_in[0];
  const float* other0  = (const float*)d_in[1];
  const float* other1  = (const float*)d_in[2];
  const float* pos     = (const float*)d_in[3];
  const float* mq      = (const float*)d_in[4];
  const float* s_w1    = (const float*)d_in[5];
  const float* s_b1    = (const float*)d_in[6];
  const float* s_w2    = (const float*)d_in[7];
  const float* sa_in_w = (const float*)d_in[9];
  const float* sa_in_b = (const float*)d_in[10];
  const float* sa_out_w= (const float*)d_in[11];
  const float* sa_out_b= (const float*)d_in[12];
  const float* ca_in_w = (const float*)d_in[13];
  const float* ca_in_b = (const float*)d_in[14];
  const float* ca_out_w= (const float*)d_in[15];
  const float* ca_out_b= (const float*)d_in[16];
  const float* ff1_w   = (const float*)d_in[17];
  const float* ff1_b   = (const float*)d_in[18];
  const float* ff2_w   = (const float*)d_in[19];
  const float* ff2_b   = (const float*)d_in[20];
  const float* ln_w    = (const float*)d_in[21];
  const float* ln_b    = (const float*)d_in[22];
  const float* brand   = (const float*)d_in[23];
  const float* arand   = (const float*)d_in[24];

  // ---- workspace layout ----
  char* p = (char*)d_ws;
  auto alloc = [&](size_t bytes) { char* r = p; p += (bytes + 255) & ~(size_t)255; return (void*)r; };
  float* tgt    = (float*)alloc((size_t)TOK_*C_*4);       // 24 MB; holds mainxT during stage A
  hbf16* wb0    = (hbf16*)alloc((size_t)2359296*2);       // 4.5 MB (transposed weights)
  hbf16* wb1    = (hbf16*)alloc((size_t)2359296*2);       // 4.5 MB
  hbf16* w1t_hi = (hbf16*)alloc((size_t)C_*C_*2);
  hbf16* w1t_lo = (hbf16*)alloc((size_t)C_*C_*2);
  float* kvm    = (float*)alloc((size_t)80*1536*4);
  float* memf   = (float*)alloc((size_t)80*C_*4);
  float* coords = (float*)alloc((size_t)16*NPTS*2*4);
  float* logit  = (float*)alloc((size_t)16*NPTS*4);
  int*   idxb   = (int*)alloc(16*8*4);
  char*  S      = p;
  size_t used = (size_t)(p - (char*)d_ws);
  size_t Savail = (ws_size > used) ? ws_size - used : 0;
  int CH = 1;
  if (Savail >= (size_t)8*1024*9216 + 4096) CH = 8;
  else if (Savail >= (size_t)4*1024*9216 + 4096) CH = 4;
  else if (Savail >= (size_t)2*1024*9216 + 4096) CH = 2;
  const size_t R = (size_t)CH*1024;
  const size_t perG = (size_t)NPTS*C_*2*2;  // pf_hi+pf_lo per instance
  // stage-A scratch: oT (one image set, channel-last) at front of S, pf after
  const size_t oTb = (size_t)B_*HW_*C_*4;   // 25.2 MB, 256-aligned
  float* oT = (float*)S;
  char* Spf = S + oTb;
  size_t SA = (Savail > oTb) ? Savail - oTb : 0;
  int G = 1;
  if (SA >= 8*perG) G = 8;
  else if (SA >= 4*perG) G = 4;
  else if (SA >= 2*perG) G = 2;

  // ---- stage A ----
  // mainx [B][C][HW] -> channel-last in tgt (softalign reads it; tgt0 finishes in place)
  btrans_kernel<<<dim3(HW_/32, C_/32, B_), 256, 0, stream>>>(mainx, tgt, C_, HW_);
  wtrans_split_kernel<<<dim3(C_/32, C_/32), 256, 0, stream>>>(s_w1, w1t_hi, w1t_lo, C_, C_);
  zero_kernel<<<16*NPTS/256, 256, 0, stream>>>(logit, 16*NPTS);
  for (int g0 = 0; g0 < 16; g0 += G) {
    if ((g0 & 7) == 0)
      btrans_kernel<<<dim3(HW_/32, C_/32, B_), 256, 0, stream>>>(g0 < 8 ? other0 : other1,
          oT, C_, HW_);
    hbf16* pf_hi = (hbf16*)Spf;
    hbf16* pf_lo = pf_hi + (size_t)G*NPTS*C_;
    sample_all_kernel<<<dim3(G, NPTS/4), 256, 0, stream>>>(oT, brand,
        pf_hi, pf_lo, coords, g0);
    score_gemm_kernel<<<dim3(6, G*16), 256, 0, stream>>>((const short*)pf_hi, (const short*)pf_lo,
        (const short*)w1t_hi, (const short*)w1t_lo, s_b1, s_w2, logit + (size_t)g0*NPTS);
    topk_all_kernel<<<G, 64, 0, stream>>>(logit + (size_t)g0*NPTS, idxb + g0*8);
    softalign_all_kernel<<<dim3(TOPK_, G), 256, 0, stream>>>(tgt, pos, pf_hi, pf_lo,
        coords, idxb + g0*8, arand, mq, memf, g0);
  }

  // ---- stage B ----
  size_t total = (size_t)TOK_*C_;
  tgt0_kernel<<<(int)((total/4+255)/256), 256, 0, stream>>>(tgt, mq, pos);

  for (int l = 0; l < 2; ++l) {
    // ===== self-attention =====
    wtrans_kernel<<<dim3(3*C_/32, C_/32), 256, 0, stream>>>(sa_in_w + (size_t)l*C_*3*C_, wb0, C_, 3*C_);
    wtrans_kernel<<<dim3(C_/32, C_/32), 256, 0, stream>>>(sa_out_w + (size_t)l*C_*C_, wb1, C_, C_);
    for (int c0 = 0; c0 < B_; c0 += CH) {
      float* tgtc = tgt + (size_t)c0*HW_*C_;
      hbf16* abuf = (hbf16*)S;
      hbf16* qkv  = abuf + R*C_;
      hbf16* oatt = qkv + R*3*C_;
      hbf16* tmpb = oatt + R*C_;
      f2b_kernel<<<(int)((R*C_/4+255)/256), 256, 0, stream>>>(tgtc, abuf, (int)(R*C_));
      gemm_mfma_t<<<dim3(3*C_/128, (int)(R/128)), 256, 0, stream>>>((const short*)abuf, C_,
          (const short*)wb0, C_, sa_in_b + (size_t)l*3*C_, qkv, 3*C_, C_, 0);
      flash_attn_kernel<<<dim3(NH_*CH, HW_/128), 512, 0, stream>>>(qkv, oatt);
      gemm_mfma_t<<<dim3(C_/128, (int)(R/128)), 256, 0, stream>>>((const short*)oatt, C_,
          (const short*)wb1, C_, sa_out_b + (size_t)l*C_, tmpb, C_, C_, 0);
      ln_res_kernel<<<(int)R, 256, 0, stream>>>(tgtc, tmpb,
          ln_w + (size_t)(l*3+0)*C_, ln_b + (size_t)(l*3+0)*C_);
    }

    // ===== cross-attention =====
    wtrans_kernel<<<dim3(C_/32, C_/32), 256, 0, stream>>>(ca_in_w + (size_t)l*C_*3*C_, wb0, C_, 3*C_);
    wtrans_kernel<<<dim3(C_/32, C_/32), 256, 0, stream>>>(ca_out_w + (size_t)l*C_*C_, wb1, C_, C_);
    gemm_kernel<<<dim3((2*C_+BN-1)/BN, (80+BM-1)/BM), 256, 0, stream>>>(memf, C_,
        ca_in_w + (size_t)l*C_*3*C_ + C_, 3*C_, ca_in_b + (size_t)l*3*C_ + C_, kvm, 2*C_,
        80, 2*C_, C_, 0);
    for (int c0 = 0; c0 < B_; c0 += CH) {
      float* tgtc = tgt + (size_t)c0*HW_*C_;
      hbf16* abuf = (hbf16*)S;
      hbf16* qb   = abuf + R*C_;
      hbf16* tmpb = qb + R*C_;
      f2b_kernel<<<(int)((R*C_/4+255)/256), 256, 0, stream>>>(tgtc, abuf, (int)(R*C_));
      gemm_mfma_t<<<dim3(C_/128, (int)(R/128)), 256, 0, stream>>>((const short*)abuf, C_,
          (const short*)wb0, C_, ca_in_b + (size_t)l*3*C_, qb, C_, C_, 0);
      cross_attn_kernel<<<dim3(HW_, CH), 128, 0, stream>>>(qb, kvm, c0);
      gemm_mfma_t<<<dim3(C_/128, (int)(R/128)), 256, 0, stream>>>((const short*)qb, C_,
          (const short*)wb1, C_, ca_out_b + (size_t)l*C_, tmpb, C_, C_, 0);
      ln_res_kernel<<<(int)R, 256, 0, stream>>>(tgtc, tmpb,
          ln_w + (size_t)(l*3+1)*C_, ln_b + (size_t)(l*3+1)*C_);
    }

    // ===== FFN =====
    wtrans_kernel<<<dim3(FF_/32, C_/32), 256, 0, stream>>>(ff1_w + (size_t)l*C_*FF_, wb0, C_, FF_);
    wtrans_kernel<<<dim3(C_/32, FF_/32), 256, 0, stream>>>(ff2_w + (size_t)l*FF_*C_, wb1, FF_, C_);
    for (int c0 = 0; c0 < B_; c0 += CH) {
      float* tgtc = tgt + (size_t)c0*HW_*C_;
      hbf16* abuf = (hbf16*)S;
      hbf16* ffh  = abuf + R*C_;
      hbf16* tmpb = ffh + R*FF_;
      f2b_kernel<<<(int)((R*C_/4+255)/256), 256, 0, stream>>>(tgtc, abuf, (int)(R*C_));
      gemm_mfma_t<<<dim3(FF_/128, (int)(R/128)), 256, 0, stream>>>((const short*)abuf, C_,
          (const short*)wb0, C_, ff1_b + (size_t)l*FF_, ffh, FF_, C_, 1);
      gemm_mfma_t<<<dim3(C_/128, (int)(R/128)), 256, 0, stream>>>((const short*)ffh, FF_,
          (const short*)wb1, FF_, ff2_b + (size_t)l*C_, tmpb, C_, FF_, 0);
      ln_res_kernel<<<(int)R, 256, 0, stream>>>(tgtc, tmpb,
          ln_w + (size_t)(l*3+2)*C_, ln_b + (size_t)(l*3+2)*C_);
    }
  }

  // ---- final: tgt [B][HW][C] -> out [B][C][H][W], LDS-tiled transpose ----
  btrans_kernel<<<dim3(C_/32, HW_/32, B_), 256, 0, stream>>>(tgt, (float*)d_out, HW_, C_);
}

// Round 5
// 1542.726 us; speedup vs baseline: 1.2338x; 1.0332x over previous
//
#include <hip/hip_runtime.h>
#include <hip/hip_bf16.h>
#include <math.h>

typedef __hip_bfloat16 hbf16;

#define B_ 8
#define C_ 768
#define HW_ 1024
#define NH_ 8
#define HD_ 96
#define NPTS 2048      // PH*PW*K
#define AROUND_ 5
#define TOPK_ 5
#define MOD_ 2
#define FF_ 3072
#define TOK_ (B_*HW_)  // 8192

typedef __attribute__((ext_vector_type(8))) short short8v;
typedef __attribute__((ext_vector_type(4))) short short4v;
typedef __attribute__((ext_vector_type(4))) float f32x4;

__device__ __forceinline__ float b2f(hbf16 v){ return __bfloat162float(v); }

// ---- bilinear taps, torch grid_sample semantics (align_corners=False, zeros pad), H=W=32 ----
struct Taps { int x0,x1,y0,y1; float w00,w10,w01,w11; };
__device__ __forceinline__ Taps bilin_taps(float gx, float gy) {
  Taps t;
  float ix = ((gx+1.f)*32.f - 1.f)*0.5f;
  float iy = ((gy+1.f)*32.f - 1.f)*0.5f;
  float x0f = floorf(ix), y0f = floorf(iy);
  float wx1 = ix-x0f, wy1 = iy-y0f, wx0 = 1.f-wx1, wy0 = 1.f-wy1;
  int x0=(int)x0f, y0=(int)y0f, x1=x0+1, y1=y0+1;
  bool vx0=(x0>=0)&&(x0<=31), vx1=(x1>=0)&&(x1<=31);
  bool vy0=(y0>=0)&&(y0<=31), vy1=(y1>=0)&&(y1<=31);
  t.w00 = (vx0&&vy0) ? wx0*wy0 : 0.f;
  t.w10 = (vx1&&vy0) ? wx1*wy0 : 0.f;
  t.w01 = (vx0&&vy1) ? wx0*wy1 : 0.f;
  t.w11 = (vx1&&vy1) ? wx1*wy1 : 0.f;
  t.x0 = min(max(x0,0),31); t.x1 = min(max(x1,0),31);
  t.y0 = min(max(y0,0),31); t.y1 = min(max(y1,0),31);
  return t;
}

__device__ __forceinline__ float block_reduce_sum_256(float v, float* red) {
  int tid = threadIdx.x;
  red[tid] = v; __syncthreads();
  for (int s = 128; s > 0; s >>= 1) { if (tid < s) red[tid] += red[tid+s]; __syncthreads(); }
  float r = red[0]; __syncthreads();
  return r;
}

// ---- fp32 -> bf16 elementwise convert (n multiple of 4) ----
__global__ __launch_bounds__(256) void f2b_kernel(const float* __restrict__ in,
    hbf16* __restrict__ out, int n) {
  int i = (blockIdx.x*256 + threadIdx.x)*4;
  if (i >= n) return;
  float4 v = *(const float4*)&in[i];
  out[i+0] = __float2bfloat16(v.x);
  out[i+1] = __float2bfloat16(v.y);
  out[i+2] = __float2bfloat16(v.z);
  out[i+3] = __float2bfloat16(v.w);
}

// ---- transpose+convert: fp32 in[K][N] -> bf16 out[N][K] (K,N multiples of 32) ----
__global__ __launch_bounds__(256) void wtrans_kernel(const float* __restrict__ in,
    hbf16* __restrict__ out, int K, int N) {
  __shared__ float t[32][33];
  int tx = threadIdx.x & 31, ty = threadIdx.x >> 5;
  int k0 = blockIdx.y*32, n0 = blockIdx.x*32;
  #pragma unroll
  for (int i = 0; i < 32; i += 8) t[ty+i][tx] = in[(size_t)(k0+ty+i)*N + n0+tx];
  __syncthreads();
  #pragma unroll
  for (int i = 0; i < 32; i += 8)
    out[(size_t)(n0+ty+i)*K + k0 + tx] = __float2bfloat16(t[tx][ty+i]);
}

// ---- transpose + split-convert: fp32 in[K][N] -> hi[N][K], lo[N][K] ----
__global__ __launch_bounds__(256) void wtrans_split_kernel(const float* __restrict__ in,
    hbf16* __restrict__ hi, hbf16* __restrict__ lo, int K, int N) {
  __shared__ float t[32][33];
  int tx = threadIdx.x & 31, ty = threadIdx.x >> 5;
  int k0 = blockIdx.y*32, n0 = blockIdx.x*32;
  #pragma unroll
  for (int i = 0; i < 32; i += 8) t[ty+i][tx] = in[(size_t)(k0+ty+i)*N + n0+tx];
  __syncthreads();
  #pragma unroll
  for (int i = 0; i < 32; i += 8) {
    float v = t[tx][ty+i];
    hbf16 h = __float2bfloat16(v);
    hi[(size_t)(n0+ty+i)*K + k0 + tx] = h;
    lo[(size_t)(n0+ty+i)*K + k0 + tx] = __float2bfloat16(v - b2f(h));
  }
}

// ---- batched fp32 transpose: per z, in [R][S] -> out [S][R] (R,S multiples of 32) ----
// grid (S/32, R/32, batch)
__global__ __launch_bounds__(256) void btrans_kernel(const float* __restrict__ in,
    float* __restrict__ out, int R, int S) {
  __shared__ float t[32][33];
  int tx = threadIdx.x & 31, ty = threadIdx.x >> 5;
  int r0 = blockIdx.y*32, s0 = blockIdx.x*32;
  const float* ib = in + (size_t)blockIdx.z*R*S;
  float* ob = out + (size_t)blockIdx.z*R*S;
  #pragma unroll
  for (int i = 0; i < 32; i += 8) t[ty+i][tx] = ib[(size_t)(r0+ty+i)*S + s0+tx];
  __syncthreads();
  #pragma unroll
  for (int i = 0; i < 32; i += 8) ob[(size_t)(s0+ty+i)*R + r0+tx] = t[tx][ty+i];
}

__global__ __launch_bounds__(256) void zero_kernel(float* __restrict__ p, int n) {
  int i = blockIdx.x*256 + threadIdx.x;
  if (i < n) p[i] = 0.f;
}

// ---- stage A: blockwise sample from CHANNEL-LAST image oT [B][HW][C] ----
// grid (G, NPTS/4): blockIdx.x = instance (XCD-pinned), 4 points per block.
__global__ __launch_bounds__(256) void sample_all_kernel(const float* __restrict__ oT,
    const float* __restrict__ brand, hbf16* __restrict__ pf_hi, hbf16* __restrict__ pf_lo,
    float* __restrict__ coords_all, int g0) {
  int ly = blockIdx.x;
  int inst = g0 + ly;
  int b = inst & 7;
  const float* xT = oT + (size_t)b*HW_*C_;
  int tid = threadIdx.x;
  int p = tid >> 6, lane = tid & 63;
  int n = blockIdx.y*4 + p;
  int k = n & 1, pw = (n >> 1) & 31, ph = n >> 6;
  const float* br = brand + (size_t)inst*4096;
  int roff = ((ph*32 + pw)*2 + k)*2;
  float r0 = br[roff], r1 = br[roff+1];
  const float bs = 0.0625f;
  float c0 = r0*bs + ((float)ph*bs - 1.0f);
  float c1 = r1*bs + ((float)pw*bs - 1.0f);
  Taps t = bilin_taps(c0, c1);
  const float* r00 = xT + (size_t)(t.y0*32+t.x0)*C_;
  const float* r10 = xT + (size_t)(t.y0*32+t.x1)*C_;
  const float* r01 = xT + (size_t)(t.y1*32+t.x0)*C_;
  const float* r11 = xT + (size_t)(t.y1*32+t.x1)*C_;
  size_t base = ((size_t)ly*NPTS + n)*C_;
  short* ph_ = (short*)pf_hi;
  short* pl_ = (short*)pf_lo;
  #pragma unroll
  for (int kk = 0; kk < 3; ++kk) {
    int c = kk*256 + lane*4;
    float4 v00 = *(const float4*)(r00 + c);
    float4 v10 = *(const float4*)(r10 + c);
    float4 v01 = *(const float4*)(r01 + c);
    float4 v11 = *(const float4*)(r11 + c);
    float o[4];
    o[0] = t.w00*v00.x + t.w10*v10.x + t.w01*v01.x + t.w11*v11.x;
    o[1] = t.w00*v00.y + t.w10*v10.y + t.w01*v01.y + t.w11*v11.y;
    o[2] = t.w00*v00.z + t.w10*v10.z + t.w01*v01.z + t.w11*v11.z;
    o[3] = t.w00*v00.w + t.w10*v10.w + t.w01*v01.w + t.w11*v11.w;
    short4v hs, ls;
    #pragma unroll
    for (int e = 0; e < 4; ++e) {
      hbf16 h = __float2bfloat16(o[e]);
      hs[e] = *(short*)&h;
      hbf16 l = __float2bfloat16(o[e] - b2f(h));
      ls[e] = *(short*)&l;
    }
    *(short4v*)&ph_[base + c] = hs;
    *(short4v*)&pl_[base + c] = ls;
  }
  if (lane == 0) {
    size_t co = ((size_t)inst*NPTS + n)*2;
    coords_all[co] = c0; coords_all[co+1] = c1;
  }
}

// ---- fused score GEMM (split-bf16, 3-term) + relu + w2-dot -> atomicAdd logits ----
__global__ __launch_bounds__(256) void score_gemm_kernel(const short* __restrict__ Ahi,
    const short* __restrict__ Alo, const short* __restrict__ Bhi, const short* __restrict__ Blo,
    const float* __restrict__ b1, const float* __restrict__ w2, float* __restrict__ logit) {
  __shared__ short AsH[128*40];
  __shared__ short AsL[128*40];
  __shared__ short BsH[128*40];
  __shared__ short BsL[128*40];
  int tid = threadIdx.x;
  int lane = tid & 63, w = tid >> 6;
  int wr = (w >> 1) * 64, wc = (w & 1) * 64;
  int m16 = lane & 15, quad = lane >> 4, q8 = quad * 8;
  int bm = blockIdx.y * 128, bn = blockIdx.x * 128;
  int ar = tid >> 2, ac = (tid & 3) * 8;
  f32x4 acc[4][4] = {};
  for (int k0 = 0; k0 < 768; k0 += 32) {
    *(short8v*)&AsH[ar*40 + ac]      = *(const short8v*)&Ahi[(size_t)(bm+ar)*768 + k0 + ac];
    *(short8v*)&AsH[(ar+64)*40 + ac] = *(const short8v*)&Ahi[(size_t)(bm+ar+64)*768 + k0 + ac];
    *(short8v*)&AsL[ar*40 + ac]      = *(const short8v*)&Alo[(size_t)(bm+ar)*768 + k0 + ac];
    *(short8v*)&AsL[(ar+64)*40 + ac] = *(const short8v*)&Alo[(size_t)(bm+ar+64)*768 + k0 + ac];
    *(short8v*)&BsH[ar*40 + ac]      = *(const short8v*)&Bhi[(size_t)(bn+ar)*768 + k0 + ac];
    *(short8v*)&BsH[(ar+64)*40 + ac] = *(const short8v*)&Bhi[(size_t)(bn+ar+64)*768 + k0 + ac];
    *(short8v*)&BsL[ar*40 + ac]      = *(const short8v*)&Blo[(size_t)(bn+ar)*768 + k0 + ac];
    *(short8v*)&BsL[(ar+64)*40 + ac] = *(const short8v*)&Blo[(size_t)(bn+ar+64)*768 + k0 + ac];
    __syncthreads();
    short8v ah[4], al[4], bh[4], bl[4];
    #pragma unroll
    for (int i=0;i<4;++i) {
      ah[i] = *(const short8v*)&AsH[(wr + i*16 + m16)*40 + q8];
      al[i] = *(const short8v*)&AsL[(wr + i*16 + m16)*40 + q8];
      bh[i] = *(const short8v*)&BsH[(wc + i*16 + m16)*40 + q8];
      bl[i] = *(const short8v*)&BsL[(wc + i*16 + m16)*40 + q8];
    }
    #pragma unroll
    for (int i=0;i<4;++i)
      #pragma unroll
      for (int j=0;j<4;++j) {
        acc[i][j] = __builtin_amdgcn_mfma_f32_16x16x32_bf16(ah[i], bh[j], acc[i][j], 0, 0, 0);
        acc[i][j] = __builtin_amdgcn_mfma_f32_16x16x32_bf16(ah[i], bl[j], acc[i][j], 0, 0, 0);
        acc[i][j] = __builtin_amdgcn_mfma_f32_16x16x32_bf16(al[i], bh[j], acc[i][j], 0, 0, 0);
      }
    __syncthreads();
  }
  float b1v[4], w2v[4];
  #pragma unroll
  for (int j=0;j<4;++j) {
    int col = bn + wc + j*16 + m16;
    b1v[j] = b1[col]; w2v[j] = w2[col];
  }
  #pragma unroll
  for (int i=0;i<4;++i) {
    #pragma unroll
    for (int r=0;r<4;++r) {
      float v = 0.f;
      #pragma unroll
      for (int j=0;j<4;++j) {
        float h = fmaxf(acc[i][j][r] + b1v[j], 0.f);
        v += h * w2v[j];
      }
      v += __shfl_xor(v, 1); v += __shfl_xor(v, 2);
      v += __shfl_xor(v, 4); v += __shfl_xor(v, 8);
      if (m16 == 0) atomicAdd(&logit[bm + wr + i*16 + quad*4 + r], v);
    }
  }
}

// ---- top-5 of 2048 per instance (on logits; sigmoid monotone), jax tie semantics ----
__global__ void topk_all_kernel(const float* __restrict__ logit, int* __restrict__ idx) {
  int lane = threadIdx.x;   // 64 lanes
  const float* score = logit + (size_t)blockIdx.x*NPTS;
  float v[32];
  #pragma unroll
  for (int i = 0; i < 32; ++i) v[i] = score[(i<<6) | lane];
  for (int t = 0; t < TOPK_; ++t) {
    float bv = v[0]; int bi = lane;
    #pragma unroll
    for (int i = 1; i < 32; ++i) { if (v[i] > bv) { bv = v[i]; bi = (i<<6)|lane; } }
    for (int off = 32; off; off >>= 1) {
      float ov = __shfl_xor(bv, off);
      int   oi = __shfl_xor(bi, off);
      if (ov > bv || (ov == bv && oi < bi)) { bv = ov; bi = oi; }
    }
    if (lane == 0) idx[blockIdx.x*8 + t] = bi;
    if ((bi & 63) == lane) v[bi >> 6] = -1e30f;
  }
}

// ---- soft_align + modality query -> memf rows; grid (TOPK, G) ----
// mainxT is channel-last [B][HW][C] (the tgt buffer, pre-tgt0)
__global__ __launch_bounds__(256) void softalign_all_kernel(const float* __restrict__ mainxT,
    const float* __restrict__ pos, const hbf16* __restrict__ pf_hi, const hbf16* __restrict__ pf_lo,
    const float* __restrict__ coords_all, const int* __restrict__ idx_all,
    const float* __restrict__ arand, const float* __restrict__ mq,
    float* __restrict__ memf, int g0) {
  int t = blockIdx.x;
  int ly = blockIdx.y;
  int inst = g0 + ly;
  int mod = inst >> 3, b = inst & 7;
  const float* mT_b = mainxT + (size_t)b*HW_*C_;
  const float* arand_ib = arand + (size_t)inst*AROUND_*TOPK_*2;
  const float* coords = coords_all + (size_t)inst*NPTS*2;
  int tid = threadIdx.x;
  int n = idx_all[ly*8 + t];
  float px0 = coords[n*2], px1 = coords[n*2+1];
  size_t pfb = ((size_t)ly*NPTS + n)*C_;
  float pfv[3];
  #pragma unroll
  for (int i=0;i<3;++i) {
    int c = tid + i*256;
    pfv[i] = b2f(pf_hi[pfb + c]) + b2f(pf_lo[pfb + c]);
  }
  __shared__ float red[256];
  float pp = block_reduce_sum_256(pfv[0]*pfv[0]+pfv[1]*pfv[1]+pfv[2]*pfv[2], red);
  float embr[AROUND_][3];
  float num_a[AROUND_], aa_a[AROUND_];
  for (int a=0; a<AROUND_; ++a) {
    int ar = (a*TOPK_ + t)*2;
    float g0c = px0 + (arand_ib[ar]*2.f - 0.5f)*0.2f;
    float g1c = px1 + (arand_ib[ar+1]*2.f - 0.5f)*0.2f;
    g0c = fminf(fmaxf(g0c,-1.f),1.f);
    g1c = fminf(fmaxf(g1c,-1.f),1.f);
    Taps tp = bilin_taps(g0c, g1c);
    int i00=tp.y0*32+tp.x0, i10=tp.y0*32+tp.x1, i01=tp.y1*32+tp.x0, i11=tp.y1*32+tp.x1;
    float s_num = 0.f, s_aa = 0.f;
    #pragma unroll
    for (int i=0;i<3;++i) {
      int c = tid + i*256;
      float af = tp.w00*mT_b[(size_t)i00*C_+c] + tp.w10*mT_b[(size_t)i10*C_+c]
               + tp.w01*mT_b[(size_t)i01*C_+c] + tp.w11*mT_b[(size_t)i11*C_+c];
      float em = tp.w00*pos[(size_t)i00*C_+c] + tp.w10*pos[(size_t)i10*C_+c]
               + tp.w01*pos[(size_t)i01*C_+c] + tp.w11*pos[(size_t)i11*C_+c];
      embr[a][i] = em;
      s_num += pfv[i]*af;
      s_aa  += af*af;
    }
    num_a[a] = block_reduce_sum_256(s_num, red);
    aa_a[a]  = block_reduce_sum_256(s_aa, red);
  }
  float pn = fmaxf(sqrtf(pp), 1e-8f);
  float w[AROUND_]; float mx = -1e30f;
  #pragma unroll
  for (int a=0;a<AROUND_;++a){ float den = pn * fmaxf(sqrtf(aa_a[a]),1e-8f); w[a]=num_a[a]/den; mx=fmaxf(mx,w[a]); }
  float se = 0.f;
  #pragma unroll
  for (int a=0;a<AROUND_;++a){ w[a]=expf(w[a]-mx); se+=w[a]; }
  float inv = 1.f/se;
  float* mo = memf + ((size_t)b*(MOD_*TOPK_) + mod*TOPK_ + t)*C_;
  #pragma unroll
  for (int i=0;i<3;++i) {
    int c = tid + i*256;
    float o = pfv[i];
    #pragma unroll
    for (int a=0;a<AROUND_;++a) o += embr[a][i]*(w[a]*inv);
    o += mq[(size_t)(mod+1)*C_ + c];
    mo[c] = o;
  }
}

// ---- generic fp32 GEMM (kvm only) ----
#define BM 64
#define BN 64
#define BK 16
__global__ __launch_bounds__(256) void gemm_kernel(const float* __restrict__ A, int lda,
    const float* __restrict__ Bw, int ldb, const float* __restrict__ bias,
    float* __restrict__ Cm, int ldc, int M, int N, int K, int act) {
  __shared__ float As[BK][BM];
  __shared__ float Bs[BK][BN];
  int tid = threadIdx.x;
  int bm = blockIdx.y * BM, bn = blockIdx.x * BN;
  int arw = tid >> 2, acl = (tid & 3) << 2;
  int brw = tid >> 4, bcl = (tid & 15) << 2;
  int ty = tid >> 4, tx = tid & 15;
  float acc[4][4] = {{0.f}};
  for (int k0 = 0; k0 < K; k0 += BK) {
    float a0=0.f,a1=0.f,a2=0.f,a3=0.f;
    if (bm + arw < M) {
      const float* ap = A + (size_t)(bm+arw)*lda + k0 + acl;
      a0=ap[0]; a1=ap[1]; a2=ap[2]; a3=ap[3];
    }
    As[acl+0][arw]=a0; As[acl+1][arw]=a1; As[acl+2][arw]=a2; As[acl+3][arw]=a3;
    const float* bp = Bw + (size_t)(k0+brw)*ldb + bn + bcl;
    Bs[brw][bcl+0]=bp[0]; Bs[brw][bcl+1]=bp[1]; Bs[brw][bcl+2]=bp[2]; Bs[brw][bcl+3]=bp[3];
    __syncthreads();
    #pragma unroll
    for (int kk = 0; kk < BK; ++kk) {
      float4 av = *reinterpret_cast<const float4*>(&As[kk][ty<<2]);
      float4 bv = *reinterpret_cast<const float4*>(&Bs[kk][tx<<2]);
      acc[0][0]+=av.x*bv.x; acc[0][1]+=av.x*bv.y; acc[0][2]+=av.x*bv.z; acc[0][3]+=av.x*bv.w;
      acc[1][0]+=av.y*bv.x; acc[1][1]+=av.y*bv.y; acc[1][2]+=av.y*bv.z; acc[1][3]+=av.y*bv.w;
      acc[2][0]+=av.z*bv.x; acc[2][1]+=av.z*bv.y; acc[2][2]+=av.z*bv.z; acc[2][3]+=av.z*bv.w;
      acc[3][0]+=av.w*bv.x; acc[3][1]+=av.w*bv.y; acc[3][2]+=av.w*bv.z; acc[3][3]+=av.w*bv.w;
    }
    __syncthreads();
  }
  #pragma unroll
  for (int i=0;i<4;++i) {
    int r = bm + (ty<<2) + i;
    if (r >= M) continue;
    float* cp = Cm + (size_t)r*ldc + bn + (tx<<2);
    #pragma unroll
    for (int j=0;j<4;++j) {
      float v = acc[i][j] + bias[bn + (tx<<2) + j];
      if (act) v = fmaxf(v, 0.f);
      cp[j] = v;
    }
  }
}

// ---- XCD swizzle: each XCD owns gy/8 contiguous row-panels, iterates cols fastest ----
// wgid%8 = XCD (round-robin dispatch); requires gx*gy % 8 == 0 and gy % 8 == 0.
__device__ __forceinline__ void xcd_tile(int gx, int gy, int& row, int& col) {
  int wgid = blockIdx.y * gx + blockIdx.x;
  int xcd = wgid & 7;
  int li = wgid >> 3;
  row = xcd * (gy >> 3) + li / gx;
  col = li % gx;
}

// ---- bf16 MFMA GEMM, B pre-transposed: C = act(A[M,K] @ Bt[N,K]^T + bias), 128x128 tile ----
__global__ __launch_bounds__(256) void gemm_mfma_t(const short* __restrict__ A, int lda,
    const short* __restrict__ Bt, int ldbt, const float* __restrict__ bias,
    hbf16* __restrict__ Cm, int ldc, int K, int act) {
  __shared__ short As[128*40];
  __shared__ short Bs[128*40];
  int tid = threadIdx.x;
  int lane = tid & 63, w = tid >> 6;
  int wr = (w >> 1) * 64, wc = (w & 1) * 64;
  int m16 = lane & 15, q8 = (lane >> 4) * 8;
  int brow, bcol;
  xcd_tile(gridDim.x, gridDim.y, brow, bcol);
  int bm = brow * 128, bn = bcol * 128;
  int ar = tid >> 2, ac = (tid & 3) * 8;
  f32x4 acc[4][4] = {};
  for (int k0 = 0; k0 < K; k0 += 32) {
    *(short8v*)&As[ar*40 + ac]      = *(const short8v*)&A[(size_t)(bm+ar)*lda + k0 + ac];
    *(short8v*)&As[(ar+64)*40 + ac] = *(const short8v*)&A[(size_t)(bm+ar+64)*lda + k0 + ac];
    *(short8v*)&Bs[ar*40 + ac]      = *(const short8v*)&Bt[(size_t)(bn+ar)*ldbt + k0 + ac];
    *(short8v*)&Bs[(ar+64)*40 + ac] = *(const short8v*)&Bt[(size_t)(bn+ar+64)*ldbt + k0 + ac];
    __syncthreads();
    short8v af[4], bf[4];
    #pragma unroll
    for (int i=0;i<4;++i) af[i] = *(const short8v*)&As[(wr + i*16 + m16)*40 + q8];
    #pragma unroll
    for (int j=0;j<4;++j) bf[j] = *(const short8v*)&Bs[(wc + j*16 + m16)*40 + q8];
    #pragma unroll
    for (int i=0;i<4;++i)
      #pragma unroll
      for (int j=0;j<4;++j)
        acc[i][j] = __builtin_amdgcn_mfma_f32_16x16x32_bf16(af[i], bf[j], acc[i][j], 0, 0, 0);
    __syncthreads();
  }
  #pragma unroll
  for (int j=0;j<4;++j) {
    int col = bn + wc + j*16 + m16;
    float bs = bias[col];
    #pragma unroll
    for (int i=0;i<4;++i) {
      int row0 = bm + wr + i*16 + (lane>>4)*4;
      #pragma unroll
      for (int r=0;r<4;++r) {
        float v = acc[i][j][r] + bs;
        if (act) v = fmaxf(v, 0.f);
        Cm[(size_t)(row0+r)*ldc + col] = __float2bfloat16(v);
      }
    }
  }
}

// ---- bf16 MFMA GEMM, 128x64 tile (for small-N GEMMs; doubles grid vs 128x128) ----
// 4 waves, each computes 32 rows x 64 cols (acc[2][4]).
__global__ __launch_bounds__(256) void gemm_mfma_t64(const short* __restrict__ A, int lda,
    const short* __restrict__ Bt, int ldbt, const float* __restrict__ bias,
    hbf16* __restrict__ Cm, int ldc, int K, int act) {
  __shared__ short As[128*40];
  __shared__ short Bs[64*40];
  int tid = threadIdx.x;
  int lane = tid & 63, w = tid >> 6;
  int m16 = lane & 15, q8 = (lane >> 4) * 8;
  int brow, bcol;
  xcd_tile(gridDim.x, gridDim.y, brow, bcol);
  int bm = brow * 128, bn = bcol * 64;
  int ar = tid >> 2, ac = (tid & 3) * 8;
  f32x4 acc[2][4] = {};
  for (int k0 = 0; k0 < K; k0 += 32) {
    *(short8v*)&As[ar*40 + ac]      = *(const short8v*)&A[(size_t)(bm+ar)*lda + k0 + ac];
    *(short8v*)&As[(ar+64)*40 + ac] = *(const short8v*)&A[(size_t)(bm+ar+64)*lda + k0 + ac];
    *(short8v*)&Bs[ar*40 + ac]      = *(const short8v*)&Bt[(size_t)(bn+ar)*ldbt + k0 + ac];
    __syncthreads();
    short8v af[2], bf[4];
    #pragma unroll
    for (int i=0;i<2;++i) af[i] = *(const short8v*)&As[(w*32 + i*16 + m16)*40 + q8];
    #pragma unroll
    for (int j=0;j<4;++j) bf[j] = *(const short8v*)&Bs[(j*16 + m16)*40 + q8];
    #pragma unroll
    for (int i=0;i<2;++i)
      #pragma unroll
      for (int j=0;j<4;++j)
        acc[i][j] = __builtin_amdgcn_mfma_f32_16x16x32_bf16(af[i], bf[j], acc[i][j], 0, 0, 0);
    __syncthreads();
  }
  #pragma unroll
  for (int j=0;j<4;++j) {
    int col = bn + j*16 + m16;
    float bs = bias[col];
    #pragma unroll
    for (int i=0;i<2;++i) {
      int row0 = bm + w*32 + i*16 + (lane>>4)*4;
      #pragma unroll
      for (int r=0;r<4;++r) {
        float v = acc[i][j][r] + bs;
        if (act) v = fmaxf(v, 0.f);
        Cm[(size_t)(row0+r)*ldc + col] = __float2bfloat16(v);
      }
    }
  }
}

// ---- fused flash self-attention (MFMA): grid (head+batch, qtile=8), 512 thr / 8 waves ----
// x = h + NH_*bz so all q-tiles of one (b,h) share an XCD (ids congruent mod 8).
// 8 waves x 16 q-rows each; Q fragments in registers; LDS = KP ∪ Vt (32.3 KB).
// Grid 512 blocks x 8 waves = 4096 waves = 16 waves/CU (2 blocks/CU).
__global__ __launch_bounds__(512, 4) void flash_attn_kernel(const hbf16* __restrict__ qkv_all,
    hbf16* __restrict__ o_all) {
  const int hb = blockIdx.x;
  const int h  = hb & 7;
  const int bz = hb >> 3;
  const int q0 = blockIdx.y * 128;
  const short* qkv = (const short*)(qkv_all + (size_t)bz*HW_*2304);
  hbf16* ob = o_all + (size_t)bz*HW_*C_;
  const int tid = threadIdx.x;
  const int lane = tid & 63, w = tid >> 6;
  const int m16 = lane & 15, quad = lane >> 4, q8 = quad * 8;
  const float scale = 0.10206207261596577f;  // 1/sqrt(96)

  // 16128 shorts = 32256 B. KP = lds[0..9216): K tile [64][104] (QK) / P [128][72] (PV).
  // Vt = lds[9216..16128): V^T [96][72]. Q staging [128][104]=13312 aliases both.
  __shared__ short lds[16128];
  short* KP = lds;
  short* Vt = lds + 9216;

  // stage Q -> LDS (coalesced), then hoist this wave's 16-row fragments to registers
  for (int idx = tid; idx < 128*12; idx += 512) {
    int row = idx / 12, dc = idx % 12;
    *(short8v*)&lds[row*104 + dc*8] = *(const short8v*)&qkv[(size_t)(q0+row)*2304 + h*HD_ + dc*8];
  }
  __syncthreads();
  short8v qf[3];
  #pragma unroll
  for (int kkk=0;kkk<3;++kkk)
    qf[kkk] = *(const short8v*)&lds[(w*16 + m16)*104 + q8 + kkk*32];
  __syncthreads();

  float m_st[4], l_st[4];
  f32x4 o_acc[6] = {};
  #pragma unroll
  for (int r=0;r<4;++r){ m_st[r] = -1e30f; l_st[r] = 0.f; }

  for (int t = 0; t < 16; ++t) {
    int j0 = t * 64;
    for (int idx = tid; idx < 64*12; idx += 512) {
      int row = idx / 12, dc = idx % 12;
      *(short8v*)&KP[row*104 + dc*8] = *(const short8v*)&qkv[(size_t)(j0+row)*2304 + C_ + h*HD_ + dc*8];
    }
    // V^T stage: j fast within wave -> conflict-free LDS writes
    for (int idx = tid; idx < 64*12; idx += 512) {
      int j = idx & 63, dc = idx >> 6;
      short8v v = *(const short8v*)&qkv[(size_t)(j0+j)*2304 + 2*C_ + h*HD_ + dc*8];
      #pragma unroll
      for (int s = 0; s < 8; ++s) Vt[(dc*8+s)*72 + j] = v[s];
    }
    __syncthreads();

    f32x4 accs[4] = {};
    #pragma unroll
    for (int kkk = 0; kkk < 3; ++kkk) {
      int kk = kkk*32;
      short8v bf[4];
      #pragma unroll
      for (int n=0;n<4;++n) bf[n] = *(const short8v*)&KP[(n*16 + m16)*104 + q8 + kk];
      #pragma unroll
      for (int n=0;n<4;++n)
        accs[n] = __builtin_amdgcn_mfma_f32_16x16x32_bf16(qf[kkk], bf[n], accs[n], 0, 0, 0);
    }
    __syncthreads();

    #pragma unroll
    for (int r=0;r<4;++r) {
      float mx = -1e30f;
      #pragma unroll
      for (int n=0;n<4;++n) mx = fmaxf(mx, accs[n][r]*scale);
      #pragma unroll
      for (int off=1; off<16; off<<=1) mx = fmaxf(mx, __shfl_xor(mx, off));
      float m_new = fmaxf(m_st[r], mx);
      float alpha = __expf(m_st[r] - m_new);
      float psum = 0.f;
      int prow = (w*16 + quad*4 + r)*72 + m16;
      #pragma unroll
      for (int n=0;n<4;++n) {
        float pv = __expf(accs[n][r]*scale - m_new);
        psum += pv;
        *(hbf16*)&KP[prow + n*16] = __float2bfloat16(pv);
      }
      #pragma unroll
      for (int off=1; off<16; off<<=1) psum += __shfl_xor(psum, off);
      l_st[r] = l_st[r]*alpha + psum;
      m_st[r] = m_new;
      #pragma unroll
      for (int dt=0; dt<6; ++dt) o_acc[dt][r] *= alpha;
    }

    #pragma unroll
    for (int k0 = 0; k0 < 64; k0 += 32) {
      short8v pf_, vf[6];
      pf_ = *(const short8v*)&KP[(w*16 + m16)*72 + q8 + k0];
      #pragma unroll
      for (int dt=0; dt<6; ++dt) vf[dt] = *(const short8v*)&Vt[(dt*16 + m16)*72 + q8 + k0];
      #pragma unroll
      for (int dt=0; dt<6; ++dt)
        o_acc[dt] = __builtin_amdgcn_mfma_f32_16x16x32_bf16(pf_, vf[dt], o_acc[dt], 0, 0, 0);
    }
    __syncthreads();
  }

  #pragma unroll
  for (int r=0;r<4;++r) {
    float inv = 1.f / l_st[r];
    int row = q0 + w*16 + quad*4 + r;
    #pragma unroll
    for (int dt=0; dt<6; ++dt)
      ob[(size_t)row*C_ + h*HD_ + dt*16 + m16] = __float2bfloat16(o_acc[dt][r]*inv);
  }
}

// ---- cross-attention over 10 memory tokens, grid (1024, CH), IN PLACE on bf16 q rows ----
__global__ __launch_bounds__(128) void cross_attn_kernel(hbf16* __restrict__ qb,
    const float* __restrict__ kvm, int b0) {
  int row = blockIdx.x;
  int lb = blockIdx.y;
  int b = b0 + lb;
  int tid = threadIdx.x;
  __shared__ float sc[16];
  __shared__ float qs[C_];
  hbf16* qp = qb + ((size_t)lb*HW_ + row)*C_;
  for (int c = tid; c < C_; c += 128) qs[c] = b2f(qp[c]);
  __syncthreads();
  const float scale = 0.10206207261596577f;
  for (int h = 0; h < NH_; ++h) {
    if (tid < 10) {
      const float* kp = kvm + (size_t)(b*10 + tid)*1536 + h*HD_;
      float s = 0.f;
      for (int d = 0; d < HD_; ++d) s += qs[h*HD_+d]*kp[d];
      sc[tid] = s*scale;
    }
    __syncthreads();
    if (tid == 0) {
      float m = -1e30f;
      for (int j=0;j<10;++j) m = fmaxf(m, sc[j]);
      float se = 0.f;
      for (int j=0;j<10;++j){ sc[j]=expf(sc[j]-m); se+=sc[j]; }
      float inv = 1.f/se;
      for (int j=0;j<10;++j) sc[j]*=inv;
    }
    __syncthreads();
    if (tid < HD_) {
      const float* vp = kvm + (size_t)(b*10)*1536 + C_ + h*HD_ + tid;
      float acc = 0.f;
      for (int j=0;j<10;++j) acc += sc[j]*vp[(size_t)j*1536];
      qp[h*HD_+tid] = __float2bfloat16(acc);
    }
    __syncthreads();
  }
}

// ---- tgt init: IN PLACE on pre-transposed mainxT (=tgt): += mq[0] + pos ----
__global__ __launch_bounds__(256) void tgt0_kernel(float* __restrict__ tgt,
    const float* __restrict__ mq, const float* __restrict__ pos) {
  size_t i = ((size_t)blockIdx.x*256 + threadIdx.x)*4;
  if (i >= (size_t)TOK_*C_) return;
  int c = (int)(i % C_);
  int tpos = (int)((i / C_) % HW_);
  float4 v = *(float4*)&tgt[i];
  float4 m = *(const float4*)&mq[c];
  float4 pp = *(const float4*)&pos[(size_t)tpos*C_ + c];
  v.x += m.x + pp.x; v.y += m.y + pp.y;
  v.z += m.z + pp.z; v.w += m.w + pp.w;
  *(float4*)&tgt[i] = v;
}

// ---- residual + layernorm (in place on fp32 tgt rows, bf16 add) ----
__global__ __launch_bounds__(256) void ln_res_kernel(float* __restrict__ tgt, const hbf16* __restrict__ add,
    const float* __restrict__ w, const float* __restrict__ bvec) {
  __shared__ float red[256];
  int row = blockIdx.x, tid = threadIdx.x;
  float* tp = tgt + (size_t)row*C_;
  const hbf16* ap = add + (size_t)row*C_;
  float x[3]; float s = 0.f, s2 = 0.f;
  #pragma unroll
  for (int i=0;i<3;++i){ int c=tid+i*256; float v=tp[c]+b2f(ap[c]); x[i]=v; s+=v; s2+=v*v; }
  s  = block_reduce_sum_256(s,  red);
  s2 = block_reduce_sum_256(s2, red);
  float mean = s * (1.f/C_);
  float var  = s2 * (1.f/C_) - mean*mean;
  float rstd = rsqrtf(var + 1e-5f);
  #pragma unroll
  for (int i=0;i<3;++i){ int c=tid+i*256; tp[c] = (x[i]-mean)*rstd*w[c] + bvec[c]; }
}

extern "C" void kernel_launch(void* const* d_in, const int* in_sizes, int n_in,
                              void* d_out, int out_size, void* d_ws, size_t ws_size,
                              hipStream_t stream) {
  const float* mainx   = (const float*)d_in[0];
  const float* other0  = (const float*)d_in[1];
  const float* other1  = (const float*)d_in[2];
  const float* pos     = (const float*)d_in[3];
  const float* mq      = (const float*)d_in[4];
  const float* s_w1    = (const float*)d_in[5];
  const float* s_b1    = (const float*)d_in[6];
  const float* s_w2    = (const float*)d_in[7];
  const float* sa_in_w = (const float*)d_in[9];
  const float* sa_in_b = (const float*)d_in[10];
  const float* sa_out_w= (const float*)d_in[11];
  const float* sa_out_b= (const float*)d_in[12];
  const float* ca_in_w = (const float*)d_in[13];
  const float* ca_in_b = (const float*)d_in[14];
  const float* ca_out_w= (const float*)d_in[15];
  const float* ca_out_b= (const float*)d_in[16];
  const float* ff1_w   = (const float*)d_in[17];
  const float* ff1_b   = (const float*)d_in[18];
  const float* ff2_w   = (const float*)d_in[19];
  const float* ff2_b   = (const float*)d_in[20];
  const float* ln_w    = (const float*)d_in[21];
  const float* ln_b    = (const float*)d_in[22];
  const float* brand   = (const float*)d_in[23];
  const float* arand   = (const float*)d_in[24];

  // ---- workspace layout ----
  char* p = (char*)d_ws;
  auto alloc = [&](size_t bytes) { char* r = p; p += (bytes + 255) & ~(size_t)255; return (void*)r; };
  float* tgt    = (float*)alloc((size_t)TOK_*C_*4);       // 24 MB; holds mainxT during stage A
  hbf16* wb0    = (hbf16*)alloc((size_t)2359296*2);       // 4.5 MB (transposed weights)
  hbf16* wb1    = (hbf16*)alloc((size_t)2359296*2);       // 4.5 MB
  hbf16* w1t_hi = (hbf16*)alloc((size_t)C_*C_*2);
  hbf16* w1t_lo = (hbf16*)alloc((size_t)C_*C_*2);
  float* kvm    = (float*)alloc((size_t)80*1536*4);
  float* memf   = (float*)alloc((size_t)80*C_*4);
  float* coords = (float*)alloc((size_t)16*NPTS*2*4);
  float* logit  = (float*)alloc((size_t)16*NPTS*4);
  int*   idxb   = (int*)alloc(16*8*4);
  char*  S      = p;
  size_t used = (size_t)(p - (char*)d_ws);
  size_t Savail = (ws_size > used) ? ws_size - used : 0;
  int CH = 1;
  if (Savail >= (size_t)8*1024*9216 + 4096) CH = 8;
  else if (Savail >= (size_t)4*1024*9216 + 4096) CH = 4;
  else if (Savail >= (size_t)2*1024*9216 + 4096) CH = 2;
  const size_t R = (size_t)CH*1024;
  const size_t perG = (size_t)NPTS*C_*2*2;  // pf_hi+pf_lo per instance
  // stage-A scratch: oT (one image set, channel-last) at front of S, pf after
  const size_t oTb = (size_t)B_*HW_*C_*4;   // 25.2 MB, 256-aligned
  float* oT = (float*)S;
  char* Spf = S + oTb;
  size_t SA = (Savail > oTb) ? Savail - oTb : 0;
  int G = 1;
  if (SA >= 8*perG) G = 8;
  else if (SA >= 4*perG) G = 4;
  else if (SA >= 2*perG) G = 2;

  // ---- stage A ----
  // mainx [B][C][HW] -> channel-last in tgt (softalign reads it; tgt0 finishes in place)
  btrans_kernel<<<dim3(HW_/32, C_/32, B_), 256, 0, stream>>>(mainx, tgt, C_, HW_);
  wtrans_split_kernel<<<dim3(C_/32, C_/32), 256, 0, stream>>>(s_w1, w1t_hi, w1t_lo, C_, C_);
  zero_kernel<<<16*NPTS/256, 256, 0, stream>>>(logit, 16*NPTS);
  for (int g0 = 0; g0 < 16; g0 += G) {
    if ((g0 & 7) == 0)
      btrans_kernel<<<dim3(HW_/32, C_/32, B_), 256, 0, stream>>>(g0 < 8 ? other0 : other1,
          oT, C_, HW_);
    hbf16* pf_hi = (hbf16*)Spf;
    hbf16* pf_lo = pf_hi + (size_t)G*NPTS*C_;
    sample_all_kernel<<<dim3(G, NPTS/4), 256, 0, stream>>>(oT, brand,
        pf_hi, pf_lo, coords, g0);
    score_gemm_kernel<<<dim3(6, G*16), 256, 0, stream>>>((const short*)pf_hi, (const short*)pf_lo,
        (const short*)w1t_hi, (const short*)w1t_lo, s_b1, s_w2, logit + (size_t)g0*NPTS);
    topk_all_kernel<<<G, 64, 0, stream>>>(logit + (size_t)g0*NPTS, idxb + g0*8);
    softalign_all_kernel<<<dim3(TOPK_, G), 256, 0, stream>>>(tgt, pos, pf_hi, pf_lo,
        coords, idxb + g0*8, arand, mq, memf, g0);
  }

  // ---- stage B ----
  size_t total = (size_t)TOK_*C_;
  tgt0_kernel<<<(int)((total/4+255)/256), 256, 0, stream>>>(tgt, mq, pos);

  for (int l = 0; l < 2; ++l) {
    // ===== self-attention =====
    wtrans_kernel<<<dim3(3*C_/32, C_/32), 256, 0, stream>>>(sa_in_w + (size_t)l*C_*3*C_, wb0, C_, 3*C_);
    wtrans_kernel<<<dim3(C_/32, C_/32), 256, 0, stream>>>(sa_out_w + (size_t)l*C_*C_, wb1, C_, C_);
    for (int c0 = 0; c0 < B_; c0 += CH) {
      float* tgtc = tgt + (size_t)c0*HW_*C_;
      hbf16* abuf = (hbf16*)S;
      hbf16* qkv  = abuf + R*C_;
      hbf16* oatt = qkv + R*3*C_;
      hbf16* tmpb = oatt + R*C_;
      f2b_kernel<<<(int)((R*C_/4+255)/256), 256, 0, stream>>>(tgtc, abuf, (int)(R*C_));
      gemm_mfma_t<<<dim3(3*C_/128, (int)(R/128)), 256, 0, stream>>>((const short*)abuf, C_,
          (const short*)wb0, C_, sa_in_b + (size_t)l*3*C_, qkv, 3*C_, C_, 0);
      flash_attn_kernel<<<dim3(NH_*CH, HW_/128), 512, 0, stream>>>(qkv, oatt);
      gemm_mfma_t64<<<dim3(C_/64, (int)(R/128)), 256, 0, stream>>>((const short*)oatt, C_,
          (const short*)wb1, C_, sa_out_b + (size_t)l*C_, tmpb, C_, C_, 0);
      ln_res_kernel<<<(int)R, 256, 0, stream>>>(tgtc, tmpb,
          ln_w + (size_t)(l*3+0)*C_, ln_b + (size_t)(l*3+0)*C_);
    }

    // ===== cross-attention =====
    wtrans_kernel<<<dim3(C_/32, C_/32), 256, 0, stream>>>(ca_in_w + (size_t)l*C_*3*C_, wb0, C_, 3*C_);
    wtrans_kernel<<<dim3(C_/32, C_/32), 256, 0, stream>>>(ca_out_w + (size_t)l*C_*C_, wb1, C_, C_);
    gemm_kernel<<<dim3((2*C_+BN-1)/BN, (80+BM-1)/BM), 256, 0, stream>>>(memf, C_,
        ca_in_w + (size_t)l*C_*3*C_ + C_, 3*C_, ca_in_b + (size_t)l*3*C_ + C_, kvm, 2*C_,
        80, 2*C_, C_, 0);
    for (int c0 = 0; c0 < B_; c0 += CH) {
      float* tgtc = tgt + (size_t)c0*HW_*C_;
      hbf16* abuf = (hbf16*)S;
      hbf16* qb   = abuf + R*C_;
      hbf16* tmpb = qb + R*C_;
      f2b_kernel<<<(int)((R*C_/4+255)/256), 256, 0, stream>>>(tgtc, abuf, (int)(R*C_));
      gemm_mfma_t64<<<dim3(C_/64, (int)(R/128)), 256, 0, stream>>>((const short*)abuf, C_,
          (const short*)wb0, C_, ca_in_b + (size_t)l*3*C_, qb, C_, C_, 0);
      cross_attn_kernel<<<dim3(HW_, CH), 128, 0, stream>>>(qb, kvm, c0);
      gemm_mfma_t64<<<dim3(C_/64, (int)(R/128)), 256, 0, stream>>>((const short*)qb, C_,
          (const short*)wb1, C_, ca_out_b + (size_t)l*C_, tmpb, C_, C_, 0);
      ln_res_kernel<<<(int)R, 256, 0, stream>>>(tgtc, tmpb,
          ln_w + (size_t)(l*3+1)*C_, ln_b + (size_t)(l*3+1)*C_);
    }

    // ===== FFN =====
    wtrans_kernel<<<dim3(FF_/32, C_/32), 256, 0, stream>>>(ff1_w + (size_t)l*C_*FF_, wb0, C_, FF_);
    wtrans_kernel<<<dim3(C_/32, FF_/32), 256, 0, stream>>>(ff2_w + (size_t)l*FF_*C_, wb1, FF_, C_);
    for (int c0 = 0; c0 < B_; c0 += CH) {
      float* tgtc = tgt + (size_t)c0*HW_*C_;
      hbf16* abuf = (hbf16*)S;
      hbf16* ffh  = abuf + R*C_;
      hbf16* tmpb = ffh + R*FF_;
      f2b_kernel<<<(int)((R*C_/4+255)/256), 256, 0, stream>>>(tgtc, abuf, (int)(R*C_));
      gemm_mfma_t<<<dim3(FF_/128, (int)(R/128)), 256, 0, stream>>>((const short*)abuf, C_,
          (const short*)wb0, C_, ff1_b + (size_t)l*FF_, ffh, FF_, C_, 1);
      gemm_mfma_t64<<<dim3(C_/64, (int)(R/128)), 256, 0, stream>>>((const short*)ffh, FF_,
          (const short*)wb1, FF_, ff2_b + (size_t)l*C_, tmpb, C_, FF_, 0);
      ln_res_kernel<<<(int)R, 256, 0, stream>>>(tgtc, tmpb,
          ln_w + (size_t)(l*3+2)*C_, ln_b + (size_t)(l*3+2)*C_);
    }
  }

  // ---- final: tgt [B][HW][C] -> out [B][C][H][W], LDS-tiled transpose ----
  btrans_kernel<<<dim3(C_/32, HW_/32, B_), 256, 0, stream>>>(tgt, (float*)d_out, HW_, C_);
}

// Round 6
// 1482.686 us; speedup vs baseline: 1.2838x; 1.0405x over previous
//
#include <hip/hip_runtime.h>
#include <hip/hip_bf16.h>
#include <math.h>

typedef __hip_bfloat16 hbf16;

#define B_ 8
#define C_ 768
#define HW_ 1024
#define NH_ 8
#define HD_ 96
#define NPTS 2048      // PH*PW*K
#define AROUND_ 5
#define TOPK_ 5
#define MOD_ 2
#define FF_ 3072
#define TOK_ (B_*HW_)  // 8192

typedef __attribute__((ext_vector_type(8))) short short8v;
typedef __attribute__((ext_vector_type(4))) short short4v;
typedef __attribute__((ext_vector_type(4))) float f32x4;

__device__ __forceinline__ float b2f(hbf16 v){ return __bfloat162float(v); }

// ---- async global->LDS, 16B per lane; LDS dest = wave-uniform base + lane*16 ----
__device__ __forceinline__ void gload16(const void* g, void* l) {
  __builtin_amdgcn_global_load_lds(
      (const __attribute__((address_space(1))) void*)g,
      (__attribute__((address_space(3))) void*)l, 16, 0, 0);
}

// ---- bilinear taps, torch grid_sample semantics (align_corners=False, zeros pad), H=W=32 ----
struct Taps { int x0,x1,y0,y1; float w00,w10,w01,w11; };
__device__ __forceinline__ Taps bilin_taps(float gx, float gy) {
  Taps t;
  float ix = ((gx+1.f)*32.f - 1.f)*0.5f;
  float iy = ((gy+1.f)*32.f - 1.f)*0.5f;
  float x0f = floorf(ix), y0f = floorf(iy);
  float wx1 = ix-x0f, wy1 = iy-y0f, wx0 = 1.f-wx1, wy0 = 1.f-wy1;
  int x0=(int)x0f, y0=(int)y0f, x1=x0+1, y1=y0+1;
  bool vx0=(x0>=0)&&(x0<=31), vx1=(x1>=0)&&(x1<=31);
  bool vy0=(y0>=0)&&(y0<=31), vy1=(y1>=0)&&(y1<=31);
  t.w00 = (vx0&&vy0) ? wx0*wy0 : 0.f;
  t.w10 = (vx1&&vy0) ? wx1*wy0 : 0.f;
  t.w01 = (vx0&&vy1) ? wx0*wy1 : 0.f;
  t.w11 = (vx1&&vy1) ? wx1*wy1 : 0.f;
  t.x0 = min(max(x0,0),31); t.x1 = min(max(x1,0),31);
  t.y0 = min(max(y0,0),31); t.y1 = min(max(y1,0),31);
  return t;
}

__device__ __forceinline__ float block_reduce_sum_256(float v, float* red) {
  int tid = threadIdx.x;
  red[tid] = v; __syncthreads();
  for (int s = 128; s > 0; s >>= 1) { if (tid < s) red[tid] += red[tid+s]; __syncthreads(); }
  float r = red[0]; __syncthreads();
  return r;
}

// ---- fp32 -> bf16 elementwise convert (n multiple of 4) ----
__global__ __launch_bounds__(256) void f2b_kernel(const float* __restrict__ in,
    hbf16* __restrict__ out, int n) {
  int i = (blockIdx.x*256 + threadIdx.x)*4;
  if (i >= n) return;
  float4 v = *(const float4*)&in[i];
  out[i+0] = __float2bfloat16(v.x);
  out[i+1] = __float2bfloat16(v.y);
  out[i+2] = __float2bfloat16(v.z);
  out[i+3] = __float2bfloat16(v.w);
}

// ---- transpose+convert: fp32 in[K][N] -> bf16 out[N][K] (K,N multiples of 32) ----
__global__ __launch_bounds__(256) void wtrans_kernel(const float* __restrict__ in,
    hbf16* __restrict__ out, int K, int N) {
  __shared__ float t[32][33];
  int tx = threadIdx.x & 31, ty = threadIdx.x >> 5;
  int k0 = blockIdx.y*32, n0 = blockIdx.x*32;
  #pragma unroll
  for (int i = 0; i < 32; i += 8) t[ty+i][tx] = in[(size_t)(k0+ty+i)*N + n0+tx];
  __syncthreads();
  #pragma unroll
  for (int i = 0; i < 32; i += 8)
    out[(size_t)(n0+ty+i)*K + k0 + tx] = __float2bfloat16(t[tx][ty+i]);
}

// ---- transpose + split-convert: fp32 in[K][N] -> hi[N][K], lo[N][K] ----
__global__ __launch_bounds__(256) void wtrans_split_kernel(const float* __restrict__ in,
    hbf16* __restrict__ hi, hbf16* __restrict__ lo, int K, int N) {
  __shared__ float t[32][33];
  int tx = threadIdx.x & 31, ty = threadIdx.x >> 5;
  int k0 = blockIdx.y*32, n0 = blockIdx.x*32;
  #pragma unroll
  for (int i = 0; i < 32; i += 8) t[ty+i][tx] = in[(size_t)(k0+ty+i)*N + n0+tx];
  __syncthreads();
  #pragma unroll
  for (int i = 0; i < 32; i += 8) {
    float v = t[tx][ty+i];
    hbf16 h = __float2bfloat16(v);
    hi[(size_t)(n0+ty+i)*K + k0 + tx] = h;
    lo[(size_t)(n0+ty+i)*K + k0 + tx] = __float2bfloat16(v - b2f(h));
  }
}

// ---- batched fp32 transpose: per z, in [R][S] -> out [S][R] (R,S multiples of 32) ----
// grid (S/32, R/32, batch)
__global__ __launch_bounds__(256) void btrans_kernel(const float* __restrict__ in,
    float* __restrict__ out, int R, int S) {
  __shared__ float t[32][33];
  int tx = threadIdx.x & 31, ty = threadIdx.x >> 5;
  int r0 = blockIdx.y*32, s0 = blockIdx.x*32;
  const float* ib = in + (size_t)blockIdx.z*R*S;
  float* ob = out + (size_t)blockIdx.z*R*S;
  #pragma unroll
  for (int i = 0; i < 32; i += 8) t[ty+i][tx] = ib[(size_t)(r0+ty+i)*S + s0+tx];
  __syncthreads();
  #pragma unroll
  for (int i = 0; i < 32; i += 8) ob[(size_t)(s0+ty+i)*R + r0+tx] = t[tx][ty+i];
}

__global__ __launch_bounds__(256) void zero_kernel(float* __restrict__ p, int n) {
  int i = blockIdx.x*256 + threadIdx.x;
  if (i < n) p[i] = 0.f;
}

// ---- stage A: blockwise sample from CHANNEL-LAST image oT [B][HW][C] ----
// grid (G, NPTS/4): blockIdx.x = instance (XCD-pinned), 4 points per block.
__global__ __launch_bounds__(256) void sample_all_kernel(const float* __restrict__ oT,
    const float* __restrict__ brand, hbf16* __restrict__ pf_hi, hbf16* __restrict__ pf_lo,
    float* __restrict__ coords_all, int g0) {
  int ly = blockIdx.x;
  int inst = g0 + ly;
  int b = inst & 7;
  const float* xT = oT + (size_t)b*HW_*C_;
  int tid = threadIdx.x;
  int p = tid >> 6, lane = tid & 63;
  int n = blockIdx.y*4 + p;
  int k = n & 1, pw = (n >> 1) & 31, ph = n >> 6;
  const float* br = brand + (size_t)inst*4096;
  int roff = ((ph*32 + pw)*2 + k)*2;
  float r0 = br[roff], r1 = br[roff+1];
  const float bs = 0.0625f;
  float c0 = r0*bs + ((float)ph*bs - 1.0f);
  float c1 = r1*bs + ((float)pw*bs - 1.0f);
  Taps t = bilin_taps(c0, c1);
  const float* r00 = xT + (size_t)(t.y0*32+t.x0)*C_;
  const float* r10 = xT + (size_t)(t.y0*32+t.x1)*C_;
  const float* r01 = xT + (size_t)(t.y1*32+t.x0)*C_;
  const float* r11 = xT + (size_t)(t.y1*32+t.x1)*C_;
  size_t base = ((size_t)ly*NPTS + n)*C_;
  short* ph_ = (short*)pf_hi;
  short* pl_ = (short*)pf_lo;
  #pragma unroll
  for (int kk = 0; kk < 3; ++kk) {
    int c = kk*256 + lane*4;
    float4 v00 = *(const float4*)(r00 + c);
    float4 v10 = *(const float4*)(r10 + c);
    float4 v01 = *(const float4*)(r01 + c);
    float4 v11 = *(const float4*)(r11 + c);
    float o[4];
    o[0] = t.w00*v00.x + t.w10*v10.x + t.w01*v01.x + t.w11*v11.x;
    o[1] = t.w00*v00.y + t.w10*v10.y + t.w01*v01.y + t.w11*v11.y;
    o[2] = t.w00*v00.z + t.w10*v10.z + t.w01*v01.z + t.w11*v11.z;
    o[3] = t.w00*v00.w + t.w10*v10.w + t.w01*v01.w + t.w11*v11.w;
    short4v hs, ls;
    #pragma unroll
    for (int e = 0; e < 4; ++e) {
      hbf16 h = __float2bfloat16(o[e]);
      hs[e] = *(short*)&h;
      hbf16 l = __float2bfloat16(o[e] - b2f(h));
      ls[e] = *(short*)&l;
    }
    *(short4v*)&ph_[base + c] = hs;
    *(short4v*)&pl_[base + c] = ls;
  }
  if (lane == 0) {
    size_t co = ((size_t)inst*NPTS + n)*2;
    coords_all[co] = c0; coords_all[co+1] = c1;
  }
}

// ---- XCD swizzle: each XCD owns gy/8 contiguous row-panels, iterates cols fastest ----
// wgid%8 = XCD (round-robin dispatch); requires gx*gy % 8 == 0 and gy % 8 == 0.
__device__ __forceinline__ void xcd_tile(int gx, int gy, int& row, int& col) {
  int wgid = blockIdx.y * gx + blockIdx.x;
  int xcd = wgid & 7;
  int li = wgid >> 3;
  row = xcd * (gy >> 3) + li / gx;
  col = li % gx;
}

// ---- fused score GEMM (split-bf16, 3-term) + relu + w2-dot -> atomicAdd logits ----
// Linear LDS [128][32] per buffer; staging via global_load_lds (16B/lane).
__global__ __launch_bounds__(256) void score_gemm_kernel(const short* __restrict__ Ahi,
    const short* __restrict__ Alo, const short* __restrict__ Bhi, const short* __restrict__ Blo,
    const float* __restrict__ b1, const float* __restrict__ w2, float* __restrict__ logit) {
  __shared__ short AsH[128*32];
  __shared__ short AsL[128*32];
  __shared__ short BsH[128*32];
  __shared__ short BsL[128*32];
  int tid = threadIdx.x;
  int lane = tid & 63, w = tid >> 6;
  int wr = (w >> 1) * 64, wc = (w & 1) * 64;
  int m16 = lane & 15, quad = lane >> 4, q8 = quad * 8;
  int brow, bcol;
  xcd_tile(gridDim.x, gridDim.y, brow, bcol);
  int bm = brow * 128, bn = bcol * 128;
  int sr = w * 32;                    // this wave's 32-row slice
  int lr = lane >> 2, lc = (lane & 3) * 8;
  f32x4 acc[4][4] = {};
  for (int k0 = 0; k0 < 768; k0 += 32) {
    {
      const short* pa = &Ahi[(size_t)(bm + sr + lr)*768 + k0 + lc];
      const short* pl = &Alo[(size_t)(bm + sr + lr)*768 + k0 + lc];
      const short* pb = &Bhi[(size_t)(bn + sr + lr)*768 + k0 + lc];
      const short* pq = &Blo[(size_t)(bn + sr + lr)*768 + k0 + lc];
      gload16(pa,            &AsH[sr*32]);
      gload16(pa + 16*768,   &AsH[(sr+16)*32]);
      gload16(pl,            &AsL[sr*32]);
      gload16(pl + 16*768,   &AsL[(sr+16)*32]);
      gload16(pb,            &BsH[sr*32]);
      gload16(pb + 16*768,   &BsH[(sr+16)*32]);
      gload16(pq,            &BsL[sr*32]);
      gload16(pq + 16*768,   &BsL[(sr+16)*32]);
    }
    __syncthreads();
    short8v ah[4], al[4], bh[4], bl[4];
    #pragma unroll
    for (int i=0;i<4;++i) {
      ah[i] = *(const short8v*)&AsH[(wr + i*16 + m16)*32 + q8];
      al[i] = *(const short8v*)&AsL[(wr + i*16 + m16)*32 + q8];
      bh[i] = *(const short8v*)&BsH[(wc + i*16 + m16)*32 + q8];
      bl[i] = *(const short8v*)&BsL[(wc + i*16 + m16)*32 + q8];
    }
    #pragma unroll
    for (int i=0;i<4;++i)
      #pragma unroll
      for (int j=0;j<4;++j) {
        acc[i][j] = __builtin_amdgcn_mfma_f32_16x16x32_bf16(ah[i], bh[j], acc[i][j], 0, 0, 0);
        acc[i][j] = __builtin_amdgcn_mfma_f32_16x16x32_bf16(ah[i], bl[j], acc[i][j], 0, 0, 0);
        acc[i][j] = __builtin_amdgcn_mfma_f32_16x16x32_bf16(al[i], bh[j], acc[i][j], 0, 0, 0);
      }
    __syncthreads();
  }
  float b1v[4], w2v[4];
  #pragma unroll
  for (int j=0;j<4;++j) {
    int col = bn + wc + j*16 + m16;
    b1v[j] = b1[col]; w2v[j] = w2[col];
  }
  #pragma unroll
  for (int i=0;i<4;++i) {
    #pragma unroll
    for (int r=0;r<4;++r) {
      float v = 0.f;
      #pragma unroll
      for (int j=0;j<4;++j) {
        float h = fmaxf(acc[i][j][r] + b1v[j], 0.f);
        v += h * w2v[j];
      }
      v += __shfl_xor(v, 1); v += __shfl_xor(v, 2);
      v += __shfl_xor(v, 4); v += __shfl_xor(v, 8);
      if (m16 == 0) atomicAdd(&logit[bm + wr + i*16 + quad*4 + r], v);
    }
  }
}

// ---- top-5 of 2048 per instance (on logits; sigmoid monotone), jax tie semantics ----
__global__ void topk_all_kernel(const float* __restrict__ logit, int* __restrict__ idx) {
  int lane = threadIdx.x;   // 64 lanes
  const float* score = logit + (size_t)blockIdx.x*NPTS;
  float v[32];
  #pragma unroll
  for (int i = 0; i < 32; ++i) v[i] = score[(i<<6) | lane];
  for (int t = 0; t < TOPK_; ++t) {
    float bv = v[0]; int bi = lane;
    #pragma unroll
    for (int i = 1; i < 32; ++i) { if (v[i] > bv) { bv = v[i]; bi = (i<<6)|lane; } }
    for (int off = 32; off; off >>= 1) {
      float ov = __shfl_xor(bv, off);
      int   oi = __shfl_xor(bi, off);
      if (ov > bv || (ov == bv && oi < bi)) { bv = ov; bi = oi; }
    }
    if (lane == 0) idx[blockIdx.x*8 + t] = bi;
    if ((bi & 63) == lane) v[bi >> 6] = -1e30f;
  }
}

// ---- soft_align + modality query -> memf rows; grid (TOPK, G) ----
// mainxT is channel-last [B][HW][C] (the tgt buffer, pre-tgt0)
__global__ __launch_bounds__(256) void softalign_all_kernel(const float* __restrict__ mainxT,
    const float* __restrict__ pos, const hbf16* __restrict__ pf_hi, const hbf16* __restrict__ pf_lo,
    const float* __restrict__ coords_all, const int* __restrict__ idx_all,
    const float* __restrict__ arand, const float* __restrict__ mq,
    float* __restrict__ memf, int g0) {
  int t = blockIdx.x;
  int ly = blockIdx.y;
  int inst = g0 + ly;
  int mod = inst >> 3, b = inst & 7;
  const float* mT_b = mainxT + (size_t)b*HW_*C_;
  const float* arand_ib = arand + (size_t)inst*AROUND_*TOPK_*2;
  const float* coords = coords_all + (size_t)inst*NPTS*2;
  int tid = threadIdx.x;
  int n = idx_all[ly*8 + t];
  float px0 = coords[n*2], px1 = coords[n*2+1];
  size_t pfb = ((size_t)ly*NPTS + n)*C_;
  float pfv[3];
  #pragma unroll
  for (int i=0;i<3;++i) {
    int c = tid + i*256;
    pfv[i] = b2f(pf_hi[pfb + c]) + b2f(pf_lo[pfb + c]);
  }
  __shared__ float red[256];
  float pp = block_reduce_sum_256(pfv[0]*pfv[0]+pfv[1]*pfv[1]+pfv[2]*pfv[2], red);
  float embr[AROUND_][3];
  float num_a[AROUND_], aa_a[AROUND_];
  for (int a=0; a<AROUND_; ++a) {
    int ar = (a*TOPK_ + t)*2;
    float g0c = px0 + (arand_ib[ar]*2.f - 0.5f)*0.2f;
    float g1c = px1 + (arand_ib[ar+1]*2.f - 0.5f)*0.2f;
    g0c = fminf(fmaxf(g0c,-1.f),1.f);
    g1c = fminf(fmaxf(g1c,-1.f),1.f);
    Taps tp = bilin_taps(g0c, g1c);
    int i00=tp.y0*32+tp.x0, i10=tp.y0*32+tp.x1, i01=tp.y1*32+tp.x0, i11=tp.y1*32+tp.x1;
    float s_num = 0.f, s_aa = 0.f;
    #pragma unroll
    for (int i=0;i<3;++i) {
      int c = tid + i*256;
      float af = tp.w00*mT_b[(size_t)i00*C_+c] + tp.w10*mT_b[(size_t)i10*C_+c]
               + tp.w01*mT_b[(size_t)i01*C_+c] + tp.w11*mT_b[(size_t)i11*C_+c];
      float em = tp.w00*pos[(size_t)i00*C_+c] + tp.w10*pos[(size_t)i10*C_+c]
               + tp.w01*pos[(size_t)i01*C_+c] + tp.w11*pos[(size_t)i11*C_+c];
      embr[a][i] = em;
      s_num += pfv[i]*af;
      s_aa  += af*af;
    }
    num_a[a] = block_reduce_sum_256(s_num, red);
    aa_a[a]  = block_reduce_sum_256(s_aa, red);
  }
  float pn = fmaxf(sqrtf(pp), 1e-8f);
  float w[AROUND_]; float mx = -1e30f;
  #pragma unroll
  for (int a=0;a<AROUND_;++a){ float den = pn * fmaxf(sqrtf(aa_a[a]),1e-8f); w[a]=num_a[a]/den; mx=fmaxf(mx,w[a]); }
  float se = 0.f;
  #pragma unroll
  for (int a=0;a<AROUND_;++a){ w[a]=expf(w[a]-mx); se+=w[a]; }
  float inv = 1.f/se;
  float* mo = memf + ((size_t)b*(MOD_*TOPK_) + mod*TOPK_ + t)*C_;
  #pragma unroll
  for (int i=0;i<3;++i) {
    int c = tid + i*256;
    float o = pfv[i];
    #pragma unroll
    for (int a=0;a<AROUND_;++a) o += embr[a][i]*(w[a]*inv);
    o += mq[(size_t)(mod+1)*C_ + c];
    mo[c] = o;
  }
}

// ---- generic fp32 GEMM (kvm only) ----
#define BM 64
#define BN 64
#define BK 16
__global__ __launch_bounds__(256) void gemm_kernel(const float* __restrict__ A, int lda,
    const float* __restrict__ Bw, int ldb, const float* __restrict__ bias,
    float* __restrict__ Cm, int ldc, int M, int N, int K, int act) {
  __shared__ float As[BK][BM];
  __shared__ float Bs[BK][BN];
  int tid = threadIdx.x;
  int bm = blockIdx.y * BM, bn = blockIdx.x * BN;
  int arw = tid >> 2, acl = (tid & 3) << 2;
  int brw = tid >> 4, bcl = (tid & 15) << 2;
  int ty = tid >> 4, tx = tid & 15;
  float acc[4][4] = {{0.f}};
  for (int k0 = 0; k0 < K; k0 += BK) {
    float a0=0.f,a1=0.f,a2=0.f,a3=0.f;
    if (bm + arw < M) {
      const float* ap = A + (size_t)(bm+arw)*lda + k0 + acl;
      a0=ap[0]; a1=ap[1]; a2=ap[2]; a3=ap[3];
    }
    As[acl+0][arw]=a0; As[acl+1][arw]=a1; As[acl+2][arw]=a2; As[acl+3][arw]=a3;
    const float* bp = Bw + (size_t)(k0+brw)*ldb + bn + bcl;
    Bs[brw][bcl+0]=bp[0]; Bs[brw][bcl+1]=bp[1]; Bs[brw][bcl+2]=bp[2]; Bs[brw][bcl+3]=bp[3];
    __syncthreads();
    #pragma unroll
    for (int kk = 0; kk < BK; ++kk) {
      float4 av = *reinterpret_cast<const float4*>(&As[kk][ty<<2]);
      float4 bv = *reinterpret_cast<const float4*>(&Bs[kk][tx<<2]);
      acc[0][0]+=av.x*bv.x; acc[0][1]+=av.x*bv.y; acc[0][2]+=av.x*bv.z; acc[0][3]+=av.x*bv.w;
      acc[1][0]+=av.y*bv.x; acc[1][1]+=av.y*bv.y; acc[1][2]+=av.y*bv.z; acc[1][3]+=av.y*bv.w;
      acc[2][0]+=av.z*bv.x; acc[2][1]+=av.z*bv.y; acc[2][2]+=av.z*bv.z; acc[2][3]+=av.z*bv.w;
      acc[3][0]+=av.w*bv.x; acc[3][1]+=av.w*bv.y; acc[3][2]+=av.w*bv.z; acc[3][3]+=av.w*bv.w;
    }
    __syncthreads();
  }
  #pragma unroll
  for (int i=0;i<4;++i) {
    int r = bm + (ty<<2) + i;
    if (r >= M) continue;
    float* cp = Cm + (size_t)r*ldc + bn + (tx<<2);
    #pragma unroll
    for (int j=0;j<4;++j) {
      float v = acc[i][j] + bias[bn + (tx<<2) + j];
      if (act) v = fmaxf(v, 0.f);
      cp[j] = v;
    }
  }
}

// ---- bf16 MFMA GEMM, B pre-transposed: C = act(A[M,K] @ Bt[N,K]^T + bias), 128x128 tile ----
// Linear LDS [128][32]; staging via global_load_lds.
__global__ __launch_bounds__(256) void gemm_mfma_t(const short* __restrict__ A, int lda,
    const short* __restrict__ Bt, int ldbt, const float* __restrict__ bias,
    hbf16* __restrict__ Cm, int ldc, int K, int act) {
  __shared__ short As[128*32];
  __shared__ short Bs[128*32];
  int tid = threadIdx.x;
  int lane = tid & 63, w = tid >> 6;
  int wr = (w >> 1) * 64, wc = (w & 1) * 64;
  int m16 = lane & 15, q8 = (lane >> 4) * 8;
  int brow, bcol;
  xcd_tile(gridDim.x, gridDim.y, brow, bcol);
  int bm = brow * 128, bn = bcol * 128;
  int sr = w * 32;
  int lr = lane >> 2, lc = (lane & 3) * 8;
  f32x4 acc[4][4] = {};
  for (int k0 = 0; k0 < K; k0 += 32) {
    {
      const short* pa = &A [(size_t)(bm + sr + lr)*lda  + k0 + lc];
      const short* pb = &Bt[(size_t)(bn + sr + lr)*ldbt + k0 + lc];
      gload16(pa,                    &As[sr*32]);
      gload16(pa + (size_t)16*lda,   &As[(sr+16)*32]);
      gload16(pb,                    &Bs[sr*32]);
      gload16(pb + (size_t)16*ldbt,  &Bs[(sr+16)*32]);
    }
    __syncthreads();
    short8v af[4], bf[4];
    #pragma unroll
    for (int i=0;i<4;++i) af[i] = *(const short8v*)&As[(wr + i*16 + m16)*32 + q8];
    #pragma unroll
    for (int j=0;j<4;++j) bf[j] = *(const short8v*)&Bs[(wc + j*16 + m16)*32 + q8];
    #pragma unroll
    for (int i=0;i<4;++i)
      #pragma unroll
      for (int j=0;j<4;++j)
        acc[i][j] = __builtin_amdgcn_mfma_f32_16x16x32_bf16(af[i], bf[j], acc[i][j], 0, 0, 0);
    __syncthreads();
  }
  #pragma unroll
  for (int j=0;j<4;++j) {
    int col = bn + wc + j*16 + m16;
    float bs = bias[col];
    #pragma unroll
    for (int i=0;i<4;++i) {
      int row0 = bm + wr + i*16 + (lane>>4)*4;
      #pragma unroll
      for (int r=0;r<4;++r) {
        float v = acc[i][j][r] + bs;
        if (act) v = fmaxf(v, 0.f);
        Cm[(size_t)(row0+r)*ldc + col] = __float2bfloat16(v);
      }
    }
  }
}

// ---- bf16 MFMA GEMM, 128x64 tile (for small-N GEMMs; doubles grid vs 128x128) ----
// 4 waves, each computes 32 rows x 64 cols (acc[2][4]). Linear LDS + global_load_lds.
__global__ __launch_bounds__(256) void gemm_mfma_t64(const short* __restrict__ A, int lda,
    const short* __restrict__ Bt, int ldbt, const float* __restrict__ bias,
    hbf16* __restrict__ Cm, int ldc, int K, int act) {
  __shared__ short As[128*32];
  __shared__ short Bs[64*32];
  int tid = threadIdx.x;
  int lane = tid & 63, w = tid >> 6;
  int m16 = lane & 15, q8 = (lane >> 4) * 8;
  int brow, bcol;
  xcd_tile(gridDim.x, gridDim.y, brow, bcol);
  int bm = brow * 128, bn = bcol * 64;
  int sr = w * 32;            // A slice
  int srB = w * 16;           // B slice (4 waves x 16 rows)
  int lr = lane >> 2, lc = (lane & 3) * 8;
  f32x4 acc[2][4] = {};
  for (int k0 = 0; k0 < K; k0 += 32) {
    {
      const short* pa = &A [(size_t)(bm + sr  + lr)*lda  + k0 + lc];
      const short* pb = &Bt[(size_t)(bn + srB + lr)*ldbt + k0 + lc];
      gload16(pa,                   &As[sr*32]);
      gload16(pa + (size_t)16*lda,  &As[(sr+16)*32]);
      gload16(pb,                   &Bs[srB*32]);
    }
    __syncthreads();
    short8v af[2], bf[4];
    #pragma unroll
    for (int i=0;i<2;++i) af[i] = *(const short8v*)&As[(w*32 + i*16 + m16)*32 + q8];
    #pragma unroll
    for (int j=0;j<4;++j) bf[j] = *(const short8v*)&Bs[(j*16 + m16)*32 + q8];
    #pragma unroll
    for (int i=0;i<2;++i)
      #pragma unroll
      for (int j=0;j<4;++j)
        acc[i][j] = __builtin_amdgcn_mfma_f32_16x16x32_bf16(af[i], bf[j], acc[i][j], 0, 0, 0);
    __syncthreads();
  }
  #pragma unroll
  for (int j=0;j<4;++j) {
    int col = bn + j*16 + m16;
    float bs = bias[col];
    #pragma unroll
    for (int i=0;i<2;++i) {
      int row0 = bm + w*32 + i*16 + (lane>>4)*4;
      #pragma unroll
      for (int r=0;r<4;++r) {
        float v = acc[i][j][r] + bs;
        if (act) v = fmaxf(v, 0.f);
        Cm[(size_t)(row0+r)*ldc + col] = __float2bfloat16(v);
      }
    }
  }
}

// ---- fused flash self-attention (MFMA): grid (head+batch, qtile=8), 512 thr / 8 waves ----
// x = h + NH_*bz so all q-tiles of one (b,h) share an XCD (ids congruent mod 8).
// 8 waves x 16 q-rows each; Q fragments in registers; LDS = KP ∪ Vt (32.3 KB).
// Grid 512 blocks x 8 waves = 4096 waves = 16 waves/CU (2 blocks/CU).
__global__ __launch_bounds__(512, 4) void flash_attn_kernel(const hbf16* __restrict__ qkv_all,
    hbf16* __restrict__ o_all) {
  const int hb = blockIdx.x;
  const int h  = hb & 7;
  const int bz = hb >> 3;
  const int q0 = blockIdx.y * 128;
  const short* qkv = (const short*)(qkv_all + (size_t)bz*HW_*2304);
  hbf16* ob = o_all + (size_t)bz*HW_*C_;
  const int tid = threadIdx.x;
  const int lane = tid & 63, w = tid >> 6;
  const int m16 = lane & 15, quad = lane >> 4, q8 = quad * 8;
  const float scale = 0.10206207261596577f;  // 1/sqrt(96)

  // 16128 shorts = 32256 B. KP = lds[0..9216): K tile [64][104] (QK) / P [128][72] (PV).
  // Vt = lds[9216..16128): V^T [96][72]. Q staging [128][104]=13312 aliases both.
  __shared__ short lds[16128];
  short* KP = lds;
  short* Vt = lds + 9216;

  // stage Q -> LDS (coalesced), then hoist this wave's 16-row fragments to registers
  for (int idx = tid; idx < 128*12; idx += 512) {
    int row = idx / 12, dc = idx % 12;
    *(short8v*)&lds[row*104 + dc*8] = *(const short8v*)&qkv[(size_t)(q0+row)*2304 + h*HD_ + dc*8];
  }
  __syncthreads();
  short8v qf[3];
  #pragma unroll
  for (int kkk=0;kkk<3;++kkk)
    qf[kkk] = *(const short8v*)&lds[(w*16 + m16)*104 + q8 + kkk*32];
  __syncthreads();

  float m_st[4], l_st[4];
  f32x4 o_acc[6] = {};
  #pragma unroll
  for (int r=0;r<4;++r){ m_st[r] = -1e30f; l_st[r] = 0.f; }

  for (int t = 0; t < 16; ++t) {
    int j0 = t * 64;
    for (int idx = tid; idx < 64*12; idx += 512) {
      int row = idx / 12, dc = idx % 12;
      *(short8v*)&KP[row*104 + dc*8] = *(const short8v*)&qkv[(size_t)(j0+row)*2304 + C_ + h*HD_ + dc*8];
    }
    // V^T stage: j fast within wave -> conflict-free LDS writes
    for (int idx = tid; idx < 64*12; idx += 512) {
      int j = idx & 63, dc = idx >> 6;
      short8v v = *(const short8v*)&qkv[(size_t)(j0+j)*2304 + 2*C_ + h*HD_ + dc*8];
      #pragma unroll
      for (int s = 0; s < 8; ++s) Vt[(dc*8+s)*72 + j] = v[s];
    }
    __syncthreads();

    f32x4 accs[4] = {};
    #pragma unroll
    for (int kkk = 0; kkk < 3; ++kkk) {
      int kk = kkk*32;
      short8v bf[4];
      #pragma unroll
      for (int n=0;n<4;++n) bf[n] = *(const short8v*)&KP[(n*16 + m16)*104 + q8 + kk];
      #pragma unroll
      for (int n=0;n<4;++n)
        accs[n] = __builtin_amdgcn_mfma_f32_16x16x32_bf16(qf[kkk], bf[n], accs[n], 0, 0, 0);
    }
    __syncthreads();

    #pragma unroll
    for (int r=0;r<4;++r) {
      float mx = -1e30f;
      #pragma unroll
      for (int n=0;n<4;++n) mx = fmaxf(mx, accs[n][r]*scale);
      #pragma unroll
      for (int off=1; off<16; off<<=1) mx = fmaxf(mx, __shfl_xor(mx, off));
      float m_new = fmaxf(m_st[r], mx);
      float alpha = __expf(m_st[r] - m_new);
      float psum = 0.f;
      int prow = (w*16 + quad*4 + r)*72 + m16;
      #pragma unroll
      for (int n=0;n<4;++n) {
        float pv = __expf(accs[n][r]*scale - m_new);
        psum += pv;
        *(hbf16*)&KP[prow + n*16] = __float2bfloat16(pv);
      }
      #pragma unroll
      for (int off=1; off<16; off<<=1) psum += __shfl_xor(psum, off);
      l_st[r] = l_st[r]*alpha + psum;
      m_st[r] = m_new;
      #pragma unroll
      for (int dt=0; dt<6; ++dt) o_acc[dt][r] *= alpha;
    }

    #pragma unroll
    for (int k0 = 0; k0 < 64; k0 += 32) {
      short8v pf_, vf[6];
      pf_ = *(const short8v*)&KP[(w*16 + m16)*72 + q8 + k0];
      #pragma unroll
      for (int dt=0; dt<6; ++dt) vf[dt] = *(const short8v*)&Vt[(dt*16 + m16)*72 + q8 + k0];
      #pragma unroll
      for (int dt=0; dt<6; ++dt)
        o_acc[dt] = __builtin_amdgcn_mfma_f32_16x16x32_bf16(pf_, vf[dt], o_acc[dt], 0, 0, 0);
    }
    __syncthreads();
  }

  #pragma unroll
  for (int r=0;r<4;++r) {
    float inv = 1.f / l_st[r];
    int row = q0 + w*16 + quad*4 + r;
    #pragma unroll
    for (int dt=0; dt<6; ++dt)
      ob[(size_t)row*C_ + h*HD_ + dt*16 + m16] = __float2bfloat16(o_acc[dt][r]*inv);
  }
}

// ---- cross-attention over 10 memory tokens, grid (1024, CH), IN PLACE on bf16 q rows ----
__global__ __launch_bounds__(128) void cross_attn_kernel(hbf16* __restrict__ qb,
    const float* __restrict__ kvm, int b0) {
  int row = blockIdx.x;
  int lb = blockIdx.y;
  int b = b0 + lb;
  int tid = threadIdx.x;
  __shared__ float sc[16];
  __shared__ float qs[C_];
  hbf16* qp = qb + ((size_t)lb*HW_ + row)*C_;
  for (int c = tid; c < C_; c += 128) qs[c] = b2f(qp[c]);
  __syncthreads();
  const float scale = 0.10206207261596577f;
  for (int h = 0; h < NH_; ++h) {
    if (tid < 10) {
      const float* kp = kvm + (size_t)(b*10 + tid)*1536 + h*HD_;
      float s = 0.f;
      for (int d = 0; d < HD_; ++d) s += qs[h*HD_+d]*kp[d];
      sc[tid] = s*scale;
    }
    __syncthreads();
    if (tid == 0) {
      float m = -1e30f;
      for (int j=0;j<10;++j) m = fmaxf(m, sc[j]);
      float se = 0.f;
      for (int j=0;j<10;++j){ sc[j]=expf(sc[j]-m); se+=sc[j]; }
      float inv = 1.f/se;
      for (int j=0;j<10;++j) sc[j]*=inv;
    }
    __syncthreads();
    if (tid < HD_) {
      const float* vp = kvm + (size_t)(b*10)*1536 + C_ + h*HD_ + tid;
      float acc = 0.f;
      for (int j=0;j<10;++j) acc += sc[j]*vp[(size_t)j*1536];
      qp[h*HD_+tid] = __float2bfloat16(acc);
    }
    __syncthreads();
  }
}

// ---- tgt init: IN PLACE on pre-transposed mainxT (=tgt): += mq[0] + pos ----
__global__ __launch_bounds__(256) void tgt0_kernel(float* __restrict__ tgt,
    const float* __restrict__ mq, const float* __restrict__ pos) {
  size_t i = ((size_t)blockIdx.x*256 + threadIdx.x)*4;
  if (i >= (size_t)TOK_*C_) return;
  int c = (int)(i % C_);
  int tpos = (int)((i / C_) % HW_);
  float4 v = *(float4*)&tgt[i];
  float4 m = *(const float4*)&mq[c];
  float4 pp = *(const float4*)&pos[(size_t)tpos*C_ + c];
  v.x += m.x + pp.x; v.y += m.y + pp.y;
  v.z += m.z + pp.z; v.w += m.w + pp.w;
  *(float4*)&tgt[i] = v;
}

// ---- residual + layernorm (in place on fp32 tgt rows, bf16 add) ----
__global__ __launch_bounds__(256) void ln_res_kernel(float* __restrict__ tgt, const hbf16* __restrict__ add,
    const float* __restrict__ w, const float* __restrict__ bvec) {
  __shared__ float red[256];
  int row = blockIdx.x, tid = threadIdx.x;
  float* tp = tgt + (size_t)row*C_;
  const hbf16* ap = add + (size_t)row*C_;
  float x[3]; float s = 0.f, s2 = 0.f;
  #pragma unroll
  for (int i=0;i<3;++i){ int c=tid+i*256; float v=tp[c]+b2f(ap[c]); x[i]=v; s+=v; s2+=v*v; }
  s  = block_reduce_sum_256(s,  red);
  s2 = block_reduce_sum_256(s2, red);
  float mean = s * (1.f/C_);
  float var  = s2 * (1.f/C_) - mean*mean;
  float rstd = rsqrtf(var + 1e-5f);
  #pragma unroll
  for (int i=0;i<3;++i){ int c=tid+i*256; tp[c] = (x[i]-mean)*rstd*w[c] + bvec[c]; }
}

extern "C" void kernel_launch(void* const* d_in, const int* in_sizes, int n_in,
                              void* d_out, int out_size, void* d_ws, size_t ws_size,
                              hipStream_t stream) {
  const float* mainx   = (const float*)d_in[0];
  const float* other0  = (const float*)d_in[1];
  const float* other1  = (const float*)d_in[2];
  const float* pos     = (const float*)d_in[3];
  const float* mq      = (const float*)d_in[4];
  const float* s_w1    = (const float*)d_in[5];
  const float* s_b1    = (const float*)d_in[6];
  const float* s_w2    = (const float*)d_in[7];
  const float* sa_in_w = (const float*)d_in[9];
  const float* sa_in_b = (const float*)d_in[10];
  const float* sa_out_w= (const float*)d_in[11];
  const float* sa_out_b= (const float*)d_in[12];
  const float* ca_in_w = (const float*)d_in[13];
  const float* ca_in_b = (const float*)d_in[14];
  const float* ca_out_w= (const float*)d_in[15];
  const float* ca_out_b= (const float*)d_in[16];
  const float* ff1_w   = (const float*)d_in[17];
  const float* ff1_b   = (const float*)d_in[18];
  const float* ff2_w   = (const float*)d_in[19];
  const float* ff2_b   = (const float*)d_in[20];
  const float* ln_w    = (const float*)d_in[21];
  const float* ln_b    = (const float*)d_in[22];
  const float* brand   = (const float*)d_in[23];
  const float* arand   = (const float*)d_in[24];

  // ---- workspace layout ----
  char* p = (char*)d_ws;
  auto alloc = [&](size_t bytes) { char* r = p; p += (bytes + 255) & ~(size_t)255; return (void*)r; };
  float* tgt    = (float*)alloc((size_t)TOK_*C_*4);       // 24 MB; holds mainxT during stage A
  hbf16* wb0    = (hbf16*)alloc((size_t)2359296*2);       // 4.5 MB (transposed weights)
  hbf16* wb1    = (hbf16*)alloc((size_t)2359296*2);       // 4.5 MB
  hbf16* w1t_hi = (hbf16*)alloc((size_t)C_*C_*2);
  hbf16* w1t_lo = (hbf16*)alloc((size_t)C_*C_*2);
  float* kvm    = (float*)alloc((size_t)80*1536*4);
  float* memf   = (float*)alloc((size_t)80*C_*4);
  float* coords = (float*)alloc((size_t)16*NPTS*2*4);
  float* logit  = (float*)alloc((size_t)16*NPTS*4);
  int*   idxb   = (int*)alloc(16*8*4);
  char*  S      = p;
  size_t used = (size_t)(p - (char*)d_ws);
  size_t Savail = (ws_size > used) ? ws_size - used : 0;
  int CH = 1;
  if (Savail >= (size_t)8*1024*9216 + 4096) CH = 8;
  else if (Savail >= (size_t)4*1024*9216 + 4096) CH = 4;
  else if (Savail >= (size_t)2*1024*9216 + 4096) CH = 2;
  const size_t R = (size_t)CH*1024;
  const size_t perG = (size_t)NPTS*C_*2*2;  // pf_hi+pf_lo per instance
  // stage-A scratch: oT (one image set, channel-last) at front of S, pf after
  const size_t oTb = (size_t)B_*HW_*C_*4;   // 25.2 MB, 256-aligned
  float* oT = (float*)S;
  char* Spf = S + oTb;
  size_t SA = (Savail > oTb) ? Savail - oTb : 0;
  int G = 1;
  if (SA >= 8*perG) G = 8;
  else if (SA >= 4*perG) G = 4;
  else if (SA >= 2*perG) G = 2;

  // ---- stage A ----
  // mainx [B][C][HW] -> channel-last in tgt (softalign reads it; tgt0 finishes in place)
  btrans_kernel<<<dim3(HW_/32, C_/32, B_), 256, 0, stream>>>(mainx, tgt, C_, HW_);
  wtrans_split_kernel<<<dim3(C_/32, C_/32), 256, 0, stream>>>(s_w1, w1t_hi, w1t_lo, C_, C_);
  zero_kernel<<<16*NPTS/256, 256, 0, stream>>>(logit, 16*NPTS);
  for (int g0 = 0; g0 < 16; g0 += G) {
    if ((g0 & 7) == 0)
      btrans_kernel<<<dim3(HW_/32, C_/32, B_), 256, 0, stream>>>(g0 < 8 ? other0 : other1,
          oT, C_, HW_);
    hbf16* pf_hi = (hbf16*)Spf;
    hbf16* pf_lo = pf_hi + (size_t)G*NPTS*C_;
    sample_all_kernel<<<dim3(G, NPTS/4), 256, 0, stream>>>(oT, brand,
        pf_hi, pf_lo, coords, g0);
    score_gemm_kernel<<<dim3(6, G*16), 256, 0, stream>>>((const short*)pf_hi, (const short*)pf_lo,
        (const short*)w1t_hi, (const short*)w1t_lo, s_b1, s_w2, logit + (size_t)g0*NPTS);
    topk_all_kernel<<<G, 64, 0, stream>>>(logit + (size_t)g0*NPTS, idxb + g0*8);
    softalign_all_kernel<<<dim3(TOPK_, G), 256, 0, stream>>>(tgt, pos, pf_hi, pf_lo,
        coords, idxb + g0*8, arand, mq, memf, g0);
  }

  // ---- stage B ----
  size_t total = (size_t)TOK_*C_;
  tgt0_kernel<<<(int)((total/4+255)/256), 256, 0, stream>>>(tgt, mq, pos);

  for (int l = 0; l < 2; ++l) {
    // ===== self-attention =====
    wtrans_kernel<<<dim3(3*C_/32, C_/32), 256, 0, stream>>>(sa_in_w + (size_t)l*C_*3*C_, wb0, C_, 3*C_);
    wtrans_kernel<<<dim3(C_/32, C_/32), 256, 0, stream>>>(sa_out_w + (size_t)l*C_*C_, wb1, C_, C_);
    for (int c0 = 0; c0 < B_; c0 += CH) {
      float* tgtc = tgt + (size_t)c0*HW_*C_;
      hbf16* abuf = (hbf16*)S;
      hbf16* qkv  = abuf + R*C_;
      hbf16* oatt = qkv + R*3*C_;
      hbf16* tmpb = oatt + R*C_;
      f2b_kernel<<<(int)((R*C_/4+255)/256), 256, 0, stream>>>(tgtc, abuf, (int)(R*C_));
      gemm_mfma_t<<<dim3(3*C_/128, (int)(R/128)), 256, 0, stream>>>((const short*)abuf, C_,
          (const short*)wb0, C_, sa_in_b + (size_t)l*3*C_, qkv, 3*C_, C_, 0);
      flash_attn_kernel<<<dim3(NH_*CH, HW_/128), 512, 0, stream>>>(qkv, oatt);
      gemm_mfma_t64<<<dim3(C_/64, (int)(R/128)), 256, 0, stream>>>((const short*)oatt, C_,
          (const short*)wb1, C_, sa_out_b + (size_t)l*C_, tmpb, C_, C_, 0);
      ln_res_kernel<<<(int)R, 256, 0, stream>>>(tgtc, tmpb,
          ln_w + (size_t)(l*3+0)*C_, ln_b + (size_t)(l*3+0)*C_);
    }

    // ===== cross-attention =====
    wtrans_kernel<<<dim3(C_/32, C_/32), 256, 0, stream>>>(ca_in_w + (size_t)l*C_*3*C_, wb0, C_, 3*C_);
    wtrans_kernel<<<dim3(C_/32, C_/32), 256, 0, stream>>>(ca_out_w + (size_t)l*C_*C_, wb1, C_, C_);
    gemm_kernel<<<dim3((2*C_+BN-1)/BN, (80+BM-1)/BM), 256, 0, stream>>>(memf, C_,
        ca_in_w + (size_t)l*C_*3*C_ + C_, 3*C_, ca_in_b + (size_t)l*3*C_ + C_, kvm, 2*C_,
        80, 2*C_, C_, 0);
    for (int c0 = 0; c0 < B_; c0 += CH) {
      float* tgtc = tgt + (size_t)c0*HW_*C_;
      hbf16* abuf = (hbf16*)S;
      hbf16* qb   = abuf + R*C_;
      hbf16* tmpb = qb + R*C_;
      f2b_kernel<<<(int)((R*C_/4+255)/256), 256, 0, stream>>>(tgtc, abuf, (int)(R*C_));
      gemm_mfma_t64<<<dim3(C_/64, (int)(R/128)), 256, 0, stream>>>((const short*)abuf, C_,
          (const short*)wb0, C_, ca_in_b + (size_t)l*3*C_, qb, C_, C_, 0);
      cross_attn_kernel<<<dim3(HW_, CH), 128, 0, stream>>>(qb, kvm, c0);
      gemm_mfma_t64<<<dim3(C_/64, (int)(R/128)), 256, 0, stream>>>((const short*)qb, C_,
          (const short*)wb1, C_, ca_out_b + (size_t)l*C_, tmpb, C_, C_, 0);
      ln_res_kernel<<<(int)R, 256, 0, stream>>>(tgtc, tmpb,
          ln_w + (size_t)(l*3+1)*C_, ln_b + (size_t)(l*3+1)*C_);
    }

    // ===== FFN =====
    wtrans_kernel<<<dim3(FF_/32, C_/32), 256, 0, stream>>>(ff1_w + (size_t)l*C_*FF_, wb0, C_, FF_);
    wtrans_kernel<<<dim3(C_/32, FF_/32), 256, 0, stream>>>(ff2_w + (size_t)l*FF_*C_, wb1, FF_, C_);
    for (int c0 = 0; c0 < B_; c0 += CH) {
      float* tgtc = tgt + (size_t)c0*HW_*C_;
      hbf16* abuf = (hbf16*)S;
      hbf16* ffh  = abuf + R*C_;
      hbf16* tmpb = ffh + R*FF_;
      f2b_kernel<<<(int)((R*C_/4+255)/256), 256, 0, stream>>>(tgtc, abuf, (int)(R*C_));
      gemm_mfma_t<<<dim3(FF_/128, (int)(R/128)), 256, 0, stream>>>((const short*)abuf, C_,
          (const short*)wb0, C_, ff1_b + (size_t)l*FF_, ffh, FF_, C_, 1);
      gemm_mfma_t64<<<dim3(C_/64, (int)(R/128)), 256, 0, stream>>>((const short*)ffh, FF_,
          (const short*)wb1, FF_, ff2_b + (size_t)l*C_, tmpb, C_, FF_, 0);
      ln_res_kernel<<<(int)R, 256, 0, stream>>>(tgtc, tmpb,
          ln_w + (size_t)(l*3+2)*C_, ln_b + (size_t)(l*3+2)*C_);
    }
  }

  // ---- final: tgt [B][HW][C] -> out [B][C][H][W], LDS-tiled transpose ----
  btrans_kernel<<<dim3(C_/32, HW_/32, B_), 256, 0, stream>>>(tgt, (float*)d_out, HW_, C_);
}

// Round 7
// 1388.251 us; speedup vs baseline: 1.3711x; 1.0680x over previous
//
#include <hip/hip_runtime.h>
#include <hip/hip_bf16.h>
#include <math.h>

typedef __hip_bfloat16 hbf16;

#define B_ 8
#define C_ 768
#define HW_ 1024
#define NH_ 8
#define HD_ 96
#define NPTS 2048      // PH*PW*K
#define AROUND_ 5
#define TOPK_ 5
#define MOD_ 2
#define FF_ 3072
#define TOK_ (B_*HW_)  // 8192

typedef __attribute__((ext_vector_type(8))) short short8v;
typedef __attribute__((ext_vector_type(4))) short short4v;
typedef __attribute__((ext_vector_type(4))) float f32x4;

__device__ __forceinline__ float b2f(hbf16 v){ return __bfloat162float(v); }

// ---- async global->LDS, 16B per lane; LDS dest = wave-uniform base + lane*16 ----
__device__ __forceinline__ void gload16(const void* g, void* l) {
  __builtin_amdgcn_global_load_lds(
      (const __attribute__((address_space(1))) void*)g,
      (__attribute__((address_space(3))) void*)l, 16, 0, 0);
}

// ---- bilinear taps, torch grid_sample semantics (align_corners=False, zeros pad), H=W=32 ----
struct Taps { int x0,x1,y0,y1; float w00,w10,w01,w11; };
__device__ __forceinline__ Taps bilin_taps(float gx, float gy) {
  Taps t;
  float ix = ((gx+1.f)*32.f - 1.f)*0.5f;
  float iy = ((gy+1.f)*32.f - 1.f)*0.5f;
  float x0f = floorf(ix), y0f = floorf(iy);
  float wx1 = ix-x0f, wy1 = iy-y0f, wx0 = 1.f-wx1, wy0 = 1.f-wy1;
  int x0=(int)x0f, y0=(int)y0f, x1=x0+1, y1=y0+1;
  bool vx0=(x0>=0)&&(x0<=31), vx1=(x1>=0)&&(x1<=31);
  bool vy0=(y0>=0)&&(y0<=31), vy1=(y1>=0)&&(y1<=31);
  t.w00 = (vx0&&vy0) ? wx0*wy0 : 0.f;
  t.w10 = (vx1&&vy0) ? wx1*wy0 : 0.f;
  t.w01 = (vx0&&vy1) ? wx0*wy1 : 0.f;
  t.w11 = (vx1&&vy1) ? wx1*wy1 : 0.f;
  t.x0 = min(max(x0,0),31); t.x1 = min(max(x1,0),31);
  t.y0 = min(max(y0,0),31); t.y1 = min(max(y1,0),31);
  return t;
}

__device__ __forceinline__ float block_reduce_sum_256(float v, float* red) {
  int tid = threadIdx.x;
  red[tid] = v; __syncthreads();
  for (int s = 128; s > 0; s >>= 1) { if (tid < s) red[tid] += red[tid+s]; __syncthreads(); }
  float r = red[0]; __syncthreads();
  return r;
}

// ---- fp32 -> bf16 elementwise convert (n multiple of 4) ----
__global__ __launch_bounds__(256) void f2b_kernel(const float* __restrict__ in,
    hbf16* __restrict__ out, int n) {
  int i = (blockIdx.x*256 + threadIdx.x)*4;
  if (i >= n) return;
  float4 v = *(const float4*)&in[i];
  out[i+0] = __float2bfloat16(v.x);
  out[i+1] = __float2bfloat16(v.y);
  out[i+2] = __float2bfloat16(v.z);
  out[i+3] = __float2bfloat16(v.w);
}

// ---- transpose+convert: fp32 in[K][N] -> bf16 out[N][K] (K,N multiples of 32) ----
__global__ __launch_bounds__(256) void wtrans_kernel(const float* __restrict__ in,
    hbf16* __restrict__ out, int K, int N) {
  __shared__ float t[32][33];
  int tx = threadIdx.x & 31, ty = threadIdx.x >> 5;
  int k0 = blockIdx.y*32, n0 = blockIdx.x*32;
  #pragma unroll
  for (int i = 0; i < 32; i += 8) t[ty+i][tx] = in[(size_t)(k0+ty+i)*N + n0+tx];
  __syncthreads();
  #pragma unroll
  for (int i = 0; i < 32; i += 8)
    out[(size_t)(n0+ty+i)*K + k0 + tx] = __float2bfloat16(t[tx][ty+i]);
}

// ---- transpose + split-convert: fp32 in[K][N] -> hi[N][K], lo[N][K] ----
__global__ __launch_bounds__(256) void wtrans_split_kernel(const float* __restrict__ in,
    hbf16* __restrict__ hi, hbf16* __restrict__ lo, int K, int N) {
  __shared__ float t[32][33];
  int tx = threadIdx.x & 31, ty = threadIdx.x >> 5;
  int k0 = blockIdx.y*32, n0 = blockIdx.x*32;
  #pragma unroll
  for (int i = 0; i < 32; i += 8) t[ty+i][tx] = in[(size_t)(k0+ty+i)*N + n0+tx];
  __syncthreads();
  #pragma unroll
  for (int i = 0; i < 32; i += 8) {
    float v = t[tx][ty+i];
    hbf16 h = __float2bfloat16(v);
    hi[(size_t)(n0+ty+i)*K + k0 + tx] = h;
    lo[(size_t)(n0+ty+i)*K + k0 + tx] = __float2bfloat16(v - b2f(h));
  }
}

// ---- batched fp32 transpose: per z, in [R][S] -> out [S][R] (R,S multiples of 32) ----
// grid (S/32, R/32, batch)
__global__ __launch_bounds__(256) void btrans_kernel(const float* __restrict__ in,
    float* __restrict__ out, int R, int S) {
  __shared__ float t[32][33];
  int tx = threadIdx.x & 31, ty = threadIdx.x >> 5;
  int r0 = blockIdx.y*32, s0 = blockIdx.x*32;
  const float* ib = in + (size_t)blockIdx.z*R*S;
  float* ob = out + (size_t)blockIdx.z*R*S;
  #pragma unroll
  for (int i = 0; i < 32; i += 8) t[ty+i][tx] = ib[(size_t)(r0+ty+i)*S + s0+tx];
  __syncthreads();
  #pragma unroll
  for (int i = 0; i < 32; i += 8) ob[(size_t)(s0+ty+i)*R + r0+tx] = t[tx][ty+i];
}

__global__ __launch_bounds__(256) void zero_kernel(float* __restrict__ p, int n) {
  int i = blockIdx.x*256 + threadIdx.x;
  if (i < n) p[i] = 0.f;
}

// ---- stage A: blockwise sample from CHANNEL-LAST image oT [B][HW][C] ----
// grid (G, NPTS/4): blockIdx.x = instance (XCD-pinned), 4 points per block.
__global__ __launch_bounds__(256) void sample_all_kernel(const float* __restrict__ oT,
    const float* __restrict__ brand, hbf16* __restrict__ pf_hi, hbf16* __restrict__ pf_lo,
    float* __restrict__ coords_all, int g0) {
  int ly = blockIdx.x;
  int inst = g0 + ly;
  int b = inst & 7;
  const float* xT = oT + (size_t)b*HW_*C_;
  int tid = threadIdx.x;
  int p = tid >> 6, lane = tid & 63;
  int n = blockIdx.y*4 + p;
  int k = n & 1, pw = (n >> 1) & 31, ph = n >> 6;
  const float* br = brand + (size_t)inst*4096;
  int roff = ((ph*32 + pw)*2 + k)*2;
  float r0 = br[roff], r1 = br[roff+1];
  const float bs = 0.0625f;
  float c0 = r0*bs + ((float)ph*bs - 1.0f);
  float c1 = r1*bs + ((float)pw*bs - 1.0f);
  Taps t = bilin_taps(c0, c1);
  const float* r00 = xT + (size_t)(t.y0*32+t.x0)*C_;
  const float* r10 = xT + (size_t)(t.y0*32+t.x1)*C_;
  const float* r01 = xT + (size_t)(t.y1*32+t.x0)*C_;
  const float* r11 = xT + (size_t)(t.y1*32+t.x1)*C_;
  size_t base = ((size_t)ly*NPTS + n)*C_;
  short* ph_ = (short*)pf_hi;
  short* pl_ = (short*)pf_lo;
  #pragma unroll
  for (int kk = 0; kk < 3; ++kk) {
    int c = kk*256 + lane*4;
    float4 v00 = *(const float4*)(r00 + c);
    float4 v10 = *(const float4*)(r10 + c);
    float4 v01 = *(const float4*)(r01 + c);
    float4 v11 = *(const float4*)(r11 + c);
    float o[4];
    o[0] = t.w00*v00.x + t.w10*v10.x + t.w01*v01.x + t.w11*v11.x;
    o[1] = t.w00*v00.y + t.w10*v10.y + t.w01*v01.y + t.w11*v11.y;
    o[2] = t.w00*v00.z + t.w10*v10.z + t.w01*v01.z + t.w11*v11.z;
    o[3] = t.w00*v00.w + t.w10*v10.w + t.w01*v01.w + t.w11*v11.w;
    short4v hs, ls;
    #pragma unroll
    for (int e = 0; e < 4; ++e) {
      hbf16 h = __float2bfloat16(o[e]);
      hs[e] = *(short*)&h;
      hbf16 l = __float2bfloat16(o[e] - b2f(h));
      ls[e] = *(short*)&l;
    }
    *(short4v*)&ph_[base + c] = hs;
    *(short4v*)&pl_[base + c] = ls;
  }
  if (lane == 0) {
    size_t co = ((size_t)inst*NPTS + n)*2;
    coords_all[co] = c0; coords_all[co+1] = c1;
  }
}

// ---- XCD swizzle: each XCD owns gy/8 contiguous row-panels, iterates cols fastest ----
// wgid%8 = XCD (round-robin dispatch); requires gx*gy % 8 == 0 and gy % 8 == 0.
__device__ __forceinline__ void xcd_tile(int gx, int gy, int& row, int& col) {
  int wgid = blockIdx.y * gx + blockIdx.x;
  int xcd = wgid & 7;
  int li = wgid >> 3;
  row = xcd * (gy >> 3) + li / gx;
  col = li % gx;
}

// ---- fused score GEMM (split-bf16, 3-term) + relu + w2-dot -> atomicAdd logits ----
// Linear LDS [128][32] per buffer; staging via global_load_lds (16B/lane).
__global__ __launch_bounds__(256) void score_gemm_kernel(const short* __restrict__ Ahi,
    const short* __restrict__ Alo, const short* __restrict__ Bhi, const short* __restrict__ Blo,
    const float* __restrict__ b1, const float* __restrict__ w2, float* __restrict__ logit) {
  __shared__ short AsH[128*32];
  __shared__ short AsL[128*32];
  __shared__ short BsH[128*32];
  __shared__ short BsL[128*32];
  int tid = threadIdx.x;
  int lane = tid & 63, w = tid >> 6;
  int wr = (w >> 1) * 64, wc = (w & 1) * 64;
  int m16 = lane & 15, quad = lane >> 4, q8 = quad * 8;
  int brow, bcol;
  xcd_tile(gridDim.x, gridDim.y, brow, bcol);
  int bm = brow * 128, bn = bcol * 128;
  int sr = w * 32;                    // this wave's 32-row slice
  int lr = lane >> 2, lc = (lane & 3) * 8;
  f32x4 acc[4][4] = {};
  for (int k0 = 0; k0 < 768; k0 += 32) {
    {
      const short* pa = &Ahi[(size_t)(bm + sr + lr)*768 + k0 + lc];
      const short* pl = &Alo[(size_t)(bm + sr + lr)*768 + k0 + lc];
      const short* pb = &Bhi[(size_t)(bn + sr + lr)*768 + k0 + lc];
      const short* pq = &Blo[(size_t)(bn + sr + lr)*768 + k0 + lc];
      gload16(pa,            &AsH[sr*32]);
      gload16(pa + 16*768,   &AsH[(sr+16)*32]);
      gload16(pl,            &AsL[sr*32]);
      gload16(pl + 16*768,   &AsL[(sr+16)*32]);
      gload16(pb,            &BsH[sr*32]);
      gload16(pb + 16*768,   &BsH[(sr+16)*32]);
      gload16(pq,            &BsL[sr*32]);
      gload16(pq + 16*768,   &BsL[(sr+16)*32]);
    }
    __syncthreads();
    short8v ah[4], al[4], bh[4], bl[4];
    #pragma unroll
    for (int i=0;i<4;++i) {
      ah[i] = *(const short8v*)&AsH[(wr + i*16 + m16)*32 + q8];
      al[i] = *(const short8v*)&AsL[(wr + i*16 + m16)*32 + q8];
      bh[i] = *(const short8v*)&BsH[(wc + i*16 + m16)*32 + q8];
      bl[i] = *(const short8v*)&BsL[(wc + i*16 + m16)*32 + q8];
    }
    #pragma unroll
    for (int i=0;i<4;++i)
      #pragma unroll
      for (int j=0;j<4;++j) {
        acc[i][j] = __builtin_amdgcn_mfma_f32_16x16x32_bf16(ah[i], bh[j], acc[i][j], 0, 0, 0);
        acc[i][j] = __builtin_amdgcn_mfma_f32_16x16x32_bf16(ah[i], bl[j], acc[i][j], 0, 0, 0);
        acc[i][j] = __builtin_amdgcn_mfma_f32_16x16x32_bf16(al[i], bh[j], acc[i][j], 0, 0, 0);
      }
    __syncthreads();
  }
  float b1v[4], w2v[4];
  #pragma unroll
  for (int j=0;j<4;++j) {
    int col = bn + wc + j*16 + m16;
    b1v[j] = b1[col]; w2v[j] = w2[col];
  }
  #pragma unroll
  for (int i=0;i<4;++i) {
    #pragma unroll
    for (int r=0;r<4;++r) {
      float v = 0.f;
      #pragma unroll
      for (int j=0;j<4;++j) {
        float h = fmaxf(acc[i][j][r] + b1v[j], 0.f);
        v += h * w2v[j];
      }
      v += __shfl_xor(v, 1); v += __shfl_xor(v, 2);
      v += __shfl_xor(v, 4); v += __shfl_xor(v, 8);
      if (m16 == 0) atomicAdd(&logit[bm + wr + i*16 + quad*4 + r], v);
    }
  }
}

// ---- top-5 of 2048 per instance (on logits; sigmoid monotone), jax tie semantics ----
__global__ void topk_all_kernel(const float* __restrict__ logit, int* __restrict__ idx) {
  int lane = threadIdx.x;   // 64 lanes
  const float* score = logit + (size_t)blockIdx.x*NPTS;
  float v[32];
  #pragma unroll
  for (int i = 0; i < 32; ++i) v[i] = score[(i<<6) | lane];
  for (int t = 0; t < TOPK_; ++t) {
    float bv = v[0]; int bi = lane;
    #pragma unroll
    for (int i = 1; i < 32; ++i) { if (v[i] > bv) { bv = v[i]; bi = (i<<6)|lane; } }
    for (int off = 32; off; off >>= 1) {
      float ov = __shfl_xor(bv, off);
      int   oi = __shfl_xor(bi, off);
      if (ov > bv || (ov == bv && oi < bi)) { bv = ov; bi = oi; }
    }
    if (lane == 0) idx[blockIdx.x*8 + t] = bi;
    if ((bi & 63) == lane) v[bi >> 6] = -1e30f;
  }
}

// ---- soft_align + modality query -> memf rows; grid (TOPK, G) ----
// mainxT is channel-last [B][HW][C] (the tgt buffer, pre-tgt0)
__global__ __launch_bounds__(256) void softalign_all_kernel(const float* __restrict__ mainxT,
    const float* __restrict__ pos, const hbf16* __restrict__ pf_hi, const hbf16* __restrict__ pf_lo,
    const float* __restrict__ coords_all, const int* __restrict__ idx_all,
    const float* __restrict__ arand, const float* __restrict__ mq,
    float* __restrict__ memf, int g0) {
  int t = blockIdx.x;
  int ly = blockIdx.y;
  int inst = g0 + ly;
  int mod = inst >> 3, b = inst & 7;
  const float* mT_b = mainxT + (size_t)b*HW_*C_;
  const float* arand_ib = arand + (size_t)inst*AROUND_*TOPK_*2;
  const float* coords = coords_all + (size_t)inst*NPTS*2;
  int tid = threadIdx.x;
  int n = idx_all[ly*8 + t];
  float px0 = coords[n*2], px1 = coords[n*2+1];
  size_t pfb = ((size_t)ly*NPTS + n)*C_;
  float pfv[3];
  #pragma unroll
  for (int i=0;i<3;++i) {
    int c = tid + i*256;
    pfv[i] = b2f(pf_hi[pfb + c]) + b2f(pf_lo[pfb + c]);
  }
  __shared__ float red[256];
  float pp = block_reduce_sum_256(pfv[0]*pfv[0]+pfv[1]*pfv[1]+pfv[2]*pfv[2], red);
  float embr[AROUND_][3];
  float num_a[AROUND_], aa_a[AROUND_];
  for (int a=0; a<AROUND_; ++a) {
    int ar = (a*TOPK_ + t)*2;
    float g0c = px0 + (arand_ib[ar]*2.f - 0.5f)*0.2f;
    float g1c = px1 + (arand_ib[ar+1]*2.f - 0.5f)*0.2f;
    g0c = fminf(fmaxf(g0c,-1.f),1.f);
    g1c = fminf(fmaxf(g1c,-1.f),1.f);
    Taps tp = bilin_taps(g0c, g1c);
    int i00=tp.y0*32+tp.x0, i10=tp.y0*32+tp.x1, i01=tp.y1*32+tp.x0, i11=tp.y1*32+tp.x1;
    float s_num = 0.f, s_aa = 0.f;
    #pragma unroll
    for (int i=0;i<3;++i) {
      int c = tid + i*256;
      float af = tp.w00*mT_b[(size_t)i00*C_+c] + tp.w10*mT_b[(size_t)i10*C_+c]
               + tp.w01*mT_b[(size_t)i01*C_+c] + tp.w11*mT_b[(size_t)i11*C_+c];
      float em = tp.w00*pos[(size_t)i00*C_+c] + tp.w10*pos[(size_t)i10*C_+c]
               + tp.w01*pos[(size_t)i01*C_+c] + tp.w11*pos[(size_t)i11*C_+c];
      embr[a][i] = em;
      s_num += pfv[i]*af;
      s_aa  += af*af;
    }
    num_a[a] = block_reduce_sum_256(s_num, red);
    aa_a[a]  = block_reduce_sum_256(s_aa, red);
  }
  float pn = fmaxf(sqrtf(pp), 1e-8f);
  float w[AROUND_]; float mx = -1e30f;
  #pragma unroll
  for (int a=0;a<AROUND_;++a){ float den = pn * fmaxf(sqrtf(aa_a[a]),1e-8f); w[a]=num_a[a]/den; mx=fmaxf(mx,w[a]); }
  float se = 0.f;
  #pragma unroll
  for (int a=0;a<AROUND_;++a){ w[a]=expf(w[a]-mx); se+=w[a]; }
  float inv = 1.f/se;
  float* mo = memf + ((size_t)b*(MOD_*TOPK_) + mod*TOPK_ + t)*C_;
  #pragma unroll
  for (int i=0;i<3;++i) {
    int c = tid + i*256;
    float o = pfv[i];
    #pragma unroll
    for (int a=0;a<AROUND_;++a) o += embr[a][i]*(w[a]*inv);
    o += mq[(size_t)(mod+1)*C_ + c];
    mo[c] = o;
  }
}

// ---- generic fp32 GEMM (kvm only) ----
#define BM 64
#define BN 64
#define BK 16
__global__ __launch_bounds__(256) void gemm_kernel(const float* __restrict__ A, int lda,
    const float* __restrict__ Bw, int ldb, const float* __restrict__ bias,
    float* __restrict__ Cm, int ldc, int M, int N, int K, int act) {
  __shared__ float As[BK][BM];
  __shared__ float Bs[BK][BN];
  int tid = threadIdx.x;
  int bm = blockIdx.y * BM, bn = blockIdx.x * BN;
  int arw = tid >> 2, acl = (tid & 3) << 2;
  int brw = tid >> 4, bcl = (tid & 15) << 2;
  int ty = tid >> 4, tx = tid & 15;
  float acc[4][4] = {{0.f}};
  for (int k0 = 0; k0 < K; k0 += BK) {
    float a0=0.f,a1=0.f,a2=0.f,a3=0.f;
    if (bm + arw < M) {
      const float* ap = A + (size_t)(bm+arw)*lda + k0 + acl;
      a0=ap[0]; a1=ap[1]; a2=ap[2]; a3=ap[3];
    }
    As[acl+0][arw]=a0; As[acl+1][arw]=a1; As[acl+2][arw]=a2; As[acl+3][arw]=a3;
    const float* bp = Bw + (size_t)(k0+brw)*ldb + bn + bcl;
    Bs[brw][bcl+0]=bp[0]; Bs[brw][bcl+1]=bp[1]; Bs[brw][bcl+2]=bp[2]; Bs[brw][bcl+3]=bp[3];
    __syncthreads();
    #pragma unroll
    for (int kk = 0; kk < BK; ++kk) {
      float4 av = *reinterpret_cast<const float4*>(&As[kk][ty<<2]);
      float4 bv = *reinterpret_cast<const float4*>(&Bs[kk][tx<<2]);
      acc[0][0]+=av.x*bv.x; acc[0][1]+=av.x*bv.y; acc[0][2]+=av.x*bv.z; acc[0][3]+=av.x*bv.w;
      acc[1][0]+=av.y*bv.x; acc[1][1]+=av.y*bv.y; acc[1][2]+=av.y*bv.z; acc[1][3]+=av.y*bv.w;
      acc[2][0]+=av.z*bv.x; acc[2][1]+=av.z*bv.y; acc[2][2]+=av.z*bv.z; acc[2][3]+=av.z*bv.w;
      acc[3][0]+=av.w*bv.x; acc[3][1]+=av.w*bv.y; acc[3][2]+=av.w*bv.z; acc[3][3]+=av.w*bv.w;
    }
    __syncthreads();
  }
  #pragma unroll
  for (int i=0;i<4;++i) {
    int r = bm + (ty<<2) + i;
    if (r >= M) continue;
    float* cp = Cm + (size_t)r*ldc + bn + (tx<<2);
    #pragma unroll
    for (int j=0;j<4;++j) {
      float v = acc[i][j] + bias[bn + (tx<<2) + j];
      if (act) v = fmaxf(v, 0.f);
      cp[j] = v;
    }
  }
}

// ---- bf16 MFMA GEMM, B pre-transposed: C = act(A[M,K] @ Bt[N,K]^T + bias), 128x128 tile ----
// Linear LDS [128][32]; staging via global_load_lds.
__global__ __launch_bounds__(256) void gemm_mfma_t(const short* __restrict__ A, int lda,
    const short* __restrict__ Bt, int ldbt, const float* __restrict__ bias,
    hbf16* __restrict__ Cm, int ldc, int K, int act) {
  __shared__ short As[128*32];
  __shared__ short Bs[128*32];
  int tid = threadIdx.x;
  int lane = tid & 63, w = tid >> 6;
  int wr = (w >> 1) * 64, wc = (w & 1) * 64;
  int m16 = lane & 15, q8 = (lane >> 4) * 8;
  int brow, bcol;
  xcd_tile(gridDim.x, gridDim.y, brow, bcol);
  int bm = brow * 128, bn = bcol * 128;
  int sr = w * 32;
  int lr = lane >> 2, lc = (lane & 3) * 8;
  f32x4 acc[4][4] = {};
  for (int k0 = 0; k0 < K; k0 += 32) {
    {
      const short* pa = &A [(size_t)(bm + sr + lr)*lda  + k0 + lc];
      const short* pb = &Bt[(size_t)(bn + sr + lr)*ldbt + k0 + lc];
      gload16(pa,                    &As[sr*32]);
      gload16(pa + (size_t)16*lda,   &As[(sr+16)*32]);
      gload16(pb,                    &Bs[sr*32]);
      gload16(pb + (size_t)16*ldbt,  &Bs[(sr+16)*32]);
    }
    __syncthreads();
    short8v af[4], bf[4];
    #pragma unroll
    for (int i=0;i<4;++i) af[i] = *(const short8v*)&As[(wr + i*16 + m16)*32 + q8];
    #pragma unroll
    for (int j=0;j<4;++j) bf[j] = *(const short8v*)&Bs[(wc + j*16 + m16)*32 + q8];
    #pragma unroll
    for (int i=0;i<4;++i)
      #pragma unroll
      for (int j=0;j<4;++j)
        acc[i][j] = __builtin_amdgcn_mfma_f32_16x16x32_bf16(af[i], bf[j], acc[i][j], 0, 0, 0);
    __syncthreads();
  }
  #pragma unroll
  for (int j=0;j<4;++j) {
    int col = bn + wc + j*16 + m16;
    float bs = bias[col];
    #pragma unroll
    for (int i=0;i<4;++i) {
      int row0 = bm + wr + i*16 + (lane>>4)*4;
      #pragma unroll
      for (int r=0;r<4;++r) {
        float v = acc[i][j][r] + bs;
        if (act) v = fmaxf(v, 0.f);
        Cm[(size_t)(row0+r)*ldc + col] = __float2bfloat16(v);
      }
    }
  }
}

// ---- bf16 MFMA GEMM, 128x64 tile (for small-N GEMMs; doubles grid vs 128x128) ----
// 4 waves, each computes 32 rows x 64 cols (acc[2][4]). Linear LDS + global_load_lds.
__global__ __launch_bounds__(256) void gemm_mfma_t64(const short* __restrict__ A, int lda,
    const short* __restrict__ Bt, int ldbt, const float* __restrict__ bias,
    hbf16* __restrict__ Cm, int ldc, int K, int act) {
  __shared__ short As[128*32];
  __shared__ short Bs[64*32];
  int tid = threadIdx.x;
  int lane = tid & 63, w = tid >> 6;
  int m16 = lane & 15, q8 = (lane >> 4) * 8;
  int brow, bcol;
  xcd_tile(gridDim.x, gridDim.y, brow, bcol);
  int bm = brow * 128, bn = bcol * 64;
  int sr = w * 32;            // A slice
  int srB = w * 16;           // B slice (4 waves x 16 rows)
  int lr = lane >> 2, lc = (lane & 3) * 8;
  f32x4 acc[2][4] = {};
  for (int k0 = 0; k0 < K; k0 += 32) {
    {
      const short* pa = &A [(size_t)(bm + sr  + lr)*lda  + k0 + lc];
      const short* pb = &Bt[(size_t)(bn + srB + lr)*ldbt + k0 + lc];
      gload16(pa,                   &As[sr*32]);
      gload16(pa + (size_t)16*lda,  &As[(sr+16)*32]);
      gload16(pb,                   &Bs[srB*32]);
    }
    __syncthreads();
    short8v af[2], bf[4];
    #pragma unroll
    for (int i=0;i<2;++i) af[i] = *(const short8v*)&As[(w*32 + i*16 + m16)*32 + q8];
    #pragma unroll
    for (int j=0;j<4;++j) bf[j] = *(const short8v*)&Bs[(j*16 + m16)*32 + q8];
    #pragma unroll
    for (int i=0;i<2;++i)
      #pragma unroll
      for (int j=0;j<4;++j)
        acc[i][j] = __builtin_amdgcn_mfma_f32_16x16x32_bf16(af[i], bf[j], acc[i][j], 0, 0, 0);
    __syncthreads();
  }
  #pragma unroll
  for (int j=0;j<4;++j) {
    int col = bn + j*16 + m16;
    float bs = bias[col];
    #pragma unroll
    for (int i=0;i<2;++i) {
      int row0 = bm + w*32 + i*16 + (lane>>4)*4;
      #pragma unroll
      for (int r=0;r<4;++r) {
        float v = acc[i][j][r] + bs;
        if (act) v = fmaxf(v, 0.f);
        Cm[(size_t)(row0+r)*ldc + col] = __float2bfloat16(v);
      }
    }
  }
}

// ---- fused flash self-attention (MFMA): grid (head+batch, qtile=8), 512 thr / 8 waves ----
// x = h + NH_*bz so all q-tiles of one (b,h) share an XCD (ids congruent mod 8).
// 8 waves x 16 q-rows each; Q fragments in registers; LDS = KP ∪ Vt (32.3 KB).
// Grid 512 blocks x 8 waves = 4096 waves = 16 waves/CU (2 blocks/CU).
__global__ __launch_bounds__(512, 4) void flash_attn_kernel(const hbf16* __restrict__ qkv_all,
    hbf16* __restrict__ o_all) {
  const int hb = blockIdx.x;
  const int h  = hb & 7;
  const int bz = hb >> 3;
  const int q0 = blockIdx.y * 128;
  const short* qkv = (const short*)(qkv_all + (size_t)bz*HW_*2304);
  hbf16* ob = o_all + (size_t)bz*HW_*C_;
  const int tid = threadIdx.x;
  const int lane = tid & 63, w = tid >> 6;
  const int m16 = lane & 15, quad = lane >> 4, q8 = quad * 8;
  const float scale = 0.10206207261596577f;  // 1/sqrt(96)

  // 16128 shorts = 32256 B. KP = lds[0..9216): K tile [64][104] (QK) / P [128][72] (PV).
  // Vt = lds[9216..16128): V^T [96][72]. Q staging [128][104]=13312 aliases both.
  __shared__ short lds[16128];
  short* KP = lds;
  short* Vt = lds + 9216;

  // stage Q -> LDS (coalesced), then hoist this wave's 16-row fragments to registers
  for (int idx = tid; idx < 128*12; idx += 512) {
    int row = idx / 12, dc = idx % 12;
    *(short8v*)&lds[row*104 + dc*8] = *(const short8v*)&qkv[(size_t)(q0+row)*2304 + h*HD_ + dc*8];
  }
  __syncthreads();
  short8v qf[3];
  #pragma unroll
  for (int kkk=0;kkk<3;++kkk)
    qf[kkk] = *(const short8v*)&lds[(w*16 + m16)*104 + q8 + kkk*32];
  __syncthreads();

  float m_st[4], l_st[4];
  f32x4 o_acc[6] = {};
  #pragma unroll
  for (int r=0;r<4;++r){ m_st[r] = -1e30f; l_st[r] = 0.f; }

  for (int t = 0; t < 16; ++t) {
    int j0 = t * 64;
    for (int idx = tid; idx < 64*12; idx += 512) {
      int row = idx / 12, dc = idx % 12;
      *(short8v*)&KP[row*104 + dc*8] = *(const short8v*)&qkv[(size_t)(j0+row)*2304 + C_ + h*HD_ + dc*8];
    }
    // V^T stage: j fast within wave -> conflict-free LDS writes
    for (int idx = tid; idx < 64*12; idx += 512) {
      int j = idx & 63, dc = idx >> 6;
      short8v v = *(const short8v*)&qkv[(size_t)(j0+j)*2304 + 2*C_ + h*HD_ + dc*8];
      #pragma unroll
      for (int s = 0; s < 8; ++s) Vt[(dc*8+s)*72 + j] = v[s];
    }
    __syncthreads();

    f32x4 accs[4] = {};
    #pragma unroll
    for (int kkk = 0; kkk < 3; ++kkk) {
      int kk = kkk*32;
      short8v bf[4];
      #pragma unroll
      for (int n=0;n<4;++n) bf[n] = *(const short8v*)&KP[(n*16 + m16)*104 + q8 + kk];
      #pragma unroll
      for (int n=0;n<4;++n)
        accs[n] = __builtin_amdgcn_mfma_f32_16x16x32_bf16(qf[kkk], bf[n], accs[n], 0, 0, 0);
    }
    __syncthreads();

    #pragma unroll
    for (int r=0;r<4;++r) {
      float mx = -1e30f;
      #pragma unroll
      for (int n=0;n<4;++n) mx = fmaxf(mx, accs[n][r]*scale);
      #pragma unroll
      for (int off=1; off<16; off<<=1) mx = fmaxf(mx, __shfl_xor(mx, off));
      float m_new = fmaxf(m_st[r], mx);
      float alpha = __expf(m_st[r] - m_new);
      float psum = 0.f;
      int prow = (w*16 + quad*4 + r)*72 + m16;
      #pragma unroll
      for (int n=0;n<4;++n) {
        float pv = __expf(accs[n][r]*scale - m_new);
        psum += pv;
        *(hbf16*)&KP[prow + n*16] = __float2bfloat16(pv);
      }
      #pragma unroll
      for (int off=1; off<16; off<<=1) psum += __shfl_xor(psum, off);
      l_st[r] = l_st[r]*alpha + psum;
      m_st[r] = m_new;
      #pragma unroll
      for (int dt=0; dt<6; ++dt) o_acc[dt][r] *= alpha;
    }

    #pragma unroll
    for (int k0 = 0; k0 < 64; k0 += 32) {
      short8v pf_, vf[6];
      pf_ = *(const short8v*)&KP[(w*16 + m16)*72 + q8 + k0];
      #pragma unroll
      for (int dt=0; dt<6; ++dt) vf[dt] = *(const short8v*)&Vt[(dt*16 + m16)*72 + q8 + k0];
      #pragma unroll
      for (int dt=0; dt<6; ++dt)
        o_acc[dt] = __builtin_amdgcn_mfma_f32_16x16x32_bf16(pf_, vf[dt], o_acc[dt], 0, 0, 0);
    }
    __syncthreads();
  }

  #pragma unroll
  for (int r=0;r<4;++r) {
    float inv = 1.f / l_st[r];
    int row = q0 + w*16 + quad*4 + r;
    #pragma unroll
    for (int dt=0; dt<6; ++dt)
      ob[(size_t)row*C_ + h*HD_ + dt*16 + m16] = __float2bfloat16(o_acc[dt][r]*inv);
  }
}

// ---- cross-attention over 10 memory tokens, wave-parallel: 1 wave per q row ----
// grid (HW_/4, CH), 256 thr = 4 waves. Lane owns 12 channels; head h = lane/8
// spans lanes [8h,8h+8); per-head dot via 3x shfl_xor reduce. IN PLACE on qb.
__global__ __launch_bounds__(256) void cross_attn_kernel(hbf16* __restrict__ qb,
    const float* __restrict__ kvm, int b0) {
  int wv = threadIdx.x >> 6, lane = threadIdx.x & 63;
  int row = blockIdx.x*4 + wv;
  int lb = blockIdx.y;
  int b = b0 + lb;
  const float scale = 0.10206207261596577f;
  hbf16* qp = qb + ((size_t)lb*HW_ + row)*C_;
  int c0 = lane*12;
  const short* qs = (const short*)qp;
  float q[12];
  #pragma unroll
  for (int i0 = 0; i0 < 3; ++i0) {
    short4v s = *(const short4v*)&qs[c0 + i0*4];
    #pragma unroll
    for (int e = 0; e < 4; ++e) { hbf16 hh; *(short*)&hh = s[e]; q[i0*4+e] = b2f(hh); }
  }
  const float* kb = kvm + (size_t)(b*10)*1536;
  float sc[10];
  #pragma unroll
  for (int j = 0; j < 10; ++j) {
    const float* kp = kb + (size_t)j*1536 + c0;
    float4 k0 = *(const float4*)(kp);
    float4 k1 = *(const float4*)(kp+4);
    float4 k2 = *(const float4*)(kp+8);
    float s = q[0]*k0.x + q[1]*k0.y + q[2]*k0.z + q[3]*k0.w
            + q[4]*k1.x + q[5]*k1.y + q[6]*k1.z + q[7]*k1.w
            + q[8]*k2.x + q[9]*k2.y + q[10]*k2.z + q[11]*k2.w;
    s += __shfl_xor(s, 1); s += __shfl_xor(s, 2); s += __shfl_xor(s, 4);
    sc[j] = s * scale;
  }
  float m = sc[0];
  #pragma unroll
  for (int j=1;j<10;++j) m = fmaxf(m, sc[j]);
  float se = 0.f;
  #pragma unroll
  for (int j=0;j<10;++j){ sc[j] = __expf(sc[j]-m); se += sc[j]; }
  float inv = 1.f/se;
  float o[12] = {};
  #pragma unroll
  for (int j = 0; j < 10; ++j) {
    const float* vp = kb + (size_t)j*1536 + C_ + c0;
    float4 v0 = *(const float4*)(vp);
    float4 v1 = *(const float4*)(vp+4);
    float4 v2 = *(const float4*)(vp+8);
    float pj = sc[j]*inv;
    o[0]+=pj*v0.x; o[1]+=pj*v0.y; o[2]+=pj*v0.z; o[3]+=pj*v0.w;
    o[4]+=pj*v1.x; o[5]+=pj*v1.y; o[6]+=pj*v1.z; o[7]+=pj*v1.w;
    o[8]+=pj*v2.x; o[9]+=pj*v2.y; o[10]+=pj*v2.z; o[11]+=pj*v2.w;
  }
  short* qw = (short*)qp;
  #pragma unroll
  for (int i0 = 0; i0 < 3; ++i0) {
    short4v ov;
    #pragma unroll
    for (int e = 0; e < 4; ++e) { hbf16 hh = __float2bfloat16(o[i0*4+e]); ov[e] = *(short*)&hh; }
    *(short4v*)&qw[c0 + i0*4] = ov;
  }
}

// ---- tgt init: IN PLACE on pre-transposed mainxT (=tgt): += mq[0] + pos ----
__global__ __launch_bounds__(256) void tgt0_kernel(float* __restrict__ tgt,
    const float* __restrict__ mq, const float* __restrict__ pos) {
  size_t i = ((size_t)blockIdx.x*256 + threadIdx.x)*4;
  if (i >= (size_t)TOK_*C_) return;
  int c = (int)(i % C_);
  int tpos = (int)((i / C_) % HW_);
  float4 v = *(float4*)&tgt[i];
  float4 m = *(const float4*)&mq[c];
  float4 pp = *(const float4*)&pos[(size_t)tpos*C_ + c];
  v.x += m.x + pp.x; v.y += m.y + pp.y;
  v.z += m.z + pp.z; v.w += m.w + pp.w;
  *(float4*)&tgt[i] = v;
}

// ---- residual + layernorm (in place on fp32 tgt rows, bf16 add) ----
__global__ __launch_bounds__(256) void ln_res_kernel(float* __restrict__ tgt, const hbf16* __restrict__ add,
    const float* __restrict__ w, const float* __restrict__ bvec) {
  __shared__ float red[256];
  int row = blockIdx.x, tid = threadIdx.x;
  float* tp = tgt + (size_t)row*C_;
  const hbf16* ap = add + (size_t)row*C_;
  float x[3]; float s = 0.f, s2 = 0.f;
  #pragma unroll
  for (int i=0;i<3;++i){ int c=tid+i*256; float v=tp[c]+b2f(ap[c]); x[i]=v; s+=v; s2+=v*v; }
  s  = block_reduce_sum_256(s,  red);
  s2 = block_reduce_sum_256(s2, red);
  float mean = s * (1.f/C_);
  float var  = s2 * (1.f/C_) - mean*mean;
  float rstd = rsqrtf(var + 1e-5f);
  #pragma unroll
  for (int i=0;i<3;++i){ int c=tid+i*256; tp[c] = (x[i]-mean)*rstd*w[c] + bvec[c]; }
}

extern "C" void kernel_launch(void* const* d_in, const int* in_sizes, int n_in,
                              void* d_out, int out_size, void* d_ws, size_t ws_size,
                              hipStream_t stream) {
  const float* mainx   = (const float*)d_in[0];
  const float* other0  = (const float*)d_in[1];
  const float* other1  = (const float*)d_in[2];
  const float* pos     = (const float*)d_in[3];
  const float* mq      = (const float*)d_in[4];
  const float* s_w1    = (const float*)d_in[5];
  const float* s_b1    = (const float*)d_in[6];
  const float* s_w2    = (const float*)d_in[7];
  const float* sa_in_w = (const float*)d_in[9];
  const float* sa_in_b = (const float*)d_in[10];
  const float* sa_out_w= (const float*)d_in[11];
  const float* sa_out_b= (const float*)d_in[12];
  const float* ca_in_w = (const float*)d_in[13];
  const float* ca_in_b = (const float*)d_in[14];
  const float* ca_out_w= (const float*)d_in[15];
  const float* ca_out_b= (const float*)d_in[16];
  const float* ff1_w   = (const float*)d_in[17];
  const float* ff1_b   = (const float*)d_in[18];
  const float* ff2_w   = (const float*)d_in[19];
  const float* ff2_b   = (const float*)d_in[20];
  const float* ln_w    = (const float*)d_in[21];
  const float* ln_b    = (const float*)d_in[22];
  const float* brand   = (const float*)d_in[23];
  const float* arand   = (const float*)d_in[24];

  // ---- workspace layout ----
  char* p = (char*)d_ws;
  auto alloc = [&](size_t bytes) { char* r = p; p += (bytes + 255) & ~(size_t)255; return (void*)r; };
  float* tgt    = (float*)alloc((size_t)TOK_*C_*4);       // 24 MB; holds mainxT during stage A
  hbf16* wb0    = (hbf16*)alloc((size_t)2359296*2);       // 4.5 MB (transposed weights)
  hbf16* wb1    = (hbf16*)alloc((size_t)2359296*2);       // 4.5 MB
  hbf16* w1t_hi = (hbf16*)alloc((size_t)C_*C_*2);
  hbf16* w1t_lo = (hbf16*)alloc((size_t)C_*C_*2);
  float* kvm    = (float*)alloc((size_t)80*1536*4);
  float* memf   = (float*)alloc((size_t)80*C_*4);
  float* coords = (float*)alloc((size_t)16*NPTS*2*4);
  float* logit  = (float*)alloc((size_t)16*NPTS*4);
  int*   idxb   = (int*)alloc(16*8*4);
  char*  S      = p;
  size_t used = (size_t)(p - (char*)d_ws);
  size_t Savail = (ws_size > used) ? ws_size - used : 0;
  int CH = 1;
  if (Savail >= (size_t)8*1024*9216 + 4096) CH = 8;
  else if (Savail >= (size_t)4*1024*9216 + 4096) CH = 4;
  else if (Savail >= (size_t)2*1024*9216 + 4096) CH = 2;
  const size_t R = (size_t)CH*1024;
  const size_t perG = (size_t)NPTS*C_*2*2;  // pf_hi+pf_lo per instance
  // stage-A scratch: oT (one image set, channel-last) at front of S, pf after
  const size_t oTb = (size_t)B_*HW_*C_*4;   // 25.2 MB, 256-aligned
  float* oT = (float*)S;
  char* Spf = S + oTb;
  size_t SA = (Savail > oTb) ? Savail - oTb : 0;
  int G = 1;
  if (SA >= 8*perG) G = 8;
  else if (SA >= 4*perG) G = 4;
  else if (SA >= 2*perG) G = 2;

  // ---- stage A ----
  // mainx [B][C][HW] -> channel-last in tgt (softalign reads it; tgt0 finishes in place)
  btrans_kernel<<<dim3(HW_/32, C_/32, B_), 256, 0, stream>>>(mainx, tgt, C_, HW_);
  wtrans_split_kernel<<<dim3(C_/32, C_/32), 256, 0, stream>>>(s_w1, w1t_hi, w1t_lo, C_, C_);
  zero_kernel<<<16*NPTS/256, 256, 0, stream>>>(logit, 16*NPTS);
  for (int g0 = 0; g0 < 16; g0 += G) {
    if ((g0 & 7) == 0)
      btrans_kernel<<<dim3(HW_/32, C_/32, B_), 256, 0, stream>>>(g0 < 8 ? other0 : other1,
          oT, C_, HW_);
    hbf16* pf_hi = (hbf16*)Spf;
    hbf16* pf_lo = pf_hi + (size_t)G*NPTS*C_;
    sample_all_kernel<<<dim3(G, NPTS/4), 256, 0, stream>>>(oT, brand,
        pf_hi, pf_lo, coords, g0);
    score_gemm_kernel<<<dim3(6, G*16), 256, 0, stream>>>((const short*)pf_hi, (const short*)pf_lo,
        (const short*)w1t_hi, (const short*)w1t_lo, s_b1, s_w2, logit + (size_t)g0*NPTS);
    topk_all_kernel<<<G, 64, 0, stream>>>(logit + (size_t)g0*NPTS, idxb + g0*8);
    softalign_all_kernel<<<dim3(TOPK_, G), 256, 0, stream>>>(tgt, pos, pf_hi, pf_lo,
        coords, idxb + g0*8, arand, mq, memf, g0);
  }

  // ---- stage B ----
  size_t total = (size_t)TOK_*C_;
  tgt0_kernel<<<(int)((total/4+255)/256), 256, 0, stream>>>(tgt, mq, pos);

  for (int l = 0; l < 2; ++l) {
    // ===== self-attention =====
    wtrans_kernel<<<dim3(3*C_/32, C_/32), 256, 0, stream>>>(sa_in_w + (size_t)l*C_*3*C_, wb0, C_, 3*C_);
    wtrans_kernel<<<dim3(C_/32, C_/32), 256, 0, stream>>>(sa_out_w + (size_t)l*C_*C_, wb1, C_, C_);
    for (int c0 = 0; c0 < B_; c0 += CH) {
      float* tgtc = tgt + (size_t)c0*HW_*C_;
      hbf16* abuf = (hbf16*)S;
      hbf16* qkv  = abuf + R*C_;
      hbf16* oatt = qkv + R*3*C_;
      hbf16* tmpb = oatt + R*C_;
      f2b_kernel<<<(int)((R*C_/4+255)/256), 256, 0, stream>>>(tgtc, abuf, (int)(R*C_));
      gemm_mfma_t<<<dim3(3*C_/128, (int)(R/128)), 256, 0, stream>>>((const short*)abuf, C_,
          (const short*)wb0, C_, sa_in_b + (size_t)l*3*C_, qkv, 3*C_, C_, 0);
      flash_attn_kernel<<<dim3(NH_*CH, HW_/128), 512, 0, stream>>>(qkv, oatt);
      gemm_mfma_t64<<<dim3(C_/64, (int)(R/128)), 256, 0, stream>>>((const short*)oatt, C_,
          (const short*)wb1, C_, sa_out_b + (size_t)l*C_, tmpb, C_, C_, 0);
      ln_res_kernel<<<(int)R, 256, 0, stream>>>(tgtc, tmpb,
          ln_w + (size_t)(l*3+0)*C_, ln_b + (size_t)(l*3+0)*C_);
    }

    // ===== cross-attention =====
    wtrans_kernel<<<dim3(C_/32, C_/32), 256, 0, stream>>>(ca_in_w + (size_t)l*C_*3*C_, wb0, C_, 3*C_);
    wtrans_kernel<<<dim3(C_/32, C_/32), 256, 0, stream>>>(ca_out_w + (size_t)l*C_*C_, wb1, C_, C_);
    gemm_kernel<<<dim3((2*C_+BN-1)/BN, (80+BM-1)/BM), 256, 0, stream>>>(memf, C_,
        ca_in_w + (size_t)l*C_*3*C_ + C_, 3*C_, ca_in_b + (size_t)l*3*C_ + C_, kvm, 2*C_,
        80, 2*C_, C_, 0);
    for (int c0 = 0; c0 < B_; c0 += CH) {
      float* tgtc = tgt + (size_t)c0*HW_*C_;
      hbf16* abuf = (hbf16*)S;
      hbf16* qb   = abuf + R*C_;
      hbf16* tmpb = qb + R*C_;
      f2b_kernel<<<(int)((R*C_/4+255)/256), 256, 0, stream>>>(tgtc, abuf, (int)(R*C_));
      gemm_mfma_t64<<<dim3(C_/64, (int)(R/128)), 256, 0, stream>>>((const short*)abuf, C_,
          (const short*)wb0, C_, ca_in_b + (size_t)l*3*C_, qb, C_, C_, 0);
      cross_attn_kernel<<<dim3(HW_/4, CH), 256, 0, stream>>>(qb, kvm, c0);
      gemm_mfma_t64<<<dim3(C_/64, (int)(R/128)), 256, 0, stream>>>((const short*)qb, C_,
          (const short*)wb1, C_, ca_out_b + (size_t)l*C_, tmpb, C_, C_, 0);
      ln_res_kernel<<<(int)R, 256, 0, stream>>>(tgtc, tmpb,
          ln_w + (size_t)(l*3+1)*C_, ln_b + (size_t)(l*3+1)*C_);
    }

    // ===== FFN =====
    wtrans_kernel<<<dim3(FF_/32, C_/32), 256, 0, stream>>>(ff1_w + (size_t)l*C_*FF_, wb0, C_, FF_);
    wtrans_kernel<<<dim3(C_/32, FF_/32), 256, 0, stream>>>(ff2_w + (size_t)l*FF_*C_, wb1, FF_, C_);
    for (int c0 = 0; c0 < B_; c0 += CH) {
      float* tgtc = tgt + (size_t)c0*HW_*C_;
      hbf16* abuf = (hbf16*)S;
      hbf16* ffh  = abuf + R*C_;
      hbf16* tmpb = ffh + R*FF_;
      f2b_kernel<<<(int)((R*C_/4+255)/256), 256, 0, stream>>>(tgtc, abuf, (int)(R*C_));
      gemm_mfma_t<<<dim3(FF_/128, (int)(R/128)), 256, 0, stream>>>((const short*)abuf, C_,
          (const short*)wb0, C_, ff1_b + (size_t)l*FF_, ffh, FF_, C_, 1);
      gemm_mfma_t64<<<dim3(C_/64, (int)(R/128)), 256, 0, stream>>>((const short*)ffh, FF_,
          (const short*)wb1, FF_, ff2_b + (size_t)l*C_, tmpb, C_, FF_, 0);
      ln_res_kernel<<<(int)R, 256, 0, stream>>>(tgtc, tmpb,
          ln_w + (size_t)(l*3+2)*C_, ln_b + (size_t)(l*3+2)*C_);
    }
  }

  // ---- final: tgt [B][HW][C] -> out [B][C][H][W], LDS-tiled transpose ----
  btrans_kernel<<<dim3(C_/32, HW_/32, B_), 256, 0, stream>>>(tgt, (float*)d_out, HW_, C_);
}

// Round 8
// 1318.690 us; speedup vs baseline: 1.4434x; 1.0527x over previous
//
#include <hip/hip_runtime.h>
#include <hip/hip_bf16.h>
#include <math.h>

typedef __hip_bfloat16 hbf16;

#define B_ 8
#define C_ 768
#define HW_ 1024
#define NH_ 8
#define HD_ 96
#define NPTS 2048      // PH*PW*K
#define AROUND_ 5
#define TOPK_ 5
#define MOD_ 2
#define FF_ 3072
#define TOK_ (B_*HW_)  // 8192

typedef __attribute__((ext_vector_type(8))) short short8v;
typedef __attribute__((ext_vector_type(4))) short short4v;
typedef __attribute__((ext_vector_type(4))) float f32x4;

__device__ __forceinline__ float b2f(hbf16 v){ return __bfloat162float(v); }

// ---- async global->LDS, 16B per lane; LDS dest = wave-uniform base + lane*16 ----
__device__ __forceinline__ void gload16(const void* g, void* l) {
  __builtin_amdgcn_global_load_lds(
      (const __attribute__((address_space(1))) void*)g,
      (__attribute__((address_space(3))) void*)l, 16, 0, 0);
}

// ---- bilinear taps, torch grid_sample semantics (align_corners=False, zeros pad), H=W=32 ----
struct Taps { int x0,x1,y0,y1; float w00,w10,w01,w11; };
__device__ __forceinline__ Taps bilin_taps(float gx, float gy) {
  Taps t;
  float ix = ((gx+1.f)*32.f - 1.f)*0.5f;
  float iy = ((gy+1.f)*32.f - 1.f)*0.5f;
  float x0f = floorf(ix), y0f = floorf(iy);
  float wx1 = ix-x0f, wy1 = iy-y0f, wx0 = 1.f-wx1, wy0 = 1.f-wy1;
  int x0=(int)x0f, y0=(int)y0f, x1=x0+1, y1=y0+1;
  bool vx0=(x0>=0)&&(x0<=31), vx1=(x1>=0)&&(x1<=31);
  bool vy0=(y0>=0)&&(y0<=31), vy1=(y1>=0)&&(y1<=31);
  t.w00 = (vx0&&vy0) ? wx0*wy0 : 0.f;
  t.w10 = (vx1&&vy0) ? wx1*wy0 : 0.f;
  t.w01 = (vx0&&vy1) ? wx0*wy1 : 0.f;
  t.w11 = (vx1&&vy1) ? wx1*wy1 : 0.f;
  t.x0 = min(max(x0,0),31); t.x1 = min(max(x1,0),31);
  t.y0 = min(max(y0,0),31); t.y1 = min(max(y1,0),31);
  return t;
}

__device__ __forceinline__ float block_reduce_sum_256(float v, float* red) {
  int tid = threadIdx.x;
  red[tid] = v; __syncthreads();
  for (int s = 128; s > 0; s >>= 1) { if (tid < s) red[tid] += red[tid+s]; __syncthreads(); }
  float r = red[0]; __syncthreads();
  return r;
}

// ---- transpose+convert: fp32 in[K][N] -> bf16 out[N][K] (K,N multiples of 32) ----
__global__ __launch_bounds__(256) void wtrans_kernel(const float* __restrict__ in,
    hbf16* __restrict__ out, int K, int N) {
  __shared__ float t[32][33];
  int tx = threadIdx.x & 31, ty = threadIdx.x >> 5;
  int k0 = blockIdx.y*32, n0 = blockIdx.x*32;
  #pragma unroll
  for (int i = 0; i < 32; i += 8) t[ty+i][tx] = in[(size_t)(k0+ty+i)*N + n0+tx];
  __syncthreads();
  #pragma unroll
  for (int i = 0; i < 32; i += 8)
    out[(size_t)(n0+ty+i)*K + k0 + tx] = __float2bfloat16(t[tx][ty+i]);
}

// ---- transpose + split-convert: fp32 in[K][N] -> hi[N][K], lo[N][K] ----
__global__ __launch_bounds__(256) void wtrans_split_kernel(const float* __restrict__ in,
    hbf16* __restrict__ hi, hbf16* __restrict__ lo, int K, int N) {
  __shared__ float t[32][33];
  int tx = threadIdx.x & 31, ty = threadIdx.x >> 5;
  int k0 = blockIdx.y*32, n0 = blockIdx.x*32;
  #pragma unroll
  for (int i = 0; i < 32; i += 8) t[ty+i][tx] = in[(size_t)(k0+ty+i)*N + n0+tx];
  __syncthreads();
  #pragma unroll
  for (int i = 0; i < 32; i += 8) {
    float v = t[tx][ty+i];
    hbf16 h = __float2bfloat16(v);
    hi[(size_t)(n0+ty+i)*K + k0 + tx] = h;
    lo[(size_t)(n0+ty+i)*K + k0 + tx] = __float2bfloat16(v - b2f(h));
  }
}

// ---- batched fp32 transpose: per z, in [R][S] -> out [S][R] (R,S multiples of 32) ----
// grid (S/32, R/32, batch)
__global__ __launch_bounds__(256) void btrans_kernel(const float* __restrict__ in,
    float* __restrict__ out, int R, int S) {
  __shared__ float t[32][33];
  int tx = threadIdx.x & 31, ty = threadIdx.x >> 5;
  int r0 = blockIdx.y*32, s0 = blockIdx.x*32;
  const float* ib = in + (size_t)blockIdx.z*R*S;
  float* ob = out + (size_t)blockIdx.z*R*S;
  #pragma unroll
  for (int i = 0; i < 32; i += 8) t[ty+i][tx] = ib[(size_t)(r0+ty+i)*S + s0+tx];
  __syncthreads();
  #pragma unroll
  for (int i = 0; i < 32; i += 8) ob[(size_t)(s0+ty+i)*R + r0+tx] = t[tx][ty+i];
}

__global__ __launch_bounds__(256) void zero_kernel(float* __restrict__ p, int n) {
  int i = blockIdx.x*256 + threadIdx.x;
  if (i < n) p[i] = 0.f;
}

// ---- stage A: blockwise sample from CHANNEL-LAST image oT [B][HW][C] ----
// grid (G, NPTS/4): blockIdx.x = instance (XCD-pinned), 4 points per block.
__global__ __launch_bounds__(256) void sample_all_kernel(const float* __restrict__ oT,
    const float* __restrict__ brand, hbf16* __restrict__ pf_hi, hbf16* __restrict__ pf_lo,
    float* __restrict__ coords_all, int g0) {
  int ly = blockIdx.x;
  int inst = g0 + ly;
  int b = inst & 7;
  const float* xT = oT + (size_t)b*HW_*C_;
  int tid = threadIdx.x;
  int p = tid >> 6, lane = tid & 63;
  int n = blockIdx.y*4 + p;
  int k = n & 1, pw = (n >> 1) & 31, ph = n >> 6;
  const float* br = brand + (size_t)inst*4096;
  int roff = ((ph*32 + pw)*2 + k)*2;
  float r0 = br[roff], r1 = br[roff+1];
  const float bs = 0.0625f;
  float c0 = r0*bs + ((float)ph*bs - 1.0f);
  float c1 = r1*bs + ((float)pw*bs - 1.0f);
  Taps t = bilin_taps(c0, c1);
  const float* r00 = xT + (size_t)(t.y0*32+t.x0)*C_;
  const float* r10 = xT + (size_t)(t.y0*32+t.x1)*C_;
  const float* r01 = xT + (size_t)(t.y1*32+t.x0)*C_;
  const float* r11 = xT + (size_t)(t.y1*32+t.x1)*C_;
  size_t base = ((size_t)ly*NPTS + n)*C_;
  short* ph_ = (short*)pf_hi;
  short* pl_ = (short*)pf_lo;
  #pragma unroll
  for (int kk = 0; kk < 3; ++kk) {
    int c = kk*256 + lane*4;
    float4 v00 = *(const float4*)(r00 + c);
    float4 v10 = *(const float4*)(r10 + c);
    float4 v01 = *(const float4*)(r01 + c);
    float4 v11 = *(const float4*)(r11 + c);
    float o[4];
    o[0] = t.w00*v00.x + t.w10*v10.x + t.w01*v01.x + t.w11*v11.x;
    o[1] = t.w00*v00.y + t.w10*v10.y + t.w01*v01.y + t.w11*v11.y;
    o[2] = t.w00*v00.z + t.w10*v10.z + t.w01*v01.z + t.w11*v11.z;
    o[3] = t.w00*v00.w + t.w10*v10.w + t.w01*v01.w + t.w11*v11.w;
    short4v hs, ls;
    #pragma unroll
    for (int e = 0; e < 4; ++e) {
      hbf16 h = __float2bfloat16(o[e]);
      hs[e] = *(short*)&h;
      hbf16 l = __float2bfloat16(o[e] - b2f(h));
      ls[e] = *(short*)&l;
    }
    *(short4v*)&ph_[base + c] = hs;
    *(short4v*)&pl_[base + c] = ls;
  }
  if (lane == 0) {
    size_t co = ((size_t)inst*NPTS + n)*2;
    coords_all[co] = c0; coords_all[co+1] = c1;
  }
}

// ---- XCD swizzle: each XCD owns gy/8 contiguous row-panels, iterates cols fastest ----
// wgid%8 = XCD (round-robin dispatch); requires gx*gy % 8 == 0 and gy % 8 == 0.
__device__ __forceinline__ void xcd_tile(int gx, int gy, int& row, int& col) {
  int wgid = blockIdx.y * gx + blockIdx.x;
  int xcd = wgid & 7;
  int li = wgid >> 3;
  row = xcd * (gy >> 3) + li / gx;
  col = li % gx;
}

// ---- fused score GEMM (split-bf16, 3-term) + relu + w2-dot -> atomicAdd logits ----
// Linear LDS [128][32] per buffer; staging via global_load_lds (16B/lane).
__global__ __launch_bounds__(256) void score_gemm_kernel(const short* __restrict__ Ahi,
    const short* __restrict__ Alo, const short* __restrict__ Bhi, const short* __restrict__ Blo,
    const float* __restrict__ b1, const float* __restrict__ w2, float* __restrict__ logit) {
  __shared__ short AsH[128*32];
  __shared__ short AsL[128*32];
  __shared__ short BsH[128*32];
  __shared__ short BsL[128*32];
  int tid = threadIdx.x;
  int lane = tid & 63, w = tid >> 6;
  int wr = (w >> 1) * 64, wc = (w & 1) * 64;
  int m16 = lane & 15, quad = lane >> 4, q8 = quad * 8;
  int brow, bcol;
  xcd_tile(gridDim.x, gridDim.y, brow, bcol);
  int bm = brow * 128, bn = bcol * 128;
  int sr = w * 32;                    // this wave's 32-row slice
  int lr = lane >> 2, lc = (lane & 3) * 8;
  f32x4 acc[4][4] = {};
  for (int k0 = 0; k0 < 768; k0 += 32) {
    {
      const short* pa = &Ahi[(size_t)(bm + sr + lr)*768 + k0 + lc];
      const short* pl = &Alo[(size_t)(bm + sr + lr)*768 + k0 + lc];
      const short* pb = &Bhi[(size_t)(bn + sr + lr)*768 + k0 + lc];
      const short* pq = &Blo[(size_t)(bn + sr + lr)*768 + k0 + lc];
      gload16(pa,            &AsH[sr*32]);
      gload16(pa + 16*768,   &AsH[(sr+16)*32]);
      gload16(pl,            &AsL[sr*32]);
      gload16(pl + 16*768,   &AsL[(sr+16)*32]);
      gload16(pb,            &BsH[sr*32]);
      gload16(pb + 16*768,   &BsH[(sr+16)*32]);
      gload16(pq,            &BsL[sr*32]);
      gload16(pq + 16*768,   &BsL[(sr+16)*32]);
    }
    __syncthreads();
    short8v ah[4], al[4], bh[4], bl[4];
    #pragma unroll
    for (int i=0;i<4;++i) {
      ah[i] = *(const short8v*)&AsH[(wr + i*16 + m16)*32 + q8];
      al[i] = *(const short8v*)&AsL[(wr + i*16 + m16)*32 + q8];
      bh[i] = *(const short8v*)&BsH[(wc + i*16 + m16)*32 + q8];
      bl[i] = *(const short8v*)&BsL[(wc + i*16 + m16)*32 + q8];
    }
    #pragma unroll
    for (int i=0;i<4;++i)
      #pragma unroll
      for (int j=0;j<4;++j) {
        acc[i][j] = __builtin_amdgcn_mfma_f32_16x16x32_bf16(ah[i], bh[j], acc[i][j], 0, 0, 0);
        acc[i][j] = __builtin_amdgcn_mfma_f32_16x16x32_bf16(ah[i], bl[j], acc[i][j], 0, 0, 0);
        acc[i][j] = __builtin_amdgcn_mfma_f32_16x16x32_bf16(al[i], bh[j], acc[i][j], 0, 0, 0);
      }
    __syncthreads();
  }
  float b1v[4], w2v[4];
  #pragma unroll
  for (int j=0;j<4;++j) {
    int col = bn + wc + j*16 + m16;
    b1v[j] = b1[col]; w2v[j] = w2[col];
  }
  #pragma unroll
  for (int i=0;i<4;++i) {
    #pragma unroll
    for (int r=0;r<4;++r) {
      float v = 0.f;
      #pragma unroll
      for (int j=0;j<4;++j) {
        float h = fmaxf(acc[i][j][r] + b1v[j], 0.f);
        v += h * w2v[j];
      }
      v += __shfl_xor(v, 1); v += __shfl_xor(v, 2);
      v += __shfl_xor(v, 4); v += __shfl_xor(v, 8);
      if (m16 == 0) atomicAdd(&logit[bm + wr + i*16 + quad*4 + r], v);
    }
  }
}

// ---- top-5 of 2048 per instance (on logits; sigmoid monotone), jax tie semantics ----
__global__ void topk_all_kernel(const float* __restrict__ logit, int* __restrict__ idx) {
  int lane = threadIdx.x;   // 64 lanes
  const float* score = logit + (size_t)blockIdx.x*NPTS;
  float v[32];
  #pragma unroll
  for (int i = 0; i < 32; ++i) v[i] = score[(i<<6) | lane];
  for (int t = 0; t < TOPK_; ++t) {
    float bv = v[0]; int bi = lane;
    #pragma unroll
    for (int i = 1; i < 32; ++i) { if (v[i] > bv) { bv = v[i]; bi = (i<<6)|lane; } }
    for (int off = 32; off; off >>= 1) {
      float ov = __shfl_xor(bv, off);
      int   oi = __shfl_xor(bi, off);
      if (ov > bv || (ov == bv && oi < bi)) { bv = ov; bi = oi; }
    }
    if (lane == 0) idx[blockIdx.x*8 + t] = bi;
    if ((bi & 63) == lane) v[bi >> 6] = -1e30f;
  }
}

// ---- soft_align + modality query -> memf rows; grid (TOPK, G) ----
// mainxT is channel-last [B][HW][C] (the tgt buffer, pre-tgt0)
__global__ __launch_bounds__(256) void softalign_all_kernel(const float* __restrict__ mainxT,
    const float* __restrict__ pos, const hbf16* __restrict__ pf_hi, const hbf16* __restrict__ pf_lo,
    const float* __restrict__ coords_all, const int* __restrict__ idx_all,
    const float* __restrict__ arand, const float* __restrict__ mq,
    float* __restrict__ memf, int g0) {
  int t = blockIdx.x;
  int ly = blockIdx.y;
  int inst = g0 + ly;
  int mod = inst >> 3, b = inst & 7;
  const float* mT_b = mainxT + (size_t)b*HW_*C_;
  const float* arand_ib = arand + (size_t)inst*AROUND_*TOPK_*2;
  const float* coords = coords_all + (size_t)inst*NPTS*2;
  int tid = threadIdx.x;
  int n = idx_all[ly*8 + t];
  float px0 = coords[n*2], px1 = coords[n*2+1];
  size_t pfb = ((size_t)ly*NPTS + n)*C_;
  float pfv[3];
  #pragma unroll
  for (int i=0;i<3;++i) {
    int c = tid + i*256;
    pfv[i] = b2f(pf_hi[pfb + c]) + b2f(pf_lo[pfb + c]);
  }
  __shared__ float red[256];
  float pp = block_reduce_sum_256(pfv[0]*pfv[0]+pfv[1]*pfv[1]+pfv[2]*pfv[2], red);
  float embr[AROUND_][3];
  float num_a[AROUND_], aa_a[AROUND_];
  for (int a=0; a<AROUND_; ++a) {
    int ar = (a*TOPK_ + t)*2;
    float g0c = px0 + (arand_ib[ar]*2.f - 0.5f)*0.2f;
    float g1c = px1 + (arand_ib[ar+1]*2.f - 0.5f)*0.2f;
    g0c = fminf(fmaxf(g0c,-1.f),1.f);
    g1c = fminf(fmaxf(g1c,-1.f),1.f);
    Taps tp = bilin_taps(g0c, g1c);
    int i00=tp.y0*32+tp.x0, i10=tp.y0*32+tp.x1, i01=tp.y1*32+tp.x0, i11=tp.y1*32+tp.x1;
    float s_num = 0.f, s_aa = 0.f;
    #pragma unroll
    for (int i=0;i<3;++i) {
      int c = tid + i*256;
      float af = tp.w00*mT_b[(size_t)i00*C_+c] + tp.w10*mT_b[(size_t)i10*C_+c]
               + tp.w01*mT_b[(size_t)i01*C_+c] + tp.w11*mT_b[(size_t)i11*C_+c];
      float em = tp.w00*pos[(size_t)i00*C_+c] + tp.w10*pos[(size_t)i10*C_+c]
               + tp.w01*pos[(size_t)i01*C_+c] + tp.w11*pos[(size_t)i11*C_+c];
      embr[a][i] = em;
      s_num += pfv[i]*af;
      s_aa  += af*af;
    }
    num_a[a] = block_reduce_sum_256(s_num, red);
    aa_a[a]  = block_reduce_sum_256(s_aa, red);
  }
  float pn = fmaxf(sqrtf(pp), 1e-8f);
  float w[AROUND_]; float mx = -1e30f;
  #pragma unroll
  for (int a=0;a<AROUND_;++a){ float den = pn * fmaxf(sqrtf(aa_a[a]),1e-8f); w[a]=num_a[a]/den; mx=fmaxf(mx,w[a]); }
  float se = 0.f;
  #pragma unroll
  for (int a=0;a<AROUND_;++a){ w[a]=expf(w[a]-mx); se+=w[a]; }
  float inv = 1.f/se;
  float* mo = memf + ((size_t)b*(MOD_*TOPK_) + mod*TOPK_ + t)*C_;
  #pragma unroll
  for (int i=0;i<3;++i) {
    int c = tid + i*256;
    float o = pfv[i];
    #pragma unroll
    for (int a=0;a<AROUND_;++a) o += embr[a][i]*(w[a]*inv);
    o += mq[(size_t)(mod+1)*C_ + c];
    mo[c] = o;
  }
}

// ---- generic fp32 GEMM (kvm only) ----
#define BM 64
#define BN 64
#define BK 16
__global__ __launch_bounds__(256) void gemm_kernel(const float* __restrict__ A, int lda,
    const float* __restrict__ Bw, int ldb, const float* __restrict__ bias,
    float* __restrict__ Cm, int ldc, int M, int N, int K, int act) {
  __shared__ float As[BK][BM];
  __shared__ float Bs[BK][BN];
  int tid = threadIdx.x;
  int bm = blockIdx.y * BM, bn = blockIdx.x * BN;
  int arw = tid >> 2, acl = (tid & 3) << 2;
  int brw = tid >> 4, bcl = (tid & 15) << 2;
  int ty = tid >> 4, tx = tid & 15;
  float acc[4][4] = {{0.f}};
  for (int k0 = 0; k0 < K; k0 += BK) {
    float a0=0.f,a1=0.f,a2=0.f,a3=0.f;
    if (bm + arw < M) {
      const float* ap = A + (size_t)(bm+arw)*lda + k0 + acl;
      a0=ap[0]; a1=ap[1]; a2=ap[2]; a3=ap[3];
    }
    As[acl+0][arw]=a0; As[acl+1][arw]=a1; As[acl+2][arw]=a2; As[acl+3][arw]=a3;
    const float* bp = Bw + (size_t)(k0+brw)*ldb + bn + bcl;
    Bs[brw][bcl+0]=bp[0]; Bs[brw][bcl+1]=bp[1]; Bs[brw][bcl+2]=bp[2]; Bs[brw][bcl+3]=bp[3];
    __syncthreads();
    #pragma unroll
    for (int kk = 0; kk < BK; ++kk) {
      float4 av = *reinterpret_cast<const float4*>(&As[kk][ty<<2]);
      float4 bv = *reinterpret_cast<const float4*>(&Bs[kk][tx<<2]);
      acc[0][0]+=av.x*bv.x; acc[0][1]+=av.x*bv.y; acc[0][2]+=av.x*bv.z; acc[0][3]+=av.x*bv.w;
      acc[1][0]+=av.y*bv.x; acc[1][1]+=av.y*bv.y; acc[1][2]+=av.y*bv.z; acc[1][3]+=av.y*bv.w;
      acc[2][0]+=av.z*bv.x; acc[2][1]+=av.z*bv.y; acc[2][2]+=av.z*bv.z; acc[2][3]+=av.z*bv.w;
      acc[3][0]+=av.w*bv.x; acc[3][1]+=av.w*bv.y; acc[3][2]+=av.w*bv.z; acc[3][3]+=av.w*bv.w;
    }
    __syncthreads();
  }
  #pragma unroll
  for (int i=0;i<4;++i) {
    int r = bm + (ty<<2) + i;
    if (r >= M) continue;
    float* cp = Cm + (size_t)r*ldc + bn + (tx<<2);
    #pragma unroll
    for (int j=0;j<4;++j) {
      float v = acc[i][j] + bias[bn + (tx<<2) + j];
      if (act) v = fmaxf(v, 0.f);
      cp[j] = v;
    }
  }
}

// ---- bf16 MFMA GEMM, B pre-transposed: C = act(A[M,K] @ Bt[N,K]^T + bias), 128x128 tile ----
// Linear LDS [128][32]; staging via global_load_lds.
__global__ __launch_bounds__(256) void gemm_mfma_t(const short* __restrict__ A, int lda,
    const short* __restrict__ Bt, int ldbt, const float* __restrict__ bias,
    hbf16* __restrict__ Cm, int ldc, int K, int act) {
  __shared__ short As[128*32];
  __shared__ short Bs[128*32];
  int tid = threadIdx.x;
  int lane = tid & 63, w = tid >> 6;
  int wr = (w >> 1) * 64, wc = (w & 1) * 64;
  int m16 = lane & 15, q8 = (lane >> 4) * 8;
  int brow, bcol;
  xcd_tile(gridDim.x, gridDim.y, brow, bcol);
  int bm = brow * 128, bn = bcol * 128;
  int sr = w * 32;
  int lr = lane >> 2, lc = (lane & 3) * 8;
  f32x4 acc[4][4] = {};
  for (int k0 = 0; k0 < K; k0 += 32) {
    {
      const short* pa = &A [(size_t)(bm + sr + lr)*lda  + k0 + lc];
      const short* pb = &Bt[(size_t)(bn + sr + lr)*ldbt + k0 + lc];
      gload16(pa,                    &As[sr*32]);
      gload16(pa + (size_t)16*lda,   &As[(sr+16)*32]);
      gload16(pb,                    &Bs[sr*32]);
      gload16(pb + (size_t)16*ldbt,  &Bs[(sr+16)*32]);
    }
    __syncthreads();
    short8v af[4], bf[4];
    #pragma unroll
    for (int i=0;i<4;++i) af[i] = *(const short8v*)&As[(wr + i*16 + m16)*32 + q8];
    #pragma unroll
    for (int j=0;j<4;++j) bf[j] = *(const short8v*)&Bs[(wc + j*16 + m16)*32 + q8];
    #pragma unroll
    for (int i=0;i<4;++i)
      #pragma unroll
      for (int j=0;j<4;++j)
        acc[i][j] = __builtin_amdgcn_mfma_f32_16x16x32_bf16(af[i], bf[j], acc[i][j], 0, 0, 0);
    __syncthreads();
  }
  #pragma unroll
  for (int j=0;j<4;++j) {
    int col = bn + wc + j*16 + m16;
    float bs = bias[col];
    #pragma unroll
    for (int i=0;i<4;++i) {
      int row0 = bm + wr + i*16 + (lane>>4)*4;
      #pragma unroll
      for (int r=0;r<4;++r) {
        float v = acc[i][j][r] + bs;
        if (act) v = fmaxf(v, 0.f);
        Cm[(size_t)(row0+r)*ldc + col] = __float2bfloat16(v);
      }
    }
  }
}

// ---- bf16 MFMA GEMM, 128x64 tile (for small-N GEMMs; doubles grid vs 128x128) ----
// 4 waves, each computes 32 rows x 64 cols (acc[2][4]). Linear LDS + global_load_lds.
__global__ __launch_bounds__(256) void gemm_mfma_t64(const short* __restrict__ A, int lda,
    const short* __restrict__ Bt, int ldbt, const float* __restrict__ bias,
    hbf16* __restrict__ Cm, int ldc, int K, int act) {
  __shared__ short As[128*32];
  __shared__ short Bs[64*32];
  int tid = threadIdx.x;
  int lane = tid & 63, w = tid >> 6;
  int m16 = lane & 15, q8 = (lane >> 4) * 8;
  int brow, bcol;
  xcd_tile(gridDim.x, gridDim.y, brow, bcol);
  int bm = brow * 128, bn = bcol * 64;
  int sr = w * 32;            // A slice
  int srB = w * 16;           // B slice (4 waves x 16 rows)
  int lr = lane >> 2, lc = (lane & 3) * 8;
  f32x4 acc[2][4] = {};
  for (int k0 = 0; k0 < K; k0 += 32) {
    {
      const short* pa = &A [(size_t)(bm + sr  + lr)*lda  + k0 + lc];
      const short* pb = &Bt[(size_t)(bn + srB + lr)*ldbt + k0 + lc];
      gload16(pa,                   &As[sr*32]);
      gload16(pa + (size_t)16*lda,  &As[(sr+16)*32]);
      gload16(pb,                   &Bs[srB*32]);
    }
    __syncthreads();
    short8v af[2], bf[4];
    #pragma unroll
    for (int i=0;i<2;++i) af[i] = *(const short8v*)&As[(w*32 + i*16 + m16)*32 + q8];
    #pragma unroll
    for (int j=0;j<4;++j) bf[j] = *(const short8v*)&Bs[(j*16 + m16)*32 + q8];
    #pragma unroll
    for (int i=0;i<2;++i)
      #pragma unroll
      for (int j=0;j<4;++j)
        acc[i][j] = __builtin_amdgcn_mfma_f32_16x16x32_bf16(af[i], bf[j], acc[i][j], 0, 0, 0);
    __syncthreads();
  }
  #pragma unroll
  for (int j=0;j<4;++j) {
    int col = bn + j*16 + m16;
    float bs = bias[col];
    #pragma unroll
    for (int i=0;i<2;++i) {
      int row0 = bm + w*32 + i*16 + (lane>>4)*4;
      #pragma unroll
      for (int r=0;r<4;++r) {
        float v = acc[i][j][r] + bs;
        if (act) v = fmaxf(v, 0.f);
        Cm[(size_t)(row0+r)*ldc + col] = __float2bfloat16(v);
      }
    }
  }
}

// ---- fused flash self-attention (MFMA): grid (head+batch, qtile=8), 512 thr / 8 waves ----
// x = h + NH_*bz so all q-tiles of one (b,h) share an XCD (ids congruent mod 8).
// K/V double-buffered; next tile reg-prefetched (issue early, write after PV);
// P is wave-private (16 rows/wave) -> ONE barrier per K/V tile.
__global__ __launch_bounds__(512, 4) void flash_attn_kernel(const hbf16* __restrict__ qkv_all,
    hbf16* __restrict__ o_all) {
  const int hb = blockIdx.x;
  const int h  = hb & 7;
  const int bz = hb >> 3;
  const int q0 = blockIdx.y * 128;
  const short* qkv = (const short*)(qkv_all + (size_t)bz*HW_*2304);
  hbf16* ob = o_all + (size_t)bz*HW_*C_;
  const int tid = threadIdx.x;
  const int lane = tid & 63, w = tid >> 6;
  const int m16 = lane & 15, quad = lane >> 4, q8 = quad * 8;
  const float scale = 0.10206207261596577f;  // 1/sqrt(96)

  // K0[64][104]@0, K1@6656, Vt0[96][72]@13312, Vt1@20224, P[128][72]@27136.
  // Q staging [128][104]=13312 aliases K0+K1. Total 36352 shorts = 72704 B (2 blocks/CU).
  __shared__ short lds[36352];
  short* P = lds + 27136;

  // stage Q -> LDS (coalesced), hoist this wave's 16-row fragments to registers
  for (int idx = tid; idx < 128*12; idx += 512) {
    int row = idx / 12, dc = idx % 12;
    *(short8v*)&lds[row*104 + dc*8] = *(const short8v*)&qkv[(size_t)(q0+row)*2304 + h*HD_ + dc*8];
  }
  __syncthreads();
  short8v qf[3];
  #pragma unroll
  for (int kkk=0;kkk<3;++kkk)
    qf[kkk] = *(const short8v*)&lds[(w*16 + m16)*104 + q8 + kkk*32];
  __syncthreads();

  // prologue: stage tile 0 into K0/Vt0
  for (int idx = tid; idx < 768; idx += 512) {
    int row = idx / 12, dc = idx % 12;
    *(short8v*)&lds[row*104 + dc*8] = *(const short8v*)&qkv[(size_t)row*2304 + C_ + h*HD_ + dc*8];
    int j = idx & 63, dcv = idx >> 6;
    short8v v = *(const short8v*)&qkv[(size_t)j*2304 + 2*C_ + h*HD_ + dcv*8];
    #pragma unroll
    for (int s = 0; s < 8; ++s) lds[13312 + (dcv*8+s)*72 + j] = v[s];
  }
  __syncthreads();

  float m_st[4], l_st[4];
  f32x4 o_acc[6] = {};
  #pragma unroll
  for (int r=0;r<4;++r){ m_st[r] = -1e30f; l_st[r] = 0.f; }

  for (int t = 0; t < 16; ++t) {
    int cur = t & 1;
    short* Kc = lds + (cur ? 6656 : 0);
    short* Vc = lds + (cur ? 20224 : 13312);

    // issue prefetch for tile t+1 into registers (hidden under QK+softmax)
    short8v kr0, kr1, vr0, vr1;
    if (t < 15) {
      int j0n = (t+1)*64;
      { int row = tid/12, dc = tid%12;
        kr0 = *(const short8v*)&qkv[(size_t)(j0n+row)*2304 + C_ + h*HD_ + dc*8];
        int j = tid & 63, dcv = tid >> 6;
        vr0 = *(const short8v*)&qkv[(size_t)(j0n+j)*2304 + 2*C_ + h*HD_ + dcv*8]; }
      if (tid < 256) {
        int idx = tid + 512;
        int row = idx/12, dc = idx%12;
        kr1 = *(const short8v*)&qkv[(size_t)(j0n+row)*2304 + C_ + h*HD_ + dc*8];
        int j = idx & 63, dcv = idx >> 6;
        vr1 = *(const short8v*)&qkv[(size_t)(j0n+j)*2304 + 2*C_ + h*HD_ + dcv*8];
      }
    }

    // QK^T
    f32x4 accs[4] = {};
    __builtin_amdgcn_s_setprio(1);
    #pragma unroll
    for (int kkk = 0; kkk < 3; ++kkk) {
      int kk = kkk*32;
      short8v bf[4];
      #pragma unroll
      for (int n=0;n<4;++n) bf[n] = *(const short8v*)&Kc[(n*16 + m16)*104 + q8 + kk];
      #pragma unroll
      for (int n=0;n<4;++n)
        accs[n] = __builtin_amdgcn_mfma_f32_16x16x32_bf16(qf[kkk], bf[n], accs[n], 0, 0, 0);
    }
    __builtin_amdgcn_s_setprio(0);

    // online softmax -> P (wave-private rows; intra-wave LDS ordering, no barrier)
    #pragma unroll
    for (int r=0;r<4;++r) {
      float mx = -1e30f;
      #pragma unroll
      for (int n=0;n<4;++n) mx = fmaxf(mx, accs[n][r]*scale);
      #pragma unroll
      for (int off=1; off<16; off<<=1) mx = fmaxf(mx, __shfl_xor(mx, off));
      float m_new = fmaxf(m_st[r], mx);
      float alpha = __expf(m_st[r] - m_new);
      float psum = 0.f;
      int prow = (w*16 + quad*4 + r)*72 + m16;
      #pragma unroll
      for (int n=0;n<4;++n) {
        float pv = __expf(accs[n][r]*scale - m_new);
        psum += pv;
        *(hbf16*)&P[prow + n*16] = __float2bfloat16(pv);
      }
      #pragma unroll
      for (int off=1; off<16; off<<=1) psum += __shfl_xor(psum, off);
      l_st[r] = l_st[r]*alpha + psum;
      m_st[r] = m_new;
      #pragma unroll
      for (int dt=0; dt<6; ++dt) o_acc[dt][r] *= alpha;
    }

    // PV
    __builtin_amdgcn_s_setprio(1);
    #pragma unroll
    for (int k0 = 0; k0 < 64; k0 += 32) {
      short8v pf_, vf[6];
      pf_ = *(const short8v*)&P[(w*16 + m16)*72 + q8 + k0];
      #pragma unroll
      for (int dt=0; dt<6; ++dt) vf[dt] = *(const short8v*)&Vc[(dt*16 + m16)*72 + q8 + k0];
      #pragma unroll
      for (int dt=0; dt<6; ++dt)
        o_acc[dt] = __builtin_amdgcn_mfma_f32_16x16x32_bf16(pf_, vf[dt], o_acc[dt], 0, 0, 0);
    }
    __builtin_amdgcn_s_setprio(0);

    // write prefetched tile t+1 into the other buffer (safe: last read of that
    // buffer completed before the previous barrier)
    if (t < 15) {
      short* Kn = lds + (cur ? 0 : 6656);
      short* Vn = lds + (cur ? 13312 : 20224);
      { int row = tid/12, dc = tid%12;
        *(short8v*)&Kn[row*104 + dc*8] = kr0;
        int j = tid & 63, dcv = tid >> 6;
        #pragma unroll
        for (int s = 0; s < 8; ++s) Vn[(dcv*8+s)*72 + j] = vr0[s]; }
      if (tid < 256) {
        int idx = tid + 512;
        int row = idx/12, dc = idx%12;
        *(short8v*)&Kn[row*104 + dc*8] = kr1;
        int j = idx & 63, dcv = idx >> 6;
        #pragma unroll
        for (int s = 0; s < 8; ++s) Vn[(dcv*8+s)*72 + j] = vr1[s];
      }
    }
    __syncthreads();
  }

  #pragma unroll
  for (int r=0;r<4;++r) {
    float inv = 1.f / l_st[r];
    int row = q0 + w*16 + quad*4 + r;
    #pragma unroll
    for (int dt=0; dt<6; ++dt)
      ob[(size_t)row*C_ + h*HD_ + dt*16 + m16] = __float2bfloat16(o_acc[dt][r]*inv);
  }
}

// ---- cross-attention over 10 memory tokens, wave-parallel: 1 wave per q row ----
// grid (HW_/4, CH), 256 thr = 4 waves. Lane owns 12 channels; head h = lane/8
// spans lanes [8h,8h+8); per-head dot via 3x shfl_xor reduce. IN PLACE on qb.
__global__ __launch_bounds__(256) void cross_attn_kernel(hbf16* __restrict__ qb,
    const float* __restrict__ kvm, int b0) {
  int wv = threadIdx.x >> 6, lane = threadIdx.x & 63;
  int row = blockIdx.x*4 + wv;
  int lb = blockIdx.y;
  int b = b0 + lb;
  const float scale = 0.10206207261596577f;
  hbf16* qp = qb + ((size_t)lb*HW_ + row)*C_;
  int c0 = lane*12;
  const short* qs = (const short*)qp;
  float q[12];
  #pragma unroll
  for (int i0 = 0; i0 < 3; ++i0) {
    short4v s = *(const short4v*)&qs[c0 + i0*4];
    #pragma unroll
    for (int e = 0; e < 4; ++e) { hbf16 hh; *(short*)&hh = s[e]; q[i0*4+e] = b2f(hh); }
  }
  const float* kb = kvm + (size_t)(b*10)*1536;
  float sc[10];
  #pragma unroll
  for (int j = 0; j < 10; ++j) {
    const float* kp = kb + (size_t)j*1536 + c0;
    float4 k0 = *(const float4*)(kp);
    float4 k1 = *(const float4*)(kp+4);
    float4 k2 = *(const float4*)(kp+8);
    float s = q[0]*k0.x + q[1]*k0.y + q[2]*k0.z + q[3]*k0.w
            + q[4]*k1.x + q[5]*k1.y + q[6]*k1.z + q[7]*k1.w
            + q[8]*k2.x + q[9]*k2.y + q[10]*k2.z + q[11]*k2.w;
    s += __shfl_xor(s, 1); s += __shfl_xor(s, 2); s += __shfl_xor(s, 4);
    sc[j] = s * scale;
  }
  float m = sc[0];
  #pragma unroll
  for (int j=1;j<10;++j) m = fmaxf(m, sc[j]);
  float se = 0.f;
  #pragma unroll
  for (int j=0;j<10;++j){ sc[j] = __expf(sc[j]-m); se += sc[j]; }
  float inv = 1.f/se;
  float o[12] = {};
  #pragma unroll
  for (int j = 0; j < 10; ++j) {
    const float* vp = kb + (size_t)j*1536 + C_ + c0;
    float4 v0 = *(const float4*)(vp);
    float4 v1 = *(const float4*)(vp+4);
    float4 v2 = *(const float4*)(vp+8);
    float pj = sc[j]*inv;
    o[0]+=pj*v0.x; o[1]+=pj*v0.y; o[2]+=pj*v0.z; o[3]+=pj*v0.w;
    o[4]+=pj*v1.x; o[5]+=pj*v1.y; o[6]+=pj*v1.z; o[7]+=pj*v1.w;
    o[8]+=pj*v2.x; o[9]+=pj*v2.y; o[10]+=pj*v2.z; o[11]+=pj*v2.w;
  }
  short* qw = (short*)qp;
  #pragma unroll
  for (int i0 = 0; i0 < 3; ++i0) {
    short4v ov;
    #pragma unroll
    for (int e = 0; e < 4; ++e) { hbf16 hh = __float2bfloat16(o[i0*4+e]); ov[e] = *(short*)&hh; }
    *(short4v*)&qw[c0 + i0*4] = ov;
  }
}

// ---- tgt init: IN PLACE += mq[0] + pos; also emits bf16 copy (fused f2b) ----
__global__ __launch_bounds__(256) void tgt0_kernel(float* __restrict__ tgt,
    const float* __restrict__ mq, const float* __restrict__ pos, hbf16* __restrict__ outb) {
  size_t i = ((size_t)blockIdx.x*256 + threadIdx.x)*4;
  if (i >= (size_t)TOK_*C_) return;
  int c = (int)(i % C_);
  int tpos = (int)((i / C_) % HW_);
  float4 v = *(float4*)&tgt[i];
  float4 m = *(const float4*)&mq[c];
  float4 pp = *(const float4*)&pos[(size_t)tpos*C_ + c];
  v.x += m.x + pp.x; v.y += m.y + pp.y;
  v.z += m.z + pp.z; v.w += m.w + pp.w;
  *(float4*)&tgt[i] = v;
  short4v ov;
  hbf16 h0 = __float2bfloat16(v.x); ov[0] = *(short*)&h0;
  hbf16 h1 = __float2bfloat16(v.y); ov[1] = *(short*)&h1;
  hbf16 h2 = __float2bfloat16(v.z); ov[2] = *(short*)&h2;
  hbf16 h3 = __float2bfloat16(v.w); ov[3] = *(short*)&h3;
  *(short4v*)&((short*)outb)[i] = ov;
}

// ---- residual + layernorm (in place fp32) + fused bf16 emit ----
__global__ __launch_bounds__(256) void ln_res_kernel(float* __restrict__ tgt, const hbf16* __restrict__ add,
    const float* __restrict__ w, const float* __restrict__ bvec, hbf16* __restrict__ outb) {
  __shared__ float red[256];
  int row = blockIdx.x, tid = threadIdx.x;
  float* tp = tgt + (size_t)row*C_;
  const hbf16* ap = add + (size_t)row*C_;
  hbf16* op = outb + (size_t)row*C_;
  float x[3]; float s = 0.f, s2 = 0.f;
  #pragma unroll
  for (int i=0;i<3;++i){ int c=tid+i*256; float v=tp[c]+b2f(ap[c]); x[i]=v; s+=v; s2+=v*v; }
  s  = block_reduce_sum_256(s,  red);
  s2 = block_reduce_sum_256(s2, red);
  float mean = s * (1.f/C_);
  float var  = s2 * (1.f/C_) - mean*mean;
  float rstd = rsqrtf(var + 1e-5f);
  #pragma unroll
  for (int i=0;i<3;++i){
    int c=tid+i*256;
    float y = (x[i]-mean)*rstd*w[c] + bvec[c];
    tp[c] = y;
    op[c] = __float2bfloat16(y);
  }
}

extern "C" void kernel_launch(void* const* d_in, const int* in_sizes, int n_in,
                              void* d_out, int out_size, void* d_ws, size_t ws_size,
                              hipStream_t stream) {
  const float* mainx   = (const float*)d_in[0];
  const float* other0  = (const float*)d_in[1];
  const float* other1  = (const float*)d_in[2];
  const float* pos     = (const float*)d_in[3];
  const float* mq      = (const float*)d_in[4];
  const float* s_w1    = (const float*)d_in[5];
  const float* s_b1    = (const float*)d_in[6];
  const float* s_w2    = (const float*)d_in[7];
  const float* sa_in_w = (const float*)d_in[9];
  const float* sa_in_b = (const float*)d_in[10];
  const float* sa_out_w= (const float*)d_in[11];
  const float* sa_out_b= (const float*)d_in[12];
  const float* ca_in_w = (const float*)d_in[13];
  const float* ca_in_b = (const float*)d_in[14];
  const float* ca_out_w= (const float*)d_in[15];
  const float* ca_out_b= (const float*)d_in[16];
  const float* ff1_w   = (const float*)d_in[17];
  const float* ff1_b   = (const float*)d_in[18];
  const float* ff2_w   = (const float*)d_in[19];
  const float* ff2_b   = (const float*)d_in[20];
  const float* ln_w    = (const float*)d_in[21];
  const float* ln_b    = (const float*)d_in[22];
  const float* brand   = (const float*)d_in[23];
  const float* arand   = (const float*)d_in[24];

  // ---- workspace layout ----
  char* p = (char*)d_ws;
  auto alloc = [&](size_t bytes) { char* r = p; p += (bytes + 255) & ~(size_t)255; return (void*)r; };
  float* tgt    = (float*)alloc((size_t)TOK_*C_*4);       // 24 MB; holds mainxT during stage A
  hbf16* tgt_bf = (hbf16*)alloc((size_t)TOK_*C_*2);       // 12.6 MB bf16 mirror (fused f2b)
  hbf16* wb0    = (hbf16*)alloc((size_t)2359296*2);       // 4.5 MB (transposed weights)
  hbf16* wb1    = (hbf16*)alloc((size_t)2359296*2);       // 4.5 MB
  hbf16* w1t_hi = (hbf16*)alloc((size_t)C_*C_*2);
  hbf16* w1t_lo = (hbf16*)alloc((size_t)C_*C_*2);
  float* kvm    = (float*)alloc((size_t)80*1536*4);
  float* memf   = (float*)alloc((size_t)80*C_*4);
  float* coords = (float*)alloc((size_t)16*NPTS*2*4);
  float* logit  = (float*)alloc((size_t)16*NPTS*4);
  int*   idxb   = (int*)alloc(16*8*4);
  char*  S      = p;
  size_t used = (size_t)(p - (char*)d_ws);
  size_t Savail = (ws_size > used) ? ws_size - used : 0;
  int CH = 1;
  if (Savail >= (size_t)8*1024*7680 + 4096) CH = 8;        // per-row: qkv(2304)+oatt(768)+tmpb(768) bf16
  else if (Savail >= (size_t)4*1024*7680 + 4096) CH = 4;
  else if (Savail >= (size_t)2*1024*7680 + 4096) CH = 2;
  const size_t R = (size_t)CH*1024;
  const size_t perG = (size_t)NPTS*C_*2*2;  // pf_hi+pf_lo per instance
  // stage-A scratch: oT (one image set, channel-last) at front of S, pf after
  const size_t oTb = (size_t)B_*HW_*C_*4;   // 25.2 MB, 256-aligned
  float* oT = (float*)S;
  char* Spf = S + oTb;
  size_t SA = (Savail > oTb) ? Savail - oTb : 0;
  int G = 1;
  if (SA >= 8*perG) G = 8;
  else if (SA >= 4*perG) G = 4;
  else if (SA >= 2*perG) G = 2;

  // ---- stage A ----
  // mainx [B][C][HW] -> channel-last in tgt (softalign reads it; tgt0 finishes in place)
  btrans_kernel<<<dim3(HW_/32, C_/32, B_), 256, 0, stream>>>(mainx, tgt, C_, HW_);
  wtrans_split_kernel<<<dim3(C_/32, C_/32), 256, 0, stream>>>(s_w1, w1t_hi, w1t_lo, C_, C_);
  zero_kernel<<<16*NPTS/256, 256, 0, stream>>>(logit, 16*NPTS);
  for (int g0 = 0; g0 < 16; g0 += G) {
    if ((g0 & 7) == 0)
      btrans_kernel<<<dim3(HW_/32, C_/32, B_), 256, 0, stream>>>(g0 < 8 ? other0 : other1,
          oT, C_, HW_);
    hbf16* pf_hi = (hbf16*)Spf;
    hbf16* pf_lo = pf_hi + (size_t)G*NPTS*C_;
    sample_all_kernel<<<dim3(G, NPTS/4), 256, 0, stream>>>(oT, brand,
        pf_hi, pf_lo, coords, g0);
    score_gemm_kernel<<<dim3(6, G*16), 256, 0, stream>>>((const short*)pf_hi, (const short*)pf_lo,
        (const short*)w1t_hi, (const short*)w1t_lo, s_b1, s_w2, logit + (size_t)g0*NPTS);
    topk_all_kernel<<<G, 64, 0, stream>>>(logit + (size_t)g0*NPTS, idxb + g0*8);
    softalign_all_kernel<<<dim3(TOPK_, G), 256, 0, stream>>>(tgt, pos, pf_hi, pf_lo,
        coords, idxb + g0*8, arand, mq, memf, g0);
  }

  // ---- stage B ----
  size_t total = (size_t)TOK_*C_;
  tgt0_kernel<<<(int)((total/4+255)/256), 256, 0, stream>>>(tgt, mq, pos, tgt_bf);

  for (int l = 0; l < 2; ++l) {
    // ===== self-attention =====
    wtrans_kernel<<<dim3(3*C_/32, C_/32), 256, 0, stream>>>(sa_in_w + (size_t)l*C_*3*C_, wb0, C_, 3*C_);
    wtrans_kernel<<<dim3(C_/32, C_/32), 256, 0, stream>>>(sa_out_w + (size_t)l*C_*C_, wb1, C_, C_);
    for (int c0 = 0; c0 < B_; c0 += CH) {
      float* tgtc = tgt + (size_t)c0*HW_*C_;
      hbf16* abuf = tgt_bf + (size_t)c0*HW_*C_;
      hbf16* qkv  = (hbf16*)S;
      hbf16* oatt = qkv + R*3*C_;
      hbf16* tmpb = oatt + R*C_;
      gemm_mfma_t<<<dim3(3*C_/128, (int)(R/128)), 256, 0, stream>>>((const short*)abuf, C_,
          (const short*)wb0, C_, sa_in_b + (size_t)l*3*C_, qkv, 3*C_, C_, 0);
      flash_attn_kernel<<<dim3(NH_*CH, HW_/128), 512, 0, stream>>>(qkv, oatt);
      gemm_mfma_t64<<<dim3(C_/64, (int)(R/128)), 256, 0, stream>>>((const short*)oatt, C_,
          (const short*)wb1, C_, sa_out_b + (size_t)l*C_, tmpb, C_, C_, 0);
      ln_res_kernel<<<(int)R, 256, 0, stream>>>(tgtc, tmpb,
          ln_w + (size_t)(l*3+0)*C_, ln_b + (size_t)(l*3+0)*C_, abuf);
    }

    // ===== cross-attention =====
    wtrans_kernel<<<dim3(C_/32, C_/32), 256, 0, stream>>>(ca_in_w + (size_t)l*C_*3*C_, wb0, C_, 3*C_);
    wtrans_kernel<<<dim3(C_/32, C_/32), 256, 0, stream>>>(ca_out_w + (size_t)l*C_*C_, wb1, C_, C_);
    gemm_kernel<<<dim3((2*C_+BN-1)/BN, (80+BM-1)/BM), 256, 0, stream>>>(memf, C_,
        ca_in_w + (size_t)l*C_*3*C_ + C_, 3*C_, ca_in_b + (size_t)l*3*C_ + C_, kvm, 2*C_,
        80, 2*C_, C_, 0);
    for (int c0 = 0; c0 < B_; c0 += CH) {
      float* tgtc = tgt + (size_t)c0*HW_*C_;
      hbf16* abuf = tgt_bf + (size_t)c0*HW_*C_;
      hbf16* qb   = (hbf16*)S;
      hbf16* tmpb = qb + R*C_;
      gemm_mfma_t64<<<dim3(C_/64, (int)(R/128)), 256, 0, stream>>>((const short*)abuf, C_,
          (const short*)wb0, C_, ca_in_b + (size_t)l*3*C_, qb, C_, C_, 0);
      cross_attn_kernel<<<dim3(HW_/4, CH), 256, 0, stream>>>(qb, kvm, c0);
      gemm_mfma_t64<<<dim3(C_/64, (int)(R/128)), 256, 0, stream>>>((const short*)qb, C_,
          (const short*)wb1, C_, ca_out_b + (size_t)l*C_, tmpb, C_, C_, 0);
      ln_res_kernel<<<(int)R, 256, 0, stream>>>(tgtc, tmpb,
          ln_w + (size_t)(l*3+1)*C_, ln_b + (size_t)(l*3+1)*C_, abuf);
    }

    // ===== FFN =====
    wtrans_kernel<<<dim3(FF_/32, C_/32), 256, 0, stream>>>(ff1_w + (size_t)l*C_*FF_, wb0, C_, FF_);
    wtrans_kernel<<<dim3(C_/32, FF_/32), 256, 0, stream>>>(ff2_w + (size_t)l*FF_*C_, wb1, FF_, C_);
    for (int c0 = 0; c0 < B_; c0 += CH) {
      float* tgtc = tgt + (size_t)c0*HW_*C_;
      hbf16* abuf = tgt_bf + (size_t)c0*HW_*C_;
      hbf16* ffh  = (hbf16*)S;
      hbf16* tmpb = ffh + R*FF_;
      gemm_mfma_t<<<dim3(FF_/128, (int)(R/128)), 256, 0, stream>>>((const short*)abuf, C_,
          (const short*)wb0, C_, ff1_b + (size_t)l*FF_, ffh, FF_, C_, 1);
      gemm_mfma_t64<<<dim3(C_/64, (int)(R/128)), 256, 0, stream>>>((const short*)ffh, FF_,
          (const short*)wb1, FF_, ff2_b + (size_t)l*C_, tmpb, C_, FF_, 0);
      ln_res_kernel<<<(int)R, 256, 0, stream>>>(tgtc, tmpb,
          ln_w + (size_t)(l*3+2)*C_, ln_b + (size_t)(l*3+2)*C_, abuf);
    }
  }

  // ---- final: tgt [B][HW][C] -> out [B][C][H][W], LDS-tiled transpose ----
  btrans_kernel<<<dim3(C_/32, HW_/32, B_), 256, 0, stream>>>(tgt, (float*)d_out, HW_, C_);
}